// Round 1
// baseline (280.978 us; speedup 1.0000x reference)
//
#include <hip/hip_runtime.h>
#include <hip/hip_bf16.h>

// ---------------------------------------------------------------------------
// Decoder block on MI355X. All matmuls via v_mfma_f32_16x16x32_bf16.
// Layouts: A [M][K] bf16 row-major; B pre-transposed to [N][K] bf16 so both
// MFMA operand fragments are contiguous ds_read_b128 (m92 pattern).
// ---------------------------------------------------------------------------

typedef __attribute__((ext_vector_type(8))) short short8;
typedef __attribute__((ext_vector_type(4))) short short4v;
typedef __attribute__((ext_vector_type(4))) float f32x4;

#define DEVI static __device__ __forceinline__

DEVI void gload_lds16(const void* g, void* l) {
  __builtin_amdgcn_global_load_lds(
      (const __attribute__((address_space(1))) void*)g,
      (__attribute__((address_space(3))) void*)l, 16, 0, 0);
}

DEVI float bf2f(short s) {
  union { float f; unsigned u; } cv;
  cv.u = ((unsigned)(unsigned short)s) << 16;
  return cv.f;
}
DEVI short f2bf(float f) {  // round-to-nearest-even
  union { float f; unsigned u; } cv;
  cv.f = f;
  unsigned u = cv.u;
  u += 0x7FFFu + ((u >> 16) & 1u);
  return (short)(u >> 16);
}

DEVI void block_reduce2(float& s, float& s2, float* red, int t) {
#pragma unroll
  for (int off = 1; off < 64; off <<= 1) {
    s += __shfl_xor(s, off, 64);
    s2 += __shfl_xor(s2, off, 64);
  }
  __syncthreads();  // protects red reuse across successive calls
  if ((t & 63) == 0) { red[(t >> 6) * 2] = s; red[(t >> 6) * 2 + 1] = s2; }
  __syncthreads();
  s = red[0] + red[2] + red[4] + red[6];
  s2 = red[1] + red[3] + red[5] + red[7];
}

// --------------------------- transpose f32 -> bf16 -------------------------
// in: [batch][R][C] f32, out: [batch][C][R] bf16. block (32,8).
__global__ __launch_bounds__(256) void transpose_to_bf16(
    const float* __restrict__ in, short* __restrict__ out, int R, int C) {
  __shared__ float tile[32][33];
  const int b = blockIdx.z;
  in += (size_t)b * R * C;
  out += (size_t)b * R * C;
  const int r0 = blockIdx.y * 32, c0 = blockIdx.x * 32;
  const int tx = threadIdx.x, ty = threadIdx.y;
#pragma unroll
  for (int i = 0; i < 32; i += 8)
    tile[ty + i][tx] = in[(size_t)(r0 + ty + i) * C + c0 + tx];
  __syncthreads();
#pragma unroll
  for (int i = 0; i < 32; i += 8)
    out[(size_t)(c0 + ty + i) * R + r0 + tx] = f2bf(tile[tx][ty + i]);
}

// ------------------------------- LayerNorms --------------------------------
__global__ __launch_bounds__(256) void ln1_kernel(
    const float* __restrict__ x, const float* __restrict__ g,
    const float* __restrict__ b, float* __restrict__ hf,
    short* __restrict__ hb) {
  __shared__ float red[8];
  const int row = blockIdx.x, t = threadIdx.x;
  float4 v = ((const float4*)(x + (size_t)row * 1024))[t];
  float s = v.x + v.y + v.z + v.w;
  float s2 = v.x * v.x + v.y * v.y + v.z * v.z + v.w * v.w;
  block_reduce2(s, s2, red, t);
  const float mu = s * (1.0f / 1024.0f);
  const float rstd = rsqrtf(s2 * (1.0f / 1024.0f) - mu * mu + 1e-5f);
  float4 gv = ((const float4*)g)[t], bv = ((const float4*)b)[t];
  float4 o;
  o.x = (v.x - mu) * rstd * gv.x + bv.x;
  o.y = (v.y - mu) * rstd * gv.y + bv.y;
  o.z = (v.z - mu) * rstd * gv.z + bv.z;
  o.w = (v.w - mu) * rstd * gv.w + bv.w;
  ((float4*)(hf + (size_t)row * 1024))[t] = o;
  short4v p = {f2bf(o.x), f2bf(o.y), f2bf(o.z), f2bf(o.w)};
  ((short4v*)(hb + (size_t)row * 1024))[t] = p;
}

// x2 = h + o; x3 = LN(x2,g2,b2) [f32 out]; hf = LN(x3,gf,bf) [bf16 out]
__global__ __launch_bounds__(256) void ln2f_kernel(
    const float* __restrict__ h, const float* __restrict__ o,
    const float* __restrict__ g2, const float* __restrict__ b2,
    const float* __restrict__ gf, const float* __restrict__ bfp,
    float* __restrict__ x3, short* __restrict__ hfb) {
  __shared__ float red[8];
  const int row = blockIdx.x, t = threadIdx.x;
  float4 hv = ((const float4*)(h + (size_t)row * 1024))[t];
  float4 ov = ((const float4*)(o + (size_t)row * 1024))[t];
  float4 v;
  v.x = hv.x + ov.x; v.y = hv.y + ov.y; v.z = hv.z + ov.z; v.w = hv.w + ov.w;
  float s = v.x + v.y + v.z + v.w;
  float s2 = v.x * v.x + v.y * v.y + v.z * v.z + v.w * v.w;
  block_reduce2(s, s2, red, t);
  float mu = s * (1.0f / 1024.0f);
  float rstd = rsqrtf(s2 * (1.0f / 1024.0f) - mu * mu + 1e-5f);
  float4 gv = ((const float4*)g2)[t], bv = ((const float4*)b2)[t];
  float4 xv;
  xv.x = (v.x - mu) * rstd * gv.x + bv.x;
  xv.y = (v.y - mu) * rstd * gv.y + bv.y;
  xv.z = (v.z - mu) * rstd * gv.z + bv.z;
  xv.w = (v.w - mu) * rstd * gv.w + bv.w;
  ((float4*)(x3 + (size_t)row * 1024))[t] = xv;
  s = xv.x + xv.y + xv.z + xv.w;
  s2 = xv.x * xv.x + xv.y * xv.y + xv.z * xv.z + xv.w * xv.w;
  block_reduce2(s, s2, red, t);
  mu = s * (1.0f / 1024.0f);
  rstd = rsqrtf(s2 * (1.0f / 1024.0f) - mu * mu + 1e-5f);
  float4 gv2 = ((const float4*)gf)[t], bv2 = ((const float4*)bfp)[t];
  short4v pk = {f2bf((xv.x - mu) * rstd * gv2.x + bv2.x),
                f2bf((xv.y - mu) * rstd * gv2.y + bv2.y),
                f2bf((xv.z - mu) * rstd * gv2.z + bv2.z),
                f2bf((xv.w - mu) * rstd * gv2.w + bv2.w)};
  ((short4v*)(hfb + (size_t)row * 1024))[t] = pk;
}

// ------------------------------- GEMM core ---------------------------------
// C[M][N] = A[M][K] * B^T[N][K], bf16 in, f32 acc. 128x128 tile, BK=32,
// 4 waves in 2x2, each 64x64 (4x4 frags of 16x16x32 MFMA).
// EPI 0: QKV  (bias add; q,k -> [BH][T][64] bf16, v -> [BH][64][T] bf16)
// EPI 1: FFN1 (bias+relu -> u bf16 [M][4096])
// EPI 2: FFN2 (acc + b2f + hf + x3 -> out f32 [M][1024])
template <int EPI>
__global__ __launch_bounds__(256) void gemm_kernel(
    const short* __restrict__ A, const short* __restrict__ B, int M, int N,
    int K, const float* __restrict__ f0, const float* __restrict__ f1,
    const float* __restrict__ f2, const float* __restrict__ fx3,
    const short* __restrict__ hfb, short* __restrict__ s0,
    short* __restrict__ s1, short* __restrict__ s2, float* __restrict__ fo) {
  __shared__ __align__(16) short Asm[128 * 32];
  __shared__ __align__(16) short Bsm[128 * 32];
  const int tid = threadIdx.x;
  const int lane = tid & 63, w = tid >> 6;
  const int wr = w >> 1, wc = w & 1;
  const int lr = lane & 15, lg = lane >> 4;
  const int m0 = blockIdx.y * 128, n0 = blockIdx.x * 128;

  const int crow = lane >> 2;       // row within a 16-row staging chunk
  const int ccol = (lane & 3) * 8;  // bf16 col offset (8 elems = 16B)
  const short* Ab = A + ((size_t)m0 + crow) * K + ccol;
  const short* Bb = B + ((size_t)n0 + crow) * K + ccol;
  const int ca = w, cb = w + 4;

  f32x4 acc[4][4] = {};

  for (int k0 = 0; k0 < K; k0 += 32) {
    __syncthreads();
    gload_lds16(Ab + (size_t)(ca * 16) * K + k0, &Asm[ca * 512]);
    gload_lds16(Ab + (size_t)(cb * 16) * K + k0, &Asm[cb * 512]);
    gload_lds16(Bb + (size_t)(ca * 16) * K + k0, &Bsm[ca * 512]);
    gload_lds16(Bb + (size_t)(cb * 16) * K + k0, &Bsm[cb * 512]);
    __syncthreads();
    short8 af[4], bfr[4];
#pragma unroll
    for (int mt = 0; mt < 4; ++mt)
      af[mt] = *(const short8*)&Asm[(wr * 64 + mt * 16 + lr) * 32 + lg * 8];
#pragma unroll
    for (int nt = 0; nt < 4; ++nt)
      bfr[nt] = *(const short8*)&Bsm[(wc * 64 + nt * 16 + lr) * 32 + lg * 8];
#pragma unroll
    for (int mt = 0; mt < 4; ++mt)
#pragma unroll
      for (int nt = 0; nt < 4; ++nt)
        acc[mt][nt] = __builtin_amdgcn_mfma_f32_16x16x32_bf16(
            af[mt], bfr[nt], acc[mt][nt], 0, 0, 0);
  }

#pragma unroll
  for (int mt = 0; mt < 4; ++mt) {
#pragma unroll
    for (int nt = 0; nt < 4; ++nt) {
      const int col = n0 + wc * 64 + nt * 16 + lr;
#pragma unroll
      for (int r = 0; r < 4; ++r) {
        const int row = m0 + wr * 64 + mt * 16 + lg * 4 + r;
        float val = acc[mt][nt][r];
        if constexpr (EPI == 0) {
          const int sel = col >> 10, nn = col & 1023;
          const int hh = nn >> 6, dd = nn & 63;
          const int bb = row >> 10, tt = row & 1023;
          if (sel == 0) {
            val += f0[nn];
            s0[(((size_t)(bb * 16 + hh)) * 1024 + tt) * 64 + dd] = f2bf(val);
          } else if (sel == 1) {
            val += f1[nn];
            s1[(((size_t)(bb * 16 + hh)) * 1024 + tt) * 64 + dd] = f2bf(val);
          } else {
            val += f2[nn];
            s2[(((size_t)(bb * 16 + hh)) * 64 + dd) * 1024 + tt] = f2bf(val);
          }
        } else if constexpr (EPI == 1) {
          val += f0[col];
          val = fmaxf(val, 0.0f);
          s0[(size_t)row * 4096 + col] = f2bf(val);
        } else {
          const size_t idx = (size_t)row * 1024 + col;
          fo[idx] = val + f0[col] + bf2f(hfb[idx]) + fx3[idx];
        }
      }
    }
  }
}

// ----------------------------- flash attention -----------------------------
// q,k: [64 bh][1024][64] bf16 ; vt: [64 bh][64][1024] bf16 ; o: [4][1024][1024] f32
// Block = (bh, 64-row q-tile). 4 waves x 16 q-rows. KV tiles of 64.
// K/V/P tiles in LDS with XOR-16B swizzle (row-major 128B rows otherwise
// 16-way bank conflict).
__global__ __launch_bounds__(256) void attn_kernel(
    const short* __restrict__ q, const short* __restrict__ k,
    const short* __restrict__ vt, float* __restrict__ o) {
  __shared__ __align__(16) short Ksm[64 * 64];
  __shared__ __align__(16) short Vsm[64 * 64];
  __shared__ __align__(16) short Psm[4 * 16 * 64];
  const int bh = blockIdx.x, qt = blockIdx.y;
  const int tid = threadIdx.x, lane = tid & 63, w = tid >> 6;
  const int lr = lane & 15, lg = lane >> 4;

  const short* qb = q + (size_t)bh * 1024 * 64;
  const short* kb = k + (size_t)bh * 1024 * 64;
  const short* vb = vt + (size_t)bh * 64 * 1024;

  const int qrow = qt * 64 + w * 16 + lr;
  short8 qf0 = *(const short8*)&qb[(size_t)qrow * 64 + lg * 8];
  short8 qf1 = *(const short8*)&qb[(size_t)qrow * 64 + 32 + lg * 8];

  f32x4 oacc[4] = {};
  float mrun[4], lrun[4];
#pragma unroll
  for (int r = 0; r < 4; ++r) { mrun[r] = -1e30f; lrun[r] = 0.0f; }

  const float scale = 0.03125f;  // 1/sqrt(C)=1/32
  const int srow = tid >> 3;     // staging row (0..31), +32 on pass 2
  const int sc8 = tid & 7;       // 16B chunk within 128B row
  short* pw = Psm + w * 1024;    // per-wave 16x64 P tile

  for (int kt = 0; kt <= qt; ++kt) {
    __syncthreads();
#pragma unroll
    for (int p = 0; p < 2; ++p) {
      const int rr = srow + p * 32;
      short8 kv8 = *(const short8*)&kb[((size_t)(kt * 64 + rr)) * 64 + sc8 * 8];
      *(short8*)((char*)Ksm + rr * 128 + ((sc8 ^ (rr & 7)) << 4)) = kv8;
      short8 vv8 = *(const short8*)&vb[(size_t)rr * 1024 + kt * 64 + sc8 * 8];
      *(short8*)((char*)Vsm + rr * 128 + ((sc8 ^ (rr & 7)) << 4)) = vv8;
    }
    __syncthreads();

    // S = Q K^T  (16 q-rows x 64 kv-cols per wave)
    f32x4 sfr[4];
#pragma unroll
    for (int nt = 0; nt < 4; ++nt) {
      const int krow = nt * 16 + lr;
      short8 kf0 = *(const short8*)((const char*)Ksm + krow * 128 +
                                    (((0 + lg) ^ (krow & 7)) << 4));
      short8 kf1 = *(const short8*)((const char*)Ksm + krow * 128 +
                                    (((4 + lg) ^ (krow & 7)) << 4));
      f32x4 z = {};
      z = __builtin_amdgcn_mfma_f32_16x16x32_bf16(qf0, kf0, z, 0, 0, 0);
      z = __builtin_amdgcn_mfma_f32_16x16x32_bf16(qf1, kf1, z, 0, 0, 0);
      sfr[nt] = z;
    }
    const int qg = qt * 64 + w * 16 + lg * 4;
    if (kt == qt) {
#pragma unroll
      for (int nt = 0; nt < 4; ++nt) {
        const int sg = kt * 64 + nt * 16 + lr;
#pragma unroll
        for (int r = 0; r < 4; ++r)
          sfr[nt][r] = (sg <= qg + r) ? sfr[nt][r] * scale : -1e30f;
      }
    } else {
#pragma unroll
      for (int nt = 0; nt < 4; ++nt)
#pragma unroll
        for (int r = 0; r < 4; ++r) sfr[nt][r] *= scale;
    }
    // online softmax (rows live in 16-lane groups)
    float pm[4];
#pragma unroll
    for (int r = 0; r < 4; ++r) {
      pm[r] = fmaxf(fmaxf(sfr[0][r], sfr[1][r]), fmaxf(sfr[2][r], sfr[3][r]));
#pragma unroll
      for (int off = 1; off < 16; off <<= 1)
        pm[r] = fmaxf(pm[r], __shfl_xor(pm[r], off, 64));
    }
    float alpha[4], rsum[4];
#pragma unroll
    for (int r = 0; r < 4; ++r) {
      const float mnew = fmaxf(mrun[r], pm[r]);
      alpha[r] = __expf(mrun[r] - mnew);
      mrun[r] = mnew;
      rsum[r] = 0.0f;
    }
#pragma unroll
    for (int nt = 0; nt < 4; ++nt)
#pragma unroll
      for (int r = 0; r < 4; ++r) {
        const float pv = __expf(sfr[nt][r] - mrun[r]);
        sfr[nt][r] = pv;
        rsum[r] += pv;
      }
#pragma unroll
    for (int r = 0; r < 4; ++r) {
#pragma unroll
      for (int off = 1; off < 16; off <<= 1)
        rsum[r] += __shfl_xor(rsum[r], off, 64);
      lrun[r] = lrun[r] * alpha[r] + rsum[r];
    }
#pragma unroll
    for (int nt = 0; nt < 4; ++nt)
#pragma unroll
      for (int r = 0; r < 4; ++r) oacc[nt][r] *= alpha[r];

    // P (D-layout) -> per-wave LDS (A-layout for PV), swizzled
#pragma unroll
    for (int nt = 0; nt < 4; ++nt)
#pragma unroll
      for (int r = 0; r < 4; ++r) {
        const int prow = lg * 4 + r, pcol = nt * 16 + lr;
        *(short*)((char*)pw + prow * 128 +
                  ((pcol * 2) ^ ((prow & 7) << 4))) = f2bf(sfr[nt][r]);
      }
    __syncthreads();

    // O += P * V
#pragma unroll
    for (int kc = 0; kc < 2; ++kc) {
      short8 pa = *(const short8*)((const char*)pw + lr * 128 +
                                   (((kc * 4 + lg) ^ (lr & 7)) << 4));
#pragma unroll
      for (int nt = 0; nt < 4; ++nt) {
        const int vrow = nt * 16 + lr;
        short8 vf = *(const short8*)((const char*)Vsm + vrow * 128 +
                                     (((kc * 4 + lg) ^ (vrow & 7)) << 4));
        oacc[nt] = __builtin_amdgcn_mfma_f32_16x16x32_bf16(pa, vf, oacc[nt], 0, 0, 0);
      }
    }
  }

  float* ob = o + (size_t)(bh >> 4) * 1024 * 1024 + (bh & 15) * 64;
#pragma unroll
  for (int nt = 0; nt < 4; ++nt)
#pragma unroll
    for (int r = 0; r < 4; ++r) {
      const int trow = qt * 64 + w * 16 + lg * 4 + r;
      ob[(size_t)trow * 1024 + nt * 16 + lr] = oacc[nt][r] / lrun[r];
    }
}

// ------------------------------- launcher ----------------------------------
extern "C" void kernel_launch(void* const* d_in, const int* in_sizes, int n_in,
                              void* d_out, int out_size, void* d_ws,
                              size_t ws_size, hipStream_t stream) {
  const float* x = (const float*)d_in[0];
  const float* Wq = (const float*)d_in[1];
  const float* bq = (const float*)d_in[2];
  const float* Wk = (const float*)d_in[3];
  const float* bk = (const float*)d_in[4];
  const float* Wv = (const float*)d_in[5];
  const float* bv = (const float*)d_in[6];
  const float* g1 = (const float*)d_in[7];
  const float* b1 = (const float*)d_in[8];
  const float* g2 = (const float*)d_in[9];
  const float* b2 = (const float*)d_in[10];
  const float* gf = (const float*)d_in[11];
  const float* bfp = (const float*)d_in[12];
  const float* W1 = (const float*)d_in[13];
  const float* b1f = (const float*)d_in[14];
  const float* W2 = (const float*)d_in[15];
  const float* b2f = (const float*)d_in[16];
  float* out = (float*)d_out;

  char* p = (char*)d_ws;
  short* wqkv_t = (short*)p; p += (size_t)3 * 1024 * 1024 * 2;   // 6MB  [3072][1024]
  short* w1_t = (short*)p;   p += (size_t)4096 * 1024 * 2;       // 8MB  [4096][1024]
  short* w2_t = (short*)p;   p += (size_t)1024 * 4096 * 2;       // 8MB  [1024][4096]
  float* hbuf = (float*)p;   p += (size_t)4096 * 1024 * 4;       // 16MB h (f32)
  short* hbb = (short*)p;    p += (size_t)4096 * 1024 * 2;       // 8MB  h (bf16)
  short* qbuf = (short*)p;   p += (size_t)64 * 1024 * 64 * 2;    // 8MB
  short* kbuf = (short*)p;   p += (size_t)64 * 1024 * 64 * 2;    // 8MB
  short* vtb = (short*)p;    p += (size_t)64 * 64 * 1024 * 2;    // 8MB
  float* obuf = (float*)p;   p += (size_t)4096 * 1024 * 4;       // 16MB
  float* x3b = (float*)p;    p += (size_t)4096 * 1024 * 4;       // 16MB
  short* hfb = (short*)p;    p += (size_t)4096 * 1024 * 2;       // 8MB
  short* ub = (short*)p;     p += (size_t)4096 * 4096 * 2;       // 32MB

  dim3 tb(32, 8);
  transpose_to_bf16<<<dim3(2, 32, 16), tb, 0, stream>>>(Wq, wqkv_t, 1024, 64);
  transpose_to_bf16<<<dim3(2, 32, 16), tb, 0, stream>>>(Wk, wqkv_t + 1024 * 1024, 1024, 64);
  transpose_to_bf16<<<dim3(2, 32, 16), tb, 0, stream>>>(Wv, wqkv_t + 2 * 1024 * 1024, 1024, 64);
  transpose_to_bf16<<<dim3(128, 32, 1), tb, 0, stream>>>(W1, w1_t, 1024, 4096);
  transpose_to_bf16<<<dim3(32, 128, 1), tb, 0, stream>>>(W2, w2_t, 4096, 1024);

  ln1_kernel<<<4096, 256, 0, stream>>>(x, g1, b1, hbuf, hbb);

  gemm_kernel<0><<<dim3(24, 32), 256, 0, stream>>>(
      hbb, wqkv_t, 4096, 3072, 1024, bq, bk, bv, nullptr, nullptr, qbuf, kbuf,
      vtb, nullptr);

  attn_kernel<<<dim3(64, 16), 256, 0, stream>>>(qbuf, kbuf, vtb, obuf);

  ln2f_kernel<<<4096, 256, 0, stream>>>(hbuf, obuf, g2, b2, gf, bfp, x3b, hfb);

  gemm_kernel<1><<<dim3(32, 32), 256, 0, stream>>>(
      hfb, w1_t, 4096, 4096, 1024, b1f, nullptr, nullptr, nullptr, nullptr, ub,
      nullptr, nullptr, nullptr);

  gemm_kernel<2><<<dim3(8, 32), 256, 0, stream>>>(
      ub, w2_t, 4096, 1024, 4096, b2f, nullptr, nullptr, x3b, hfb, nullptr,
      nullptr, nullptr, out);
}

// Round 2
// 273.616 us; speedup vs baseline: 1.0269x; 1.0269x over previous
//
#include <hip/hip_runtime.h>
#include <hip/hip_bf16.h>

// ---------------------------------------------------------------------------
// Decoder block on MI355X. All matmuls via v_mfma_f32_16x16x32_bf16.
// Layouts: A [M][K] bf16 row-major; B pre-transposed to [N][K] bf16 so both
// MFMA operand fragments are contiguous ds_read_b128 (m92 pattern).
// FFN2 uses split-K x4 (grid z) into f32 partials + fused reduce epilogue,
// because N=1024 alone gives only 256 blocks = 1 block/CU (occupancy cliff).
// ---------------------------------------------------------------------------

typedef __attribute__((ext_vector_type(8))) short short8;
typedef __attribute__((ext_vector_type(4))) short short4v;
typedef __attribute__((ext_vector_type(4))) float f32x4;

#define DEVI static __device__ __forceinline__

DEVI void gload_lds16(const void* g, void* l) {
  __builtin_amdgcn_global_load_lds(
      (const __attribute__((address_space(1))) void*)g,
      (__attribute__((address_space(3))) void*)l, 16, 0, 0);
}

DEVI float bf2f(short s) {
  union { float f; unsigned u; } cv;
  cv.u = ((unsigned)(unsigned short)s) << 16;
  return cv.f;
}
DEVI short f2bf(float f) {  // round-to-nearest-even
  union { float f; unsigned u; } cv;
  cv.f = f;
  unsigned u = cv.u;
  u += 0x7FFFu + ((u >> 16) & 1u);
  return (short)(u >> 16);
}

DEVI void block_reduce2(float& s, float& s2, float* red, int t) {
#pragma unroll
  for (int off = 1; off < 64; off <<= 1) {
    s += __shfl_xor(s, off, 64);
    s2 += __shfl_xor(s2, off, 64);
  }
  __syncthreads();  // protects red reuse across successive calls
  if ((t & 63) == 0) { red[(t >> 6) * 2] = s; red[(t >> 6) * 2 + 1] = s2; }
  __syncthreads();
  s = red[0] + red[2] + red[4] + red[6];
  s2 = red[1] + red[3] + red[5] + red[7];
}

// --------------------------- transpose f32 -> bf16 -------------------------
__global__ __launch_bounds__(256) void transpose_to_bf16(
    const float* __restrict__ in, short* __restrict__ out, int R, int C) {
  __shared__ float tile[32][33];
  const int b = blockIdx.z;
  in += (size_t)b * R * C;
  out += (size_t)b * R * C;
  const int r0 = blockIdx.y * 32, c0 = blockIdx.x * 32;
  const int tx = threadIdx.x, ty = threadIdx.y;
#pragma unroll
  for (int i = 0; i < 32; i += 8)
    tile[ty + i][tx] = in[(size_t)(r0 + ty + i) * C + c0 + tx];
  __syncthreads();
#pragma unroll
  for (int i = 0; i < 32; i += 8)
    out[(size_t)(c0 + ty + i) * R + r0 + tx] = f2bf(tile[tx][ty + i]);
}

// ------------------------------- LayerNorms --------------------------------
__global__ __launch_bounds__(256) void ln1_kernel(
    const float* __restrict__ x, const float* __restrict__ g,
    const float* __restrict__ b, float* __restrict__ hf,
    short* __restrict__ hb) {
  __shared__ float red[8];
  const int row = blockIdx.x, t = threadIdx.x;
  float4 v = ((const float4*)(x + (size_t)row * 1024))[t];
  float s = v.x + v.y + v.z + v.w;
  float s2 = v.x * v.x + v.y * v.y + v.z * v.z + v.w * v.w;
  block_reduce2(s, s2, red, t);
  const float mu = s * (1.0f / 1024.0f);
  const float rstd = rsqrtf(s2 * (1.0f / 1024.0f) - mu * mu + 1e-5f);
  float4 gv = ((const float4*)g)[t], bv = ((const float4*)b)[t];
  float4 o;
  o.x = (v.x - mu) * rstd * gv.x + bv.x;
  o.y = (v.y - mu) * rstd * gv.y + bv.y;
  o.z = (v.z - mu) * rstd * gv.z + bv.z;
  o.w = (v.w - mu) * rstd * gv.w + bv.w;
  ((float4*)(hf + (size_t)row * 1024))[t] = o;
  short4v p = {f2bf(o.x), f2bf(o.y), f2bf(o.z), f2bf(o.w)};
  ((short4v*)(hb + (size_t)row * 1024))[t] = p;
}

// x2 = h + o; x3 = LN(x2,g2,b2) [f32 out]; hf = LN(x3,gf,bf) [bf16 out]
__global__ __launch_bounds__(256) void ln2f_kernel(
    const float* __restrict__ h, const float* __restrict__ o,
    const float* __restrict__ g2, const float* __restrict__ b2,
    const float* __restrict__ gf, const float* __restrict__ bfp,
    float* __restrict__ x3, short* __restrict__ hfb) {
  __shared__ float red[8];
  const int row = blockIdx.x, t = threadIdx.x;
  float4 hv = ((const float4*)(h + (size_t)row * 1024))[t];
  float4 ov = ((const float4*)(o + (size_t)row * 1024))[t];
  float4 v;
  v.x = hv.x + ov.x; v.y = hv.y + ov.y; v.z = hv.z + ov.z; v.w = hv.w + ov.w;
  float s = v.x + v.y + v.z + v.w;
  float s2 = v.x * v.x + v.y * v.y + v.z * v.z + v.w * v.w;
  block_reduce2(s, s2, red, t);
  float mu = s * (1.0f / 1024.0f);
  float rstd = rsqrtf(s2 * (1.0f / 1024.0f) - mu * mu + 1e-5f);
  float4 gv = ((const float4*)g2)[t], bv = ((const float4*)b2)[t];
  float4 xv;
  xv.x = (v.x - mu) * rstd * gv.x + bv.x;
  xv.y = (v.y - mu) * rstd * gv.y + bv.y;
  xv.z = (v.z - mu) * rstd * gv.z + bv.z;
  xv.w = (v.w - mu) * rstd * gv.w + bv.w;
  ((float4*)(x3 + (size_t)row * 1024))[t] = xv;
  s = xv.x + xv.y + xv.z + xv.w;
  s2 = xv.x * xv.x + xv.y * xv.y + xv.z * xv.z + xv.w * xv.w;
  block_reduce2(s, s2, red, t);
  mu = s * (1.0f / 1024.0f);
  rstd = rsqrtf(s2 * (1.0f / 1024.0f) - mu * mu + 1e-5f);
  float4 gv2 = ((const float4*)gf)[t], bv2 = ((const float4*)bfp)[t];
  short4v pk = {f2bf((xv.x - mu) * rstd * gv2.x + bv2.x),
                f2bf((xv.y - mu) * rstd * gv2.y + bv2.y),
                f2bf((xv.z - mu) * rstd * gv2.z + bv2.z),
                f2bf((xv.w - mu) * rstd * gv2.w + bv2.w)};
  ((short4v*)(hfb + (size_t)row * 1024))[t] = pk;
}

// ------------------------------- GEMM core ---------------------------------
// C[M][N] = A[M][K] * B^T[N][K], bf16 in, f32 acc. 128x128 tile, BK=32,
// 4 waves in 2x2, each 64x64 (4x4 frags of 16x16x32 MFMA).
// K-loop runs [kbeg, kend). Epilogue is a functor-style template param.
template <int EPI>
DEVI void gemm_body(const short* __restrict__ A, const short* __restrict__ B,
                    int K, int kbeg, int kend, int m0, int n0,
                    const float* __restrict__ f0, const float* __restrict__ f1,
                    const float* __restrict__ f2, short* __restrict__ s0,
                    short* __restrict__ s1, short* __restrict__ s2,
                    float* __restrict__ fo) {
  __shared__ __align__(16) short Asm[128 * 32];
  __shared__ __align__(16) short Bsm[128 * 32];
  const int tid = threadIdx.x;
  const int lane = tid & 63, w = tid >> 6;
  const int wr = w >> 1, wc = w & 1;
  const int lr = lane & 15, lg = lane >> 4;

  const int crow = lane >> 2;       // row within a 16-row staging chunk
  const int ccol = (lane & 3) * 8;  // bf16 col offset (8 elems = 16B)
  const short* Ab = A + ((size_t)m0 + crow) * K + ccol;
  const short* Bb = B + ((size_t)n0 + crow) * K + ccol;
  const int ca = w, cb = w + 4;

  f32x4 acc[4][4] = {};

  for (int k0 = kbeg; k0 < kend; k0 += 32) {
    __syncthreads();
    gload_lds16(Ab + (size_t)(ca * 16) * K + k0, &Asm[ca * 512]);
    gload_lds16(Ab + (size_t)(cb * 16) * K + k0, &Asm[cb * 512]);
    gload_lds16(Bb + (size_t)(ca * 16) * K + k0, &Bsm[ca * 512]);
    gload_lds16(Bb + (size_t)(cb * 16) * K + k0, &Bsm[cb * 512]);
    __syncthreads();
    short8 af[4], bfr[4];
#pragma unroll
    for (int mt = 0; mt < 4; ++mt)
      af[mt] = *(const short8*)&Asm[(wr * 64 + mt * 16 + lr) * 32 + lg * 8];
#pragma unroll
    for (int nt = 0; nt < 4; ++nt)
      bfr[nt] = *(const short8*)&Bsm[(wc * 64 + nt * 16 + lr) * 32 + lg * 8];
#pragma unroll
    for (int mt = 0; mt < 4; ++mt)
#pragma unroll
      for (int nt = 0; nt < 4; ++nt)
        acc[mt][nt] = __builtin_amdgcn_mfma_f32_16x16x32_bf16(
            af[mt], bfr[nt], acc[mt][nt], 0, 0, 0);
  }

#pragma unroll
  for (int mt = 0; mt < 4; ++mt) {
#pragma unroll
    for (int nt = 0; nt < 4; ++nt) {
      const int col = n0 + wc * 64 + nt * 16 + lr;
      const int row0 = m0 + wr * 64 + mt * 16 + lg * 4;
      if constexpr (EPI == 0) {  // QKV: bias + scatter into q/k [BH][T][64],
                                 // v transposed [BH][64][T]
        const int sel = col >> 10, nn = col & 1023;
        const int hh = nn >> 6, dd = nn & 63;
        const int bb = row0 >> 10, tt0 = row0 & 1023;  // 4 rows same bb
        if (sel == 2) {
          const float bias = f2[nn];
          short4v pk = {f2bf(acc[mt][nt][0] + bias), f2bf(acc[mt][nt][1] + bias),
                        f2bf(acc[mt][nt][2] + bias), f2bf(acc[mt][nt][3] + bias)};
          *(short4v*)&s2[(((size_t)(bb * 16 + hh)) * 64 + dd) * 1024 + tt0] = pk;
        } else {
          const float bias = (sel == 0) ? f0[nn] : f1[nn];
          short* dst = (sel == 0) ? s0 : s1;
#pragma unroll
          for (int r = 0; r < 4; ++r)
            dst[(((size_t)(bb * 16 + hh)) * 1024 + tt0 + r) * 64 + dd] =
                f2bf(acc[mt][nt][r] + bias);
        }
      } else if constexpr (EPI == 1) {  // FFN1: bias + relu -> bf16
#pragma unroll
        for (int r = 0; r < 4; ++r) {
          float val = fmaxf(acc[mt][nt][r] + f0[col], 0.0f);
          s0[(size_t)(row0 + r) * 4096 + col] = f2bf(val);
        }
      } else {  // EPI == 2: split-K partial, raw f32
#pragma unroll
        for (int r = 0; r < 4; ++r)
          fo[(size_t)(row0 + r) * 1024 + col] = acc[mt][nt][r];
      }
    }
  }
}

__global__ __launch_bounds__(256) void gemm_qkv(
    const short* __restrict__ A, const short* __restrict__ B,
    const float* __restrict__ bq, const float* __restrict__ bk,
    const float* __restrict__ bv, short* __restrict__ q,
    short* __restrict__ k, short* __restrict__ vt) {
  gemm_body<0>(A, B, 1024, 0, 1024, blockIdx.y * 128, blockIdx.x * 128, bq, bk,
               bv, q, k, vt, nullptr);
}

__global__ __launch_bounds__(256) void gemm_ffn1(
    const short* __restrict__ A, const short* __restrict__ B,
    const float* __restrict__ b1f, short* __restrict__ u) {
  gemm_body<1>(A, B, 1024, 0, 1024, blockIdx.y * 128, blockIdx.x * 128, b1f,
               nullptr, nullptr, u, nullptr, nullptr, nullptr);
}

// split-K: z in [0,4), K-chunk of 1024 over K=4096; writes f32 partials.
__global__ __launch_bounds__(256) void gemm_ffn2sk(
    const short* __restrict__ A, const short* __restrict__ B,
    float* __restrict__ part) {
  const int z = blockIdx.z;
  gemm_body<2>(A, B, 4096, z * 1024, (z + 1) * 1024, blockIdx.y * 128,
               blockIdx.x * 128, nullptr, nullptr, nullptr, nullptr, nullptr,
               nullptr, part + (size_t)z * 4096 * 1024);
}

// out = sum_z part[z] + b2f + hf + x3   (all [4096][1024])
__global__ __launch_bounds__(256) void ffn2_reduce(
    const float* __restrict__ part, const float* __restrict__ b2f,
    const short* __restrict__ hfb, const float* __restrict__ x3,
    float* __restrict__ out) {
  const size_t i = (size_t)blockIdx.x * 256 + threadIdx.x;  // float4 index
  const size_t S = (size_t)4096 * 1024 / 4;
  float4 a0 = ((const float4*)part)[i];
  float4 a1 = ((const float4*)part)[i + S];
  float4 a2 = ((const float4*)part)[i + 2 * S];
  float4 a3 = ((const float4*)part)[i + 3 * S];
  float4 bb = ((const float4*)b2f)[i & 255];  // 1024 floats = 256 float4
  float4 xv = ((const float4*)x3)[i];
  short4v hv = ((const short4v*)hfb)[i];
  float4 o;
  o.x = a0.x + a1.x + a2.x + a3.x + bb.x + bf2f(hv.x) + xv.x;
  o.y = a0.y + a1.y + a2.y + a3.y + bb.y + bf2f(hv.y) + xv.y;
  o.z = a0.z + a1.z + a2.z + a3.z + bb.z + bf2f(hv.z) + xv.z;
  o.w = a0.w + a1.w + a2.w + a3.w + bb.w + bf2f(hv.w) + xv.w;
  ((float4*)out)[i] = o;
}

// ----------------------------- flash attention -----------------------------
__global__ __launch_bounds__(256) void attn_kernel(
    const short* __restrict__ q, const short* __restrict__ k,
    const short* __restrict__ vt, float* __restrict__ o) {
  __shared__ __align__(16) short Ksm[64 * 64];
  __shared__ __align__(16) short Vsm[64 * 64];
  __shared__ __align__(16) short Psm[4 * 16 * 64];
  const int bh = blockIdx.x, qt = blockIdx.y;
  const int tid = threadIdx.x, lane = tid & 63, w = tid >> 6;
  const int lr = lane & 15, lg = lane >> 4;

  const short* qb = q + (size_t)bh * 1024 * 64;
  const short* kb = k + (size_t)bh * 1024 * 64;
  const short* vb = vt + (size_t)bh * 64 * 1024;

  const int qrow = qt * 64 + w * 16 + lr;
  short8 qf0 = *(const short8*)&qb[(size_t)qrow * 64 + lg * 8];
  short8 qf1 = *(const short8*)&qb[(size_t)qrow * 64 + 32 + lg * 8];

  f32x4 oacc[4] = {};
  float mrun[4], lrun[4];
#pragma unroll
  for (int r = 0; r < 4; ++r) { mrun[r] = -1e30f; lrun[r] = 0.0f; }

  const float scale = 0.03125f;  // 1/sqrt(C)=1/32
  const int srow = tid >> 3;     // staging row (0..31), +32 on pass 2
  const int sc8 = tid & 7;       // 16B chunk within 128B row
  short* pw = Psm + w * 1024;    // per-wave 16x64 P tile

  for (int kt = 0; kt <= qt; ++kt) {
    __syncthreads();
#pragma unroll
    for (int p = 0; p < 2; ++p) {
      const int rr = srow + p * 32;
      short8 kv8 = *(const short8*)&kb[((size_t)(kt * 64 + rr)) * 64 + sc8 * 8];
      *(short8*)((char*)Ksm + rr * 128 + ((sc8 ^ (rr & 7)) << 4)) = kv8;
      short8 vv8 = *(const short8*)&vb[(size_t)rr * 1024 + kt * 64 + sc8 * 8];
      *(short8*)((char*)Vsm + rr * 128 + ((sc8 ^ (rr & 7)) << 4)) = vv8;
    }
    __syncthreads();

    f32x4 sfr[4];
#pragma unroll
    for (int nt = 0; nt < 4; ++nt) {
      const int krow = nt * 16 + lr;
      short8 kf0 = *(const short8*)((const char*)Ksm + krow * 128 +
                                    (((0 + lg) ^ (krow & 7)) << 4));
      short8 kf1 = *(const short8*)((const char*)Ksm + krow * 128 +
                                    (((4 + lg) ^ (krow & 7)) << 4));
      f32x4 z = {};
      z = __builtin_amdgcn_mfma_f32_16x16x32_bf16(qf0, kf0, z, 0, 0, 0);
      z = __builtin_amdgcn_mfma_f32_16x16x32_bf16(qf1, kf1, z, 0, 0, 0);
      sfr[nt] = z;
    }
    const int qg = qt * 64 + w * 16 + lg * 4;
    if (kt == qt) {
#pragma unroll
      for (int nt = 0; nt < 4; ++nt) {
        const int sg = kt * 64 + nt * 16 + lr;
#pragma unroll
        for (int r = 0; r < 4; ++r)
          sfr[nt][r] = (sg <= qg + r) ? sfr[nt][r] * scale : -1e30f;
      }
    } else {
#pragma unroll
      for (int nt = 0; nt < 4; ++nt)
#pragma unroll
        for (int r = 0; r < 4; ++r) sfr[nt][r] *= scale;
    }
    float pm[4];
#pragma unroll
    for (int r = 0; r < 4; ++r) {
      pm[r] = fmaxf(fmaxf(sfr[0][r], sfr[1][r]), fmaxf(sfr[2][r], sfr[3][r]));
#pragma unroll
      for (int off = 1; off < 16; off <<= 1)
        pm[r] = fmaxf(pm[r], __shfl_xor(pm[r], off, 64));
    }
    float alpha[4], rsum[4];
#pragma unroll
    for (int r = 0; r < 4; ++r) {
      const float mnew = fmaxf(mrun[r], pm[r]);
      alpha[r] = __expf(mrun[r] - mnew);
      mrun[r] = mnew;
      rsum[r] = 0.0f;
    }
#pragma unroll
    for (int nt = 0; nt < 4; ++nt)
#pragma unroll
      for (int r = 0; r < 4; ++r) {
        const float pv = __expf(sfr[nt][r] - mrun[r]);
        sfr[nt][r] = pv;
        rsum[r] += pv;
      }
#pragma unroll
    for (int r = 0; r < 4; ++r) {
#pragma unroll
      for (int off = 1; off < 16; off <<= 1)
        rsum[r] += __shfl_xor(rsum[r], off, 64);
      lrun[r] = lrun[r] * alpha[r] + rsum[r];
    }
#pragma unroll
    for (int nt = 0; nt < 4; ++nt)
#pragma unroll
      for (int r = 0; r < 4; ++r) oacc[nt][r] *= alpha[r];

#pragma unroll
    for (int nt = 0; nt < 4; ++nt)
#pragma unroll
      for (int r = 0; r < 4; ++r) {
        const int prow = lg * 4 + r, pcol = nt * 16 + lr;
        *(short*)((char*)pw + prow * 128 +
                  ((pcol * 2) ^ ((prow & 7) << 4))) = f2bf(sfr[nt][r]);
      }
    __syncthreads();

#pragma unroll
    for (int kc = 0; kc < 2; ++kc) {
      short8 pa = *(const short8*)((const char*)pw + lr * 128 +
                                   (((kc * 4 + lg) ^ (lr & 7)) << 4));
#pragma unroll
      for (int nt = 0; nt < 4; ++nt) {
        const int vrow = nt * 16 + lr;
        short8 vf = *(const short8*)((const char*)Vsm + vrow * 128 +
                                     (((kc * 4 + lg) ^ (vrow & 7)) << 4));
        oacc[nt] = __builtin_amdgcn_mfma_f32_16x16x32_bf16(pa, vf, oacc[nt], 0, 0, 0);
      }
    }
  }

  float* ob = o + (size_t)(bh >> 4) * 1024 * 1024 + (bh & 15) * 64;
#pragma unroll
  for (int nt = 0; nt < 4; ++nt)
#pragma unroll
    for (int r = 0; r < 4; ++r) {
      const int trow = qt * 64 + w * 16 + lg * 4 + r;
      ob[(size_t)trow * 1024 + nt * 16 + lr] = oacc[nt][r] / lrun[r];
    }
}

// ------------------------------- launcher ----------------------------------
extern "C" void kernel_launch(void* const* d_in, const int* in_sizes, int n_in,
                              void* d_out, int out_size, void* d_ws,
                              size_t ws_size, hipStream_t stream) {
  const float* x = (const float*)d_in[0];
  const float* Wq = (const float*)d_in[1];
  const float* bq = (const float*)d_in[2];
  const float* Wk = (const float*)d_in[3];
  const float* bk = (const float*)d_in[4];
  const float* Wv = (const float*)d_in[5];
  const float* bv = (const float*)d_in[6];
  const float* g1 = (const float*)d_in[7];
  const float* b1 = (const float*)d_in[8];
  const float* g2 = (const float*)d_in[9];
  const float* b2 = (const float*)d_in[10];
  const float* gf = (const float*)d_in[11];
  const float* bfp = (const float*)d_in[12];
  const float* W1 = (const float*)d_in[13];
  const float* b1f = (const float*)d_in[14];
  const float* W2 = (const float*)d_in[15];
  const float* b2f = (const float*)d_in[16];
  float* out = (float*)d_out;

  const size_t MB = 1024 * 1024;
  char* p = (char*)d_ws;
  // Region A (70MB): everything here is dead before gemm_ffn2sk runs; the
  // 64MB split-K partial buffer aliases it.
  float* hbuf = (float*)(p + 0 * MB);      // 16MB  h (f32), dead after ln2f
  short* qbuf = (short*)(p + 16 * MB);     // 8MB   dead after attn
  short* kbuf = (short*)(p + 24 * MB);     // 8MB   dead after attn
  short* vtb = (short*)(p + 32 * MB);      // 8MB   dead after attn
  float* obuf = (float*)(p + 40 * MB);     // 16MB  dead after ln2f
  short* wqkv_t = (short*)(p + 56 * MB);   // 6MB   dead after gemm_qkv
  short* w1_t = (short*)(p + 62 * MB);     // 8MB   dead after gemm_ffn1
  float* part = (float*)(p + 0 * MB);      // 64MB  alias of the above
  // Region B (72MB): live through the end.
  char* q = p + 70 * MB;
  short* w2_t = (short*)(q + 0 * MB);      // 8MB
  short* hbb = (short*)(q + 8 * MB);       // 8MB
  float* x3b = (float*)(q + 16 * MB);      // 16MB
  short* hfb = (short*)(q + 32 * MB);      // 8MB
  short* ub = (short*)(q + 40 * MB);       // 32MB

  dim3 tb(32, 8);
  transpose_to_bf16<<<dim3(2, 32, 16), tb, 0, stream>>>(Wq, wqkv_t, 1024, 64);
  transpose_to_bf16<<<dim3(2, 32, 16), tb, 0, stream>>>(Wk, wqkv_t + 1024 * 1024, 1024, 64);
  transpose_to_bf16<<<dim3(2, 32, 16), tb, 0, stream>>>(Wv, wqkv_t + 2 * 1024 * 1024, 1024, 64);
  transpose_to_bf16<<<dim3(128, 32, 1), tb, 0, stream>>>(W1, w1_t, 1024, 4096);
  transpose_to_bf16<<<dim3(32, 128, 1), tb, 0, stream>>>(W2, w2_t, 4096, 1024);

  ln1_kernel<<<4096, 256, 0, stream>>>(x, g1, b1, hbuf, hbb);

  gemm_qkv<<<dim3(24, 32), 256, 0, stream>>>(hbb, wqkv_t, bq, bk, bv, qbuf,
                                             kbuf, vtb);

  attn_kernel<<<dim3(64, 16), 256, 0, stream>>>(qbuf, kbuf, vtb, obuf);

  ln2f_kernel<<<4096, 256, 0, stream>>>(hbuf, obuf, g2, b2, gf, bfp, x3b, hfb);

  gemm_ffn1<<<dim3(32, 32), 256, 0, stream>>>(hfb, w1_t, b1f, ub);

  gemm_ffn2sk<<<dim3(8, 32, 4), 256, 0, stream>>>(ub, w2_t, part);

  ffn2_reduce<<<4096, 256, 0, stream>>>(part, b2f, hfb, x3b, out);
}

// Round 3
// 219.554 us; speedup vs baseline: 1.2798x; 1.2462x over previous
//
#include <hip/hip_runtime.h>
#include <hip/hip_bf16.h>

// ---------------------------------------------------------------------------
// Decoder block on MI355X. GEMMs use the 256x256 / BK=64 / 8-wave 8-phase
// counted-vmcnt schedule (guide §5 template, T2+T3+T4+T5), plain HIP.
// LDS layout per operand per K-half: [128 lines][128B], line j packs rows
// {2j,2j+1}; chunk c=((row&1)<<2)|kchunk stored at c^(j&7) (XOR swizzle,
// pre-swizzled on the GLOBAL source side since global_load_lds writes
// linearly). vmcnt ledger: stage order Ak0,Bk0,Ak1,Bk1 one half per phase;
// vmcnt(4) at end of phases 2 and 4 retires exactly the halves the next two
// phases read; 8 outstanding max; vmcnt(0) only mid-last-tile.
// ---------------------------------------------------------------------------

typedef __attribute__((ext_vector_type(8))) short short8;
typedef __attribute__((ext_vector_type(4))) short short4v;
typedef __attribute__((ext_vector_type(4))) float f32x4;

#define DEVI static __device__ __forceinline__

#define BAR() __builtin_amdgcn_s_barrier()
#define SB0() __builtin_amdgcn_sched_barrier(0)
#define LGKM0()                                         \
  {                                                     \
    asm volatile("s_waitcnt lgkmcnt(0)" ::: "memory");  \
    __builtin_amdgcn_sched_barrier(0);                  \
  }
#define VMW(n)                                              \
  {                                                         \
    asm volatile("s_waitcnt vmcnt(" #n ")" ::: "memory");   \
    __builtin_amdgcn_sched_barrier(0);                      \
  }

DEVI void gload_lds16(const void* g, void* l) {
  __builtin_amdgcn_global_load_lds(
      (const __attribute__((address_space(1))) void*)g,
      (__attribute__((address_space(3))) void*)l, 16, 0, 0);
}

DEVI float bf2f(short s) {
  union { float f; unsigned u; } cv;
  cv.u = ((unsigned)(unsigned short)s) << 16;
  return cv.f;
}
DEVI short f2bf(float f) {  // round-to-nearest-even
  union { float f; unsigned u; } cv;
  cv.f = f;
  unsigned u = cv.u;
  u += 0x7FFFu + ((u >> 16) & 1u);
  return (short)(u >> 16);
}

DEVI void block_reduce2(float& s, float& s2, float* red, int t) {
#pragma unroll
  for (int off = 1; off < 64; off <<= 1) {
    s += __shfl_xor(s, off, 64);
    s2 += __shfl_xor(s2, off, 64);
  }
  __syncthreads();
  if ((t & 63) == 0) { red[(t >> 6) * 2] = s; red[(t >> 6) * 2 + 1] = s2; }
  __syncthreads();
  s = red[0] + red[2] + red[4] + red[6];
  s2 = red[1] + red[3] + red[5] + red[7];
}

// --------------------------- transpose f32 -> bf16 -------------------------
__global__ __launch_bounds__(256) void transpose_to_bf16(
    const float* __restrict__ in, short* __restrict__ out, int R, int C) {
  __shared__ float tile[32][33];
  const int b = blockIdx.z;
  in += (size_t)b * R * C;
  out += (size_t)b * R * C;
  const int r0 = blockIdx.y * 32, c0 = blockIdx.x * 32;
  const int tx = threadIdx.x, ty = threadIdx.y;
#pragma unroll
  for (int i = 0; i < 32; i += 8)
    tile[ty + i][tx] = in[(size_t)(r0 + ty + i) * C + c0 + tx];
  __syncthreads();
#pragma unroll
  for (int i = 0; i < 32; i += 8)
    out[(size_t)(c0 + ty + i) * R + r0 + tx] = f2bf(tile[tx][ty + i]);
}

// ------------------------------- LayerNorms --------------------------------
__global__ __launch_bounds__(256) void ln1_kernel(
    const float* __restrict__ x, const float* __restrict__ g,
    const float* __restrict__ b, float* __restrict__ hf,
    short* __restrict__ hb) {
  __shared__ float red[8];
  const int row = blockIdx.x, t = threadIdx.x;
  float4 v = ((const float4*)(x + (size_t)row * 1024))[t];
  float s = v.x + v.y + v.z + v.w;
  float s2 = v.x * v.x + v.y * v.y + v.z * v.z + v.w * v.w;
  block_reduce2(s, s2, red, t);
  const float mu = s * (1.0f / 1024.0f);
  const float rstd = rsqrtf(s2 * (1.0f / 1024.0f) - mu * mu + 1e-5f);
  float4 gv = ((const float4*)g)[t], bv = ((const float4*)b)[t];
  float4 o;
  o.x = (v.x - mu) * rstd * gv.x + bv.x;
  o.y = (v.y - mu) * rstd * gv.y + bv.y;
  o.z = (v.z - mu) * rstd * gv.z + bv.z;
  o.w = (v.w - mu) * rstd * gv.w + bv.w;
  ((float4*)(hf + (size_t)row * 1024))[t] = o;
  short4v p = {f2bf(o.x), f2bf(o.y), f2bf(o.z), f2bf(o.w)};
  ((short4v*)(hb + (size_t)row * 1024))[t] = p;
}

__global__ __launch_bounds__(256) void ln2f_kernel(
    const float* __restrict__ h, const float* __restrict__ o,
    const float* __restrict__ g2, const float* __restrict__ b2,
    const float* __restrict__ gf, const float* __restrict__ bfp,
    float* __restrict__ x3, short* __restrict__ hfb) {
  __shared__ float red[8];
  const int row = blockIdx.x, t = threadIdx.x;
  float4 hv = ((const float4*)(h + (size_t)row * 1024))[t];
  float4 ov = ((const float4*)(o + (size_t)row * 1024))[t];
  float4 v;
  v.x = hv.x + ov.x; v.y = hv.y + ov.y; v.z = hv.z + ov.z; v.w = hv.w + ov.w;
  float s = v.x + v.y + v.z + v.w;
  float s2 = v.x * v.x + v.y * v.y + v.z * v.z + v.w * v.w;
  block_reduce2(s, s2, red, t);
  float mu = s * (1.0f / 1024.0f);
  float rstd = rsqrtf(s2 * (1.0f / 1024.0f) - mu * mu + 1e-5f);
  float4 gv = ((const float4*)g2)[t], bv = ((const float4*)b2)[t];
  float4 xv;
  xv.x = (v.x - mu) * rstd * gv.x + bv.x;
  xv.y = (v.y - mu) * rstd * gv.y + bv.y;
  xv.z = (v.z - mu) * rstd * gv.z + bv.z;
  xv.w = (v.w - mu) * rstd * gv.w + bv.w;
  ((float4*)(x3 + (size_t)row * 1024))[t] = xv;
  s = xv.x + xv.y + xv.z + xv.w;
  s2 = xv.x * xv.x + xv.y * xv.y + xv.z * xv.z + xv.w * xv.w;
  block_reduce2(s, s2, red, t);
  mu = s * (1.0f / 1024.0f);
  rstd = rsqrtf(s2 * (1.0f / 1024.0f) - mu * mu + 1e-5f);
  float4 gv2 = ((const float4*)gf)[t], bv2 = ((const float4*)bfp)[t];
  short4v pk = {f2bf((xv.x - mu) * rstd * gv2.x + bv2.x),
                f2bf((xv.y - mu) * rstd * gv2.y + bv2.y),
                f2bf((xv.z - mu) * rstd * gv2.z + bv2.z),
                f2bf((xv.w - mu) * rstd * gv2.w + bv2.w)};
  ((short4v*)(hfb + (size_t)row * 1024))[t] = pk;
}

// --------------------- 256x256 8-phase GEMM core ---------------------------
// C[M][N] = A[M][K] * B^T[N][K], bf16, f32 acc. BM=BN=256, BK=64, 8 waves
// (2M x 4N), 512 threads. K-slice = [kbase, kbase + 16*64).
template <int EPI>
DEVI void gemm8_body(const short* __restrict__ A, const short* __restrict__ B,
                     int K, int kbase, int m0, int n0,
                     const float* __restrict__ f0, const float* __restrict__ f1,
                     const float* __restrict__ f2, short* __restrict__ s0,
                     short* __restrict__ s1, short* __restrict__ s2,
                     float* __restrict__ fo) {
  extern __shared__ __align__(16) char lds[];  // 131072 B
  constexpr int NT = 16;
  const int tid = threadIdx.x;
  const int l = tid & 63, w = tid >> 6;
  const int wrM = w >> 2, wcN = w & 3;
  const int lr = l & 15, lg = l >> 4;

  // read-side per-lane byte offset within an [128 lines][128B] K-half block
  const int cswz = (((lr & 1) << 2) | lg) ^ (lr >> 1);
  const int laneoff = ((lr >> 1) << 7) + (cswz << 4);

  // stage-side: lane l writes LDS byte w*1024 + i*8192 + l*16; pre-swizzle
  // the global source so LDS slot (line j, chunk c') holds logical chunk
  // c = c' ^ (j&7).
  const int rsel = l >> 3;
  const int scz = (l & 7) ^ rsel;
  const int s_roff = w * 16 + rsel * 2 + (scz >> 2);
  const int s_kc = (scz & 3) * 8;
  const short* Asrc = A + (size_t)(m0 + s_roff) * K + kbase + s_kc;
  const short* Bsrc = B + (size_t)(n0 + s_roff) * K + kbase + s_kc;
  const size_t rstep = (size_t)128 * K;

  auto STAGE = [&](int op, int kh, int t) {
    const short* g = (op ? Bsrc : Asrc) + t * 64 + kh * 32;
    char* d = lds + ((t & 1) * 65536 + op * 32768 + kh * 16384 + w * 1024);
    gload_lds16(g, d);
    gload_lds16(g + rstep, d + 8192);
  };

  f32x4 acc[8][4] = {};

  // prologue: tile 0, all 4 halves; vmcnt(4) leaves Ak1,Bk1 in flight
  STAGE(0, 0, 0); STAGE(1, 0, 0); STAGE(0, 1, 0); STAGE(1, 1, 0);
  VMW(4); BAR(); SB0();

  for (int t = 0; t < NT; ++t) {
    const char* pa = lds + (t & 1) * 65536 + wrM * 8192 + laneoff;
    const char* pb = lds + (t & 1) * 65536 + 32768 + wcN * 4096 + laneoff;
    const bool st = (t + 1) < NT;
    short8 a[8], b[4];

    // ---- phase 1 (kk=0): A frags + B n0,n1 ----
#pragma unroll
    for (int mt = 0; mt < 8; ++mt) a[mt] = *(const short8*)(pa + mt * 1024);
    b[0] = *(const short8*)(pb);
    b[1] = *(const short8*)(pb + 1024);
    if (st) STAGE(0, 0, t + 1);
    BAR(); LGKM0();
    __builtin_amdgcn_s_setprio(1);
#pragma unroll
    for (int mt = 0; mt < 8; ++mt) {
      acc[mt][0] = __builtin_amdgcn_mfma_f32_16x16x32_bf16(a[mt], b[0], acc[mt][0], 0, 0, 0);
      acc[mt][1] = __builtin_amdgcn_mfma_f32_16x16x32_bf16(a[mt], b[1], acc[mt][1], 0, 0, 0);
    }
    __builtin_amdgcn_s_setprio(0);
    BAR(); SB0();

    // ---- phase 2 (kk=0): B n2,n3 ----
    b[2] = *(const short8*)(pb + 2048);
    b[3] = *(const short8*)(pb + 3072);
    if (st) STAGE(1, 0, t + 1);
    BAR(); LGKM0();
    __builtin_amdgcn_s_setprio(1);
#pragma unroll
    for (int mt = 0; mt < 8; ++mt) {
      acc[mt][2] = __builtin_amdgcn_mfma_f32_16x16x32_bf16(a[mt], b[2], acc[mt][2], 0, 0, 0);
      acc[mt][3] = __builtin_amdgcn_mfma_f32_16x16x32_bf16(a[mt], b[3], acc[mt][3], 0, 0, 0);
    }
    __builtin_amdgcn_s_setprio(0);
    if (st) { VMW(4); } else { VMW(0); }   // retire Ak1,Bk1 of tile t
    BAR(); SB0();

    // ---- phase 3 (kk=1): A frags + B n0,n1 ----
    pa += 16384; pb += 16384;
#pragma unroll
    for (int mt = 0; mt < 8; ++mt) a[mt] = *(const short8*)(pa + mt * 1024);
    b[0] = *(const short8*)(pb);
    b[1] = *(const short8*)(pb + 1024);
    if (st) STAGE(0, 1, t + 1);
    BAR(); LGKM0();
    __builtin_amdgcn_s_setprio(1);
#pragma unroll
    for (int mt = 0; mt < 8; ++mt) {
      acc[mt][0] = __builtin_amdgcn_mfma_f32_16x16x32_bf16(a[mt], b[0], acc[mt][0], 0, 0, 0);
      acc[mt][1] = __builtin_amdgcn_mfma_f32_16x16x32_bf16(a[mt], b[1], acc[mt][1], 0, 0, 0);
    }
    __builtin_amdgcn_s_setprio(0);
    BAR(); SB0();

    // ---- phase 4 (kk=1): B n2,n3 ----
    b[2] = *(const short8*)(pb + 2048);
    b[3] = *(const short8*)(pb + 3072);
    if (st) STAGE(1, 1, t + 1);
    BAR(); LGKM0();
    __builtin_amdgcn_s_setprio(1);
#pragma unroll
    for (int mt = 0; mt < 8; ++mt) {
      acc[mt][2] = __builtin_amdgcn_mfma_f32_16x16x32_bf16(a[mt], b[2], acc[mt][2], 0, 0, 0);
      acc[mt][3] = __builtin_amdgcn_mfma_f32_16x16x32_bf16(a[mt], b[3], acc[mt][3], 0, 0, 0);
    }
    __builtin_amdgcn_s_setprio(0);
    if (st) VMW(4);   // retire Ak0,Bk0 of tile t+1
    BAR(); SB0();
  }

  // --------------------------- epilogue ---------------------------
#pragma unroll
  for (int mt = 0; mt < 8; ++mt) {
#pragma unroll
    for (int nt = 0; nt < 4; ++nt) {
      const int col = n0 + wcN * 64 + nt * 16 + lr;
      const int row0 = m0 + wrM * 128 + mt * 16 + lg * 4;
      if constexpr (EPI == 0) {  // QKV scatter
        const int sel = col >> 10, nn = col & 1023;
        const int hh = nn >> 6, dd = nn & 63;
        const int bb = row0 >> 10, tt0 = row0 & 1023;
        if (sel == 2) {
          const float bias = f2[nn];
          short4v pk = {f2bf(acc[mt][nt][0] + bias), f2bf(acc[mt][nt][1] + bias),
                        f2bf(acc[mt][nt][2] + bias), f2bf(acc[mt][nt][3] + bias)};
          *(short4v*)&s2[(((size_t)(bb * 16 + hh)) * 64 + dd) * 1024 + tt0] = pk;
        } else {
          const float bias = (sel == 0) ? f0[nn] : f1[nn];
          short* dst = (sel == 0) ? s0 : s1;
#pragma unroll
          for (int r = 0; r < 4; ++r)
            dst[(((size_t)(bb * 16 + hh)) * 1024 + tt0 + r) * 64 + dd] =
                f2bf(acc[mt][nt][r] + bias);
        }
      } else if constexpr (EPI == 1) {  // FFN1 bias+relu -> bf16
#pragma unroll
        for (int r = 0; r < 4; ++r) {
          float val = fmaxf(acc[mt][nt][r] + f0[col], 0.0f);
          s0[(size_t)(row0 + r) * 4096 + col] = f2bf(val);
        }
      } else {  // split-K partials f32
#pragma unroll
        for (int r = 0; r < 4; ++r)
          fo[(size_t)(row0 + r) * 1024 + col] = acc[mt][nt][r];
      }
    }
  }
}

__global__ __launch_bounds__(512, 2) void gemm8_qkv(
    const short* __restrict__ A, const short* __restrict__ B,
    const float* __restrict__ bq, const float* __restrict__ bk,
    const float* __restrict__ bv, short* __restrict__ q,
    short* __restrict__ k, short* __restrict__ vt) {
  gemm8_body<0>(A, B, 1024, 0, blockIdx.y * 256, blockIdx.x * 256, bq, bk, bv,
                q, k, vt, nullptr);
}

__global__ __launch_bounds__(512, 2) void gemm8_ffn1(
    const short* __restrict__ A, const short* __restrict__ B,
    const float* __restrict__ b1f, short* __restrict__ u) {
  gemm8_body<1>(A, B, 1024, 0, blockIdx.y * 256, blockIdx.x * 256, b1f,
                nullptr, nullptr, u, nullptr, nullptr, nullptr);
}

__global__ __launch_bounds__(512, 2) void gemm8_ffn2sk(
    const short* __restrict__ A, const short* __restrict__ B,
    float* __restrict__ part) {
  const int z = blockIdx.z;
  gemm8_body<2>(A, B, 4096, z * 1024, blockIdx.y * 256, blockIdx.x * 256,
                nullptr, nullptr, nullptr, nullptr, nullptr, nullptr,
                part + (size_t)z * 4096 * 1024);
}

// out = sum_z part[z] + b2f + hf + x3
__global__ __launch_bounds__(256) void ffn2_reduce(
    const float* __restrict__ part, const float* __restrict__ b2f,
    const short* __restrict__ hfb, const float* __restrict__ x3,
    float* __restrict__ out) {
  const size_t i = (size_t)blockIdx.x * 256 + threadIdx.x;
  const size_t S = (size_t)4096 * 1024 / 4;
  float4 a0 = ((const float4*)part)[i];
  float4 a1 = ((const float4*)part)[i + S];
  float4 a2 = ((const float4*)part)[i + 2 * S];
  float4 a3 = ((const float4*)part)[i + 3 * S];
  float4 bb = ((const float4*)b2f)[i & 255];
  float4 xv = ((const float4*)x3)[i];
  short4v hv = ((const short4v*)hfb)[i];
  float4 o;
  o.x = a0.x + a1.x + a2.x + a3.x + bb.x + bf2f(hv.x) + xv.x;
  o.y = a0.y + a1.y + a2.y + a3.y + bb.y + bf2f(hv.y) + xv.y;
  o.z = a0.z + a1.z + a2.z + a3.z + bb.z + bf2f(hv.z) + xv.z;
  o.w = a0.w + a1.w + a2.w + a3.w + bb.w + bf2f(hv.w) + xv.w;
  ((float4*)out)[i] = o;
}

// ----------------------------- flash attention -----------------------------
__global__ __launch_bounds__(256) void attn_kernel(
    const short* __restrict__ q, const short* __restrict__ k,
    const short* __restrict__ vt, float* __restrict__ o) {
  __shared__ __align__(16) short Ksm[64 * 64];
  __shared__ __align__(16) short Vsm[64 * 64];
  __shared__ __align__(16) short Psm[4 * 16 * 64];
  const int bh = blockIdx.x, qt = blockIdx.y;
  const int tid = threadIdx.x, lane = tid & 63, w = tid >> 6;
  const int lr = lane & 15, lg = lane >> 4;

  const short* qb = q + (size_t)bh * 1024 * 64;
  const short* kb = k + (size_t)bh * 1024 * 64;
  const short* vb = vt + (size_t)bh * 64 * 1024;

  const int qrow = qt * 64 + w * 16 + lr;
  short8 qf0 = *(const short8*)&qb[(size_t)qrow * 64 + lg * 8];
  short8 qf1 = *(const short8*)&qb[(size_t)qrow * 64 + 32 + lg * 8];

  f32x4 oacc[4] = {};
  float mrun[4], lrun[4];
#pragma unroll
  for (int r = 0; r < 4; ++r) { mrun[r] = -1e30f; lrun[r] = 0.0f; }

  const float scale = 0.03125f;  // 1/sqrt(C)=1/32
  const int srow = tid >> 3;
  const int sc8 = tid & 7;
  short* pw = Psm + w * 1024;

  for (int kt = 0; kt <= qt; ++kt) {
    __syncthreads();
#pragma unroll
    for (int p = 0; p < 2; ++p) {
      const int rr = srow + p * 32;
      short8 kv8 = *(const short8*)&kb[((size_t)(kt * 64 + rr)) * 64 + sc8 * 8];
      *(short8*)((char*)Ksm + rr * 128 + ((sc8 ^ (rr & 7)) << 4)) = kv8;
      short8 vv8 = *(const short8*)&vb[(size_t)rr * 1024 + kt * 64 + sc8 * 8];
      *(short8*)((char*)Vsm + rr * 128 + ((sc8 ^ (rr & 7)) << 4)) = vv8;
    }
    __syncthreads();

    f32x4 sfr[4];
#pragma unroll
    for (int nt = 0; nt < 4; ++nt) {
      const int krow = nt * 16 + lr;
      short8 kf0 = *(const short8*)((const char*)Ksm + krow * 128 +
                                    (((0 + lg) ^ (krow & 7)) << 4));
      short8 kf1 = *(const short8*)((const char*)Ksm + krow * 128 +
                                    (((4 + lg) ^ (krow & 7)) << 4));
      f32x4 z = {};
      z = __builtin_amdgcn_mfma_f32_16x16x32_bf16(qf0, kf0, z, 0, 0, 0);
      z = __builtin_amdgcn_mfma_f32_16x16x32_bf16(qf1, kf1, z, 0, 0, 0);
      sfr[nt] = z;
    }
    const int qg = qt * 64 + w * 16 + lg * 4;
    if (kt == qt) {
#pragma unroll
      for (int nt = 0; nt < 4; ++nt) {
        const int sg = kt * 64 + nt * 16 + lr;
#pragma unroll
        for (int r = 0; r < 4; ++r)
          sfr[nt][r] = (sg <= qg + r) ? sfr[nt][r] * scale : -1e30f;
      }
    } else {
#pragma unroll
      for (int nt = 0; nt < 4; ++nt)
#pragma unroll
        for (int r = 0; r < 4; ++r) sfr[nt][r] *= scale;
    }
    float pm[4];
#pragma unroll
    for (int r = 0; r < 4; ++r) {
      pm[r] = fmaxf(fmaxf(sfr[0][r], sfr[1][r]), fmaxf(sfr[2][r], sfr[3][r]));
#pragma unroll
      for (int off = 1; off < 16; off <<= 1)
        pm[r] = fmaxf(pm[r], __shfl_xor(pm[r], off, 64));
    }
    float alpha[4], rsum[4];
#pragma unroll
    for (int r = 0; r < 4; ++r) {
      const float mnew = fmaxf(mrun[r], pm[r]);
      alpha[r] = __expf(mrun[r] - mnew);
      mrun[r] = mnew;
      rsum[r] = 0.0f;
    }
#pragma unroll
    for (int nt = 0; nt < 4; ++nt)
#pragma unroll
      for (int r = 0; r < 4; ++r) {
        const float pv = __expf(sfr[nt][r] - mrun[r]);
        sfr[nt][r] = pv;
        rsum[r] += pv;
      }
#pragma unroll
    for (int r = 0; r < 4; ++r) {
#pragma unroll
      for (int off = 1; off < 16; off <<= 1)
        rsum[r] += __shfl_xor(rsum[r], off, 64);
      lrun[r] = lrun[r] * alpha[r] + rsum[r];
    }
#pragma unroll
    for (int nt = 0; nt < 4; ++nt)
#pragma unroll
      for (int r = 0; r < 4; ++r) oacc[nt][r] *= alpha[r];

#pragma unroll
    for (int nt = 0; nt < 4; ++nt)
#pragma unroll
      for (int r = 0; r < 4; ++r) {
        const int prow = lg * 4 + r, pcol = nt * 16 + lr;
        *(short*)((char*)pw + prow * 128 +
                  ((pcol * 2) ^ ((prow & 7) << 4))) = f2bf(sfr[nt][r]);
      }
    __syncthreads();

#pragma unroll
    for (int kc = 0; kc < 2; ++kc) {
      short8 pa = *(const short8*)((const char*)pw + lr * 128 +
                                   (((kc * 4 + lg) ^ (lr & 7)) << 4));
#pragma unroll
      for (int nt = 0; nt < 4; ++nt) {
        const int vrow = nt * 16 + lr;
        short8 vf = *(const short8*)((const char*)Vsm + vrow * 128 +
                                     (((kc * 4 + lg) ^ (vrow & 7)) << 4));
        oacc[nt] = __builtin_amdgcn_mfma_f32_16x16x32_bf16(pa, vf, oacc[nt], 0, 0, 0);
      }
    }
  }

  float* ob = o + (size_t)(bh >> 4) * 1024 * 1024 + (bh & 15) * 64;
#pragma unroll
  for (int nt = 0; nt < 4; ++nt)
#pragma unroll
    for (int r = 0; r < 4; ++r) {
      const int trow = qt * 64 + w * 16 + lg * 4 + r;
      ob[(size_t)trow * 1024 + nt * 16 + lr] = oacc[nt][r] / lrun[r];
    }
}

// ------------------------------- launcher ----------------------------------
extern "C" void kernel_launch(void* const* d_in, const int* in_sizes, int n_in,
                              void* d_out, int out_size, void* d_ws,
                              size_t ws_size, hipStream_t stream) {
  const float* x = (const float*)d_in[0];
  const float* Wq = (const float*)d_in[1];
  const float* bq = (const float*)d_in[2];
  const float* Wk = (const float*)d_in[3];
  const float* bk = (const float*)d_in[4];
  const float* Wv = (const float*)d_in[5];
  const float* bv = (const float*)d_in[6];
  const float* g1 = (const float*)d_in[7];
  const float* b1 = (const float*)d_in[8];
  const float* g2 = (const float*)d_in[9];
  const float* b2 = (const float*)d_in[10];
  const float* gf = (const float*)d_in[11];
  const float* bfp = (const float*)d_in[12];
  const float* W1 = (const float*)d_in[13];
  const float* b1f = (const float*)d_in[14];
  const float* W2 = (const float*)d_in[15];
  const float* b2f = (const float*)d_in[16];
  float* out = (float*)d_out;

  // allow 128KB dynamic LDS for the 8-phase GEMMs (idempotent, host-side)
  hipFuncSetAttribute((const void*)gemm8_qkv,
                      hipFuncAttributeMaxDynamicSharedMemorySize, 131072);
  hipFuncSetAttribute((const void*)gemm8_ffn1,
                      hipFuncAttributeMaxDynamicSharedMemorySize, 131072);
  hipFuncSetAttribute((const void*)gemm8_ffn2sk,
                      hipFuncAttributeMaxDynamicSharedMemorySize, 131072);

  const size_t MB = 1024 * 1024;
  char* p = (char*)d_ws;
  // Region A (70MB): dead before gemm8_ffn2sk; 64MB split-K partials alias it.
  float* hbuf = (float*)(p + 0 * MB);      // 16MB  h (f32), dead after ln2f
  short* qbuf = (short*)(p + 16 * MB);     // 8MB   dead after attn
  short* kbuf = (short*)(p + 24 * MB);     // 8MB   dead after attn
  short* vtb = (short*)(p + 32 * MB);      // 8MB   dead after attn
  float* obuf = (float*)(p + 40 * MB);     // 16MB  dead after ln2f
  short* wqkv_t = (short*)(p + 56 * MB);   // 6MB   dead after gemm8_qkv
  short* w1_t = (short*)(p + 62 * MB);     // 8MB   dead after gemm8_ffn1
  float* part = (float*)(p + 0 * MB);      // 64MB  alias
  // Region B (72MB): live through the end.
  char* q = p + 70 * MB;
  short* w2_t = (short*)(q + 0 * MB);      // 8MB
  short* hbb = (short*)(q + 8 * MB);       // 8MB
  float* x3b = (float*)(q + 16 * MB);      // 16MB
  short* hfb = (short*)(q + 32 * MB);      // 8MB
  short* ub = (short*)(q + 40 * MB);       // 32MB

  dim3 tb(32, 8);
  transpose_to_bf16<<<dim3(2, 32, 16), tb, 0, stream>>>(Wq, wqkv_t, 1024, 64);
  transpose_to_bf16<<<dim3(2, 32, 16), tb, 0, stream>>>(Wk, wqkv_t + 1024 * 1024, 1024, 64);
  transpose_to_bf16<<<dim3(2, 32, 16), tb, 0, stream>>>(Wv, wqkv_t + 2 * 1024 * 1024, 1024, 64);
  transpose_to_bf16<<<dim3(128, 32, 1), tb, 0, stream>>>(W1, w1_t, 1024, 4096);
  transpose_to_bf16<<<dim3(32, 128, 1), tb, 0, stream>>>(W2, w2_t, 4096, 1024);

  ln1_kernel<<<4096, 256, 0, stream>>>(x, g1, b1, hbuf, hbb);

  gemm8_qkv<<<dim3(12, 16), 512, 131072, stream>>>(hbb, wqkv_t, bq, bk, bv,
                                                   qbuf, kbuf, vtb);

  attn_kernel<<<dim3(64, 16), 256, 0, stream>>>(qbuf, kbuf, vtb, obuf);

  ln2f_kernel<<<4096, 256, 0, stream>>>(hbuf, obuf, g2, b2, gf, bfp, x3b, hfb);

  gemm8_ffn1<<<dim3(16, 16), 512, 131072, stream>>>(hfb, w1_t, b1f, ub);

  gemm8_ffn2sk<<<dim3(4, 16, 4), 512, 131072, stream>>>(ub, w2_t, part);

  ffn2_reduce<<<4096, 256, 0, stream>>>(part, b2f, hfb, x3b, out);
}

// Round 4
// 217.191 us; speedup vs baseline: 1.2937x; 1.0109x over previous
//
#include <hip/hip_runtime.h>
#include <hip/hip_bf16.h>

// ---------------------------------------------------------------------------
// Decoder block on MI355X. GEMMs: 256x256 / BK=64 / 8-wave 8-phase
// counted-vmcnt schedule (guide §5 template, T2+T3+T4+T5), plain HIP.
// Attention: flash-style, double-buffered K/V LDS with async-stage split
// (T14) -> ONE barrier per KV tile; per-wave P transpose needs no barrier
// (same-wave DS ordering); softmax in exp2 domain.
// ---------------------------------------------------------------------------

typedef __attribute__((ext_vector_type(8))) short short8;
typedef __attribute__((ext_vector_type(4))) short short4v;
typedef __attribute__((ext_vector_type(4))) float f32x4;

#define DEVI static __device__ __forceinline__

#define BAR() __builtin_amdgcn_s_barrier()
#define SB0() __builtin_amdgcn_sched_barrier(0)
#define LGKM0()                                         \
  {                                                     \
    asm volatile("s_waitcnt lgkmcnt(0)" ::: "memory");  \
    __builtin_amdgcn_sched_barrier(0);                  \
  }
#define VMW(n)                                              \
  {                                                         \
    asm volatile("s_waitcnt vmcnt(" #n ")" ::: "memory");   \
    __builtin_amdgcn_sched_barrier(0);                      \
  }

DEVI void gload_lds16(const void* g, void* l) {
  __builtin_amdgcn_global_load_lds(
      (const __attribute__((address_space(1))) void*)g,
      (__attribute__((address_space(3))) void*)l, 16, 0, 0);
}

DEVI float bf2f(short s) {
  union { float f; unsigned u; } cv;
  cv.u = ((unsigned)(unsigned short)s) << 16;
  return cv.f;
}
DEVI short f2bf(float f) {  // round-to-nearest-even
  union { float f; unsigned u; } cv;
  cv.f = f;
  unsigned u = cv.u;
  u += 0x7FFFu + ((u >> 16) & 1u);
  return (short)(u >> 16);
}

DEVI void block_reduce2(float& s, float& s2, float* red, int t) {
#pragma unroll
  for (int off = 1; off < 64; off <<= 1) {
    s += __shfl_xor(s, off, 64);
    s2 += __shfl_xor(s2, off, 64);
  }
  __syncthreads();
  if ((t & 63) == 0) { red[(t >> 6) * 2] = s; red[(t >> 6) * 2 + 1] = s2; }
  __syncthreads();
  s = red[0] + red[2] + red[4] + red[6];
  s2 = red[1] + red[3] + red[5] + red[7];
}

// --------------------------- transpose f32 -> bf16 -------------------------
__global__ __launch_bounds__(256) void transpose_to_bf16(
    const float* __restrict__ in, short* __restrict__ out, int R, int C) {
  __shared__ float tile[32][33];
  const int b = blockIdx.z;
  in += (size_t)b * R * C;
  out += (size_t)b * R * C;
  const int r0 = blockIdx.y * 32, c0 = blockIdx.x * 32;
  const int tx = threadIdx.x, ty = threadIdx.y;
#pragma unroll
  for (int i = 0; i < 32; i += 8)
    tile[ty + i][tx] = in[(size_t)(r0 + ty + i) * C + c0 + tx];
  __syncthreads();
#pragma unroll
  for (int i = 0; i < 32; i += 8)
    out[(size_t)(c0 + ty + i) * R + r0 + tx] = f2bf(tile[tx][ty + i]);
}

// Wq/Wk/Wv merged: each [16][1024][64] -> wqkv_t [3][16][64][1024]
__global__ __launch_bounds__(256) void transpose_qkv(
    const float* __restrict__ Wq, const float* __restrict__ Wk,
    const float* __restrict__ Wv, short* __restrict__ out) {
  __shared__ float tile[32][33];
  const int z = blockIdx.z;  // 0..47
  const int sel = z >> 4, b = z & 15;
  const float* in = (sel == 0) ? Wq : (sel == 1) ? Wk : Wv;
  in += (size_t)b * 1024 * 64;
  short* o = out + (size_t)sel * 1024 * 1024 + (size_t)b * 1024 * 64;
  const int r0 = blockIdx.y * 32, c0 = blockIdx.x * 32;
  const int tx = threadIdx.x, ty = threadIdx.y;
#pragma unroll
  for (int i = 0; i < 32; i += 8)
    tile[ty + i][tx] = in[(size_t)(r0 + ty + i) * 64 + c0 + tx];
  __syncthreads();
#pragma unroll
  for (int i = 0; i < 32; i += 8)
    o[(size_t)(c0 + ty + i) * 1024 + r0 + tx] = f2bf(tile[tx][ty + i]);
}

// ------------------------------- LayerNorms --------------------------------
__global__ __launch_bounds__(256) void ln1_kernel(
    const float* __restrict__ x, const float* __restrict__ g,
    const float* __restrict__ b, float* __restrict__ hf,
    short* __restrict__ hb) {
  __shared__ float red[8];
  const int row = blockIdx.x, t = threadIdx.x;
  float4 v = ((const float4*)(x + (size_t)row * 1024))[t];
  float s = v.x + v.y + v.z + v.w;
  float s2 = v.x * v.x + v.y * v.y + v.z * v.z + v.w * v.w;
  block_reduce2(s, s2, red, t);
  const float mu = s * (1.0f / 1024.0f);
  const float rstd = rsqrtf(s2 * (1.0f / 1024.0f) - mu * mu + 1e-5f);
  float4 gv = ((const float4*)g)[t], bv = ((const float4*)b)[t];
  float4 o;
  o.x = (v.x - mu) * rstd * gv.x + bv.x;
  o.y = (v.y - mu) * rstd * gv.y + bv.y;
  o.z = (v.z - mu) * rstd * gv.z + bv.z;
  o.w = (v.w - mu) * rstd * gv.w + bv.w;
  ((float4*)(hf + (size_t)row * 1024))[t] = o;
  short4v p = {f2bf(o.x), f2bf(o.y), f2bf(o.z), f2bf(o.w)};
  ((short4v*)(hb + (size_t)row * 1024))[t] = p;
}

__global__ __launch_bounds__(256) void ln2f_kernel(
    const float* __restrict__ h, const float* __restrict__ o,
    const float* __restrict__ g2, const float* __restrict__ b2,
    const float* __restrict__ gf, const float* __restrict__ bfp,
    float* __restrict__ x3, short* __restrict__ hfb) {
  __shared__ float red[8];
  const int row = blockIdx.x, t = threadIdx.x;
  float4 hv = ((const float4*)(h + (size_t)row * 1024))[t];
  float4 ov = ((const float4*)(o + (size_t)row * 1024))[t];
  float4 v;
  v.x = hv.x + ov.x; v.y = hv.y + ov.y; v.z = hv.z + ov.z; v.w = hv.w + ov.w;
  float s = v.x + v.y + v.z + v.w;
  float s2 = v.x * v.x + v.y * v.y + v.z * v.z + v.w * v.w;
  block_reduce2(s, s2, red, t);
  float mu = s * (1.0f / 1024.0f);
  float rstd = rsqrtf(s2 * (1.0f / 1024.0f) - mu * mu + 1e-5f);
  float4 gv = ((const float4*)g2)[t], bv = ((const float4*)b2)[t];
  float4 xv;
  xv.x = (v.x - mu) * rstd * gv.x + bv.x;
  xv.y = (v.y - mu) * rstd * gv.y + bv.y;
  xv.z = (v.z - mu) * rstd * gv.z + bv.z;
  xv.w = (v.w - mu) * rstd * gv.w + bv.w;
  ((float4*)(x3 + (size_t)row * 1024))[t] = xv;
  s = xv.x + xv.y + xv.z + xv.w;
  s2 = xv.x * xv.x + xv.y * xv.y + xv.z * xv.z + xv.w * xv.w;
  block_reduce2(s, s2, red, t);
  mu = s * (1.0f / 1024.0f);
  rstd = rsqrtf(s2 * (1.0f / 1024.0f) - mu * mu + 1e-5f);
  float4 gv2 = ((const float4*)gf)[t], bv2 = ((const float4*)bfp)[t];
  short4v pk = {f2bf((xv.x - mu) * rstd * gv2.x + bv2.x),
                f2bf((xv.y - mu) * rstd * gv2.y + bv2.y),
                f2bf((xv.z - mu) * rstd * gv2.z + bv2.z),
                f2bf((xv.w - mu) * rstd * gv2.w + bv2.w)};
  ((short4v*)(hfb + (size_t)row * 1024))[t] = pk;
}

// --------------------- 256x256 8-phase GEMM core ---------------------------
template <int EPI>
DEVI void gemm8_body(const short* __restrict__ A, const short* __restrict__ B,
                     int K, int kbase, int m0, int n0,
                     const float* __restrict__ f0, const float* __restrict__ f1,
                     const float* __restrict__ f2, short* __restrict__ s0,
                     short* __restrict__ s1, short* __restrict__ s2,
                     float* __restrict__ fo) {
  extern __shared__ __align__(16) char lds[];  // 131072 B
  constexpr int NT = 16;
  const int tid = threadIdx.x;
  const int l = tid & 63, w = tid >> 6;
  const int wrM = w >> 2, wcN = w & 3;
  const int lr = l & 15, lg = l >> 4;

  const int cswz = (((lr & 1) << 2) | lg) ^ (lr >> 1);
  const int laneoff = ((lr >> 1) << 7) + (cswz << 4);

  const int rsel = l >> 3;
  const int scz = (l & 7) ^ rsel;
  const int s_roff = w * 16 + rsel * 2 + (scz >> 2);
  const int s_kc = (scz & 3) * 8;
  const short* Asrc = A + (size_t)(m0 + s_roff) * K + kbase + s_kc;
  const short* Bsrc = B + (size_t)(n0 + s_roff) * K + kbase + s_kc;
  const size_t rstep = (size_t)128 * K;

  auto STAGE = [&](int op, int kh, int t) {
    const short* g = (op ? Bsrc : Asrc) + t * 64 + kh * 32;
    char* d = lds + ((t & 1) * 65536 + op * 32768 + kh * 16384 + w * 1024);
    gload_lds16(g, d);
    gload_lds16(g + rstep, d + 8192);
  };

  f32x4 acc[8][4] = {};

  STAGE(0, 0, 0); STAGE(1, 0, 0); STAGE(0, 1, 0); STAGE(1, 1, 0);
  VMW(4); BAR(); SB0();

  for (int t = 0; t < NT; ++t) {
    const char* pa = lds + (t & 1) * 65536 + wrM * 8192 + laneoff;
    const char* pb = lds + (t & 1) * 65536 + 32768 + wcN * 4096 + laneoff;
    const bool st = (t + 1) < NT;
    short8 a[8], b[4];

#pragma unroll
    for (int mt = 0; mt < 8; ++mt) a[mt] = *(const short8*)(pa + mt * 1024);
    b[0] = *(const short8*)(pb);
    b[1] = *(const short8*)(pb + 1024);
    if (st) STAGE(0, 0, t + 1);
    BAR(); LGKM0();
    __builtin_amdgcn_s_setprio(1);
#pragma unroll
    for (int mt = 0; mt < 8; ++mt) {
      acc[mt][0] = __builtin_amdgcn_mfma_f32_16x16x32_bf16(a[mt], b[0], acc[mt][0], 0, 0, 0);
      acc[mt][1] = __builtin_amdgcn_mfma_f32_16x16x32_bf16(a[mt], b[1], acc[mt][1], 0, 0, 0);
    }
    __builtin_amdgcn_s_setprio(0);
    BAR(); SB0();

    b[2] = *(const short8*)(pb + 2048);
    b[3] = *(const short8*)(pb + 3072);
    if (st) STAGE(1, 0, t + 1);
    BAR(); LGKM0();
    __builtin_amdgcn_s_setprio(1);
#pragma unroll
    for (int mt = 0; mt < 8; ++mt) {
      acc[mt][2] = __builtin_amdgcn_mfma_f32_16x16x32_bf16(a[mt], b[2], acc[mt][2], 0, 0, 0);
      acc[mt][3] = __builtin_amdgcn_mfma_f32_16x16x32_bf16(a[mt], b[3], acc[mt][3], 0, 0, 0);
    }
    __builtin_amdgcn_s_setprio(0);
    if (st) { VMW(4); } else { VMW(0); }
    BAR(); SB0();

    pa += 16384; pb += 16384;
#pragma unroll
    for (int mt = 0; mt < 8; ++mt) a[mt] = *(const short8*)(pa + mt * 1024);
    b[0] = *(const short8*)(pb);
    b[1] = *(const short8*)(pb + 1024);
    if (st) STAGE(0, 1, t + 1);
    BAR(); LGKM0();
    __builtin_amdgcn_s_setprio(1);
#pragma unroll
    for (int mt = 0; mt < 8; ++mt) {
      acc[mt][0] = __builtin_amdgcn_mfma_f32_16x16x32_bf16(a[mt], b[0], acc[mt][0], 0, 0, 0);
      acc[mt][1] = __builtin_amdgcn_mfma_f32_16x16x32_bf16(a[mt], b[1], acc[mt][1], 0, 0, 0);
    }
    __builtin_amdgcn_s_setprio(0);
    BAR(); SB0();

    b[2] = *(const short8*)(pb + 2048);
    b[3] = *(const short8*)(pb + 3072);
    if (st) STAGE(1, 1, t + 1);
    BAR(); LGKM0();
    __builtin_amdgcn_s_setprio(1);
#pragma unroll
    for (int mt = 0; mt < 8; ++mt) {
      acc[mt][2] = __builtin_amdgcn_mfma_f32_16x16x32_bf16(a[mt], b[2], acc[mt][2], 0, 0, 0);
      acc[mt][3] = __builtin_amdgcn_mfma_f32_16x16x32_bf16(a[mt], b[3], acc[mt][3], 0, 0, 0);
    }
    __builtin_amdgcn_s_setprio(0);
    if (st) VMW(4);
    BAR(); SB0();
  }

#pragma unroll
  for (int mt = 0; mt < 8; ++mt) {
#pragma unroll
    for (int nt = 0; nt < 4; ++nt) {
      const int col = n0 + wcN * 64 + nt * 16 + lr;
      const int row0 = m0 + wrM * 128 + mt * 16 + lg * 4;
      if constexpr (EPI == 0) {  // QKV scatter
        const int sel = col >> 10, nn = col & 1023;
        const int hh = nn >> 6, dd = nn & 63;
        const int bb = row0 >> 10, tt0 = row0 & 1023;
        if (sel == 2) {
          const float bias = f2[nn];
          short4v pk = {f2bf(acc[mt][nt][0] + bias), f2bf(acc[mt][nt][1] + bias),
                        f2bf(acc[mt][nt][2] + bias), f2bf(acc[mt][nt][3] + bias)};
          *(short4v*)&s2[(((size_t)(bb * 16 + hh)) * 64 + dd) * 1024 + tt0] = pk;
        } else {
          const float bias = (sel == 0) ? f0[nn] : f1[nn];
          short* dst = (sel == 0) ? s0 : s1;
#pragma unroll
          for (int r = 0; r < 4; ++r)
            dst[(((size_t)(bb * 16 + hh)) * 1024 + tt0 + r) * 64 + dd] =
                f2bf(acc[mt][nt][r] + bias);
        }
      } else if constexpr (EPI == 1) {  // FFN1 bias+relu -> bf16
#pragma unroll
        for (int r = 0; r < 4; ++r) {
          float val = fmaxf(acc[mt][nt][r] + f0[col], 0.0f);
          s0[(size_t)(row0 + r) * 4096 + col] = f2bf(val);
        }
      } else {  // split-K partials f32
#pragma unroll
        for (int r = 0; r < 4; ++r)
          fo[(size_t)(row0 + r) * 1024 + col] = acc[mt][nt][r];
      }
    }
  }
}

__global__ __launch_bounds__(512, 2) void gemm8_qkv(
    const short* __restrict__ A, const short* __restrict__ B,
    const float* __restrict__ bq, const float* __restrict__ bk,
    const float* __restrict__ bv, short* __restrict__ q,
    short* __restrict__ k, short* __restrict__ vt) {
  gemm8_body<0>(A, B, 1024, 0, blockIdx.y * 256, blockIdx.x * 256, bq, bk, bv,
                q, k, vt, nullptr);
}

__global__ __launch_bounds__(512, 2) void gemm8_ffn1(
    const short* __restrict__ A, const short* __restrict__ B,
    const float* __restrict__ b1f, short* __restrict__ u) {
  gemm8_body<1>(A, B, 1024, 0, blockIdx.y * 256, blockIdx.x * 256, b1f,
                nullptr, nullptr, u, nullptr, nullptr, nullptr);
}

__global__ __launch_bounds__(512, 2) void gemm8_ffn2sk(
    const short* __restrict__ A, const short* __restrict__ B,
    float* __restrict__ part) {
  const int z = blockIdx.z;
  gemm8_body<2>(A, B, 4096, z * 1024, blockIdx.y * 256, blockIdx.x * 256,
                nullptr, nullptr, nullptr, nullptr, nullptr, nullptr,
                part + (size_t)z * 4096 * 1024);
}

// out = sum_z part[z] + b2f + hf + x3
__global__ __launch_bounds__(256) void ffn2_reduce(
    const float* __restrict__ part, const float* __restrict__ b2f,
    const short* __restrict__ hfb, const float* __restrict__ x3,
    float* __restrict__ out) {
  const size_t i = (size_t)blockIdx.x * 256 + threadIdx.x;
  const size_t S = (size_t)4096 * 1024 / 4;
  float4 a0 = ((const float4*)part)[i];
  float4 a1 = ((const float4*)part)[i + S];
  float4 a2 = ((const float4*)part)[i + 2 * S];
  float4 a3 = ((const float4*)part)[i + 3 * S];
  float4 bb = ((const float4*)b2f)[i & 255];
  float4 xv = ((const float4*)x3)[i];
  short4v hv = ((const short4v*)hfb)[i];
  float4 o;
  o.x = a0.x + a1.x + a2.x + a3.x + bb.x + bf2f(hv.x) + xv.x;
  o.y = a0.y + a1.y + a2.y + a3.y + bb.y + bf2f(hv.y) + xv.y;
  o.z = a0.z + a1.z + a2.z + a3.z + bb.z + bf2f(hv.z) + xv.z;
  o.w = a0.w + a1.w + a2.w + a3.w + bb.w + bf2f(hv.w) + xv.w;
  ((float4*)out)[i] = o;
}

// ----------------------------- flash attention -----------------------------
// q,k: [64 bh][1024][64] bf16 ; vt: [64 bh][64 d][1024 t] bf16 ;
// o: [4][1024][1024] f32. Block = (bh, 64-row q-tile), 4 waves x 16 q-rows.
// Double-buffered K/V LDS; loads for tile t+1 issued at top of tile t
// (regs), written to alternate buffer at end -> ONE barrier per tile.
// Softmax in exp2 domain (scale folded with log2e).
__global__ __launch_bounds__(256) void attn_kernel(
    const short* __restrict__ q, const short* __restrict__ k,
    const short* __restrict__ vt, float* __restrict__ o) {
  __shared__ __align__(16) short Ksm[2][64 * 64];
  __shared__ __align__(16) short Vsm[2][64 * 64];
  __shared__ __align__(16) short Psm[4 * 16 * 64];
  const int bh = blockIdx.x, qt = blockIdx.y;
  const int tid = threadIdx.x, lane = tid & 63, w = tid >> 6;
  const int lr = lane & 15, lg = lane >> 4;

  const short* qb = q + (size_t)bh * 1024 * 64;
  const short* kb = k + (size_t)bh * 1024 * 64;
  const short* vb = vt + (size_t)bh * 64 * 1024;

  const int qrow = qt * 64 + w * 16 + lr;
  short8 qf0 = *(const short8*)&qb[(size_t)qrow * 64 + lg * 8];
  short8 qf1 = *(const short8*)&qb[(size_t)qrow * 64 + 32 + lg * 8];

  f32x4 oacc[4] = {};
  float mrun[4], lrun[4];
#pragma unroll
  for (int r = 0; r < 4; ++r) { mrun[r] = -1e30f; lrun[r] = 0.0f; }

  const float scale2 = 0.03125f * 1.44269504088896f;  // (1/sqrt(C))*log2(e)
  const int srow = tid >> 3;  // staging row 0..31 (+32 on second chunk)
  const int sc8 = tid & 7;    // 16B chunk within 128B row
  short* pw = Psm + w * 1024;

  short8 kreg[2], vreg[2];
  // prologue: KV tile 0 -> regs -> buf 0
#pragma unroll
  for (int p = 0; p < 2; ++p) {
    const int rr = srow + p * 32;
    kreg[p] = *(const short8*)&kb[(size_t)rr * 64 + sc8 * 8];
    vreg[p] = *(const short8*)&vb[(size_t)rr * 1024 + sc8 * 8];
  }
#pragma unroll
  for (int p = 0; p < 2; ++p) {
    const int rr = srow + p * 32;
    *(short8*)((char*)Ksm[0] + rr * 128 + ((sc8 ^ (rr & 7)) << 4)) = kreg[p];
    *(short8*)((char*)Vsm[0] + rr * 128 + ((sc8 ^ (rr & 7)) << 4)) = vreg[p];
  }

  for (int kt = 0; kt <= qt; ++kt) {
    const int cur = kt & 1;
    __syncthreads();  // buf[cur] fully staged by all waves
    // issue next tile's global loads now; latency hides under compute
    if (kt < qt) {
#pragma unroll
      for (int p = 0; p < 2; ++p) {
        const int rr = srow + p * 32;
        kreg[p] =
            *(const short8*)&kb[((size_t)((kt + 1) * 64 + rr)) * 64 + sc8 * 8];
        vreg[p] =
            *(const short8*)&vb[(size_t)rr * 1024 + (kt + 1) * 64 + sc8 * 8];
      }
    }

    // S = Q K^T  (16 q-rows x 64 kv-cols per wave)
    const char* Kc = (const char*)Ksm[cur];
    const char* Vc = (const char*)Vsm[cur];
    f32x4 sfr[4];
#pragma unroll
    for (int nt = 0; nt < 4; ++nt) {
      const int krow = nt * 16 + lr;
      short8 kf0 = *(const short8*)(Kc + krow * 128 + (((0 + lg) ^ (krow & 7)) << 4));
      short8 kf1 = *(const short8*)(Kc + krow * 128 + (((4 + lg) ^ (krow & 7)) << 4));
      f32x4 z = {};
      z = __builtin_amdgcn_mfma_f32_16x16x32_bf16(qf0, kf0, z, 0, 0, 0);
      z = __builtin_amdgcn_mfma_f32_16x16x32_bf16(qf1, kf1, z, 0, 0, 0);
      sfr[nt] = z;
    }
    const int qg = qt * 64 + w * 16 + lg * 4;
    if (kt == qt) {
#pragma unroll
      for (int nt = 0; nt < 4; ++nt) {
        const int sg = kt * 64 + nt * 16 + lr;
#pragma unroll
        for (int r = 0; r < 4; ++r)
          sfr[nt][r] = (sg <= qg + r) ? sfr[nt][r] * scale2 : -1e30f;
      }
    } else {
#pragma unroll
      for (int nt = 0; nt < 4; ++nt)
#pragma unroll
        for (int r = 0; r < 4; ++r) sfr[nt][r] *= scale2;
    }
    // online softmax in exp2 domain (rows live across 16-lane groups)
    float pm[4];
#pragma unroll
    for (int r = 0; r < 4; ++r) {
      pm[r] = fmaxf(fmaxf(sfr[0][r], sfr[1][r]), fmaxf(sfr[2][r], sfr[3][r]));
#pragma unroll
      for (int off = 1; off < 16; off <<= 1)
        pm[r] = fmaxf(pm[r], __shfl_xor(pm[r], off, 64));
    }
    float alpha[4], rsum[4];
#pragma unroll
    for (int r = 0; r < 4; ++r) {
      const float mnew = fmaxf(mrun[r], pm[r]);
      alpha[r] = exp2f(mrun[r] - mnew);
      mrun[r] = mnew;
      rsum[r] = 0.0f;
    }
#pragma unroll
    for (int nt = 0; nt < 4; ++nt)
#pragma unroll
      for (int r = 0; r < 4; ++r) {
        const float pv = exp2f(sfr[nt][r] - mrun[r]);
        sfr[nt][r] = pv;
        rsum[r] += pv;
      }
#pragma unroll
    for (int r = 0; r < 4; ++r) {
#pragma unroll
      for (int off = 1; off < 16; off <<= 1)
        rsum[r] += __shfl_xor(rsum[r], off, 64);
      lrun[r] = lrun[r] * alpha[r] + rsum[r];
    }
#pragma unroll
    for (int nt = 0; nt < 4; ++nt)
#pragma unroll
      for (int r = 0; r < 4; ++r) oacc[nt][r] *= alpha[r];

    // P (D-layout) -> per-wave LDS (A-layout for PV); same-wave DS ordering
    // makes this barrier-free.
#pragma unroll
    for (int nt = 0; nt < 4; ++nt)
#pragma unroll
      for (int r = 0; r < 4; ++r) {
        const int prow = lg * 4 + r, pcol = nt * 16 + lr;
        *(short*)((char*)pw + prow * 128 +
                  ((pcol * 2) ^ ((prow & 7) << 4))) = f2bf(sfr[nt][r]);
      }

    // O += P * V
#pragma unroll
    for (int kc = 0; kc < 2; ++kc) {
      short8 pa = *(const short8*)((const char*)pw + lr * 128 +
                                   (((kc * 4 + lg) ^ (lr & 7)) << 4));
#pragma unroll
      for (int nt = 0; nt < 4; ++nt) {
        const int vrow = nt * 16 + lr;
        short8 vf = *(const short8*)(Vc + vrow * 128 +
                                     (((kc * 4 + lg) ^ (vrow & 7)) << 4));
        oacc[nt] = __builtin_amdgcn_mfma_f32_16x16x32_bf16(pa, vf, oacc[nt], 0, 0, 0);
      }
    }

    // write KV tile kt+1 into the alternate buffer (safe: top-of-tile
    // barrier guarantees everyone finished reading it in tile kt-1)
    if (kt < qt) {
      char* Kn = (char*)Ksm[cur ^ 1];
      char* Vn = (char*)Vsm[cur ^ 1];
#pragma unroll
      for (int p = 0; p < 2; ++p) {
        const int rr = srow + p * 32;
        *(short8*)(Kn + rr * 128 + ((sc8 ^ (rr & 7)) << 4)) = kreg[p];
        *(short8*)(Vn + rr * 128 + ((sc8 ^ (rr & 7)) << 4)) = vreg[p];
      }
    }
  }

  float* ob = o + (size_t)(bh >> 4) * 1024 * 1024 + (bh & 15) * 64;
#pragma unroll
  for (int nt = 0; nt < 4; ++nt)
#pragma unroll
    for (int r = 0; r < 4; ++r) {
      const int trow = qt * 64 + w * 16 + lg * 4 + r;
      ob[(size_t)trow * 1024 + nt * 16 + lr] = oacc[nt][r] / lrun[r];
    }
}

// ------------------------------- launcher ----------------------------------
extern "C" void kernel_launch(void* const* d_in, const int* in_sizes, int n_in,
                              void* d_out, int out_size, void* d_ws,
                              size_t ws_size, hipStream_t stream) {
  const float* x = (const float*)d_in[0];
  const float* Wq = (const float*)d_in[1];
  const float* bq = (const float*)d_in[2];
  const float* Wk = (const float*)d_in[3];
  const float* bk = (const float*)d_in[4];
  const float* Wv = (const float*)d_in[5];
  const float* bv = (const float*)d_in[6];
  const float* g1 = (const float*)d_in[7];
  const float* b1 = (const float*)d_in[8];
  const float* g2 = (const float*)d_in[9];
  const float* b2 = (const float*)d_in[10];
  const float* gf = (const float*)d_in[11];
  const float* bfp = (const float*)d_in[12];
  const float* W1 = (const float*)d_in[13];
  const float* b1f = (const float*)d_in[14];
  const float* W2 = (const float*)d_in[15];
  const float* b2f = (const float*)d_in[16];
  float* out = (float*)d_out;

  hipFuncSetAttribute((const void*)gemm8_qkv,
                      hipFuncAttributeMaxDynamicSharedMemorySize, 131072);
  hipFuncSetAttribute((const void*)gemm8_ffn1,
                      hipFuncAttributeMaxDynamicSharedMemorySize, 131072);
  hipFuncSetAttribute((const void*)gemm8_ffn2sk,
                      hipFuncAttributeMaxDynamicSharedMemorySize, 131072);

  const size_t MB = 1024 * 1024;
  char* p = (char*)d_ws;
  // Region A (70MB): dead before gemm8_ffn2sk; 64MB split-K partials alias it.
  float* hbuf = (float*)(p + 0 * MB);      // 16MB  h (f32), dead after ln2f
  short* qbuf = (short*)(p + 16 * MB);     // 8MB   dead after attn
  short* kbuf = (short*)(p + 24 * MB);     // 8MB   dead after attn
  short* vtb = (short*)(p + 32 * MB);      // 8MB   dead after attn
  float* obuf = (float*)(p + 40 * MB);     // 16MB  dead after ln2f
  short* wqkv_t = (short*)(p + 56 * MB);   // 6MB   dead after gemm8_qkv
  short* w1_t = (short*)(p + 62 * MB);     // 8MB   dead after gemm8_ffn1
  float* part = (float*)(p + 0 * MB);      // 64MB  alias
  // Region B (72MB): live through the end.
  char* q = p + 70 * MB;
  short* w2_t = (short*)(q + 0 * MB);      // 8MB
  short* hbb = (short*)(q + 8 * MB);       // 8MB
  float* x3b = (float*)(q + 16 * MB);      // 16MB
  short* hfb = (short*)(q + 32 * MB);      // 8MB
  short* ub = (short*)(q + 40 * MB);       // 32MB

  dim3 tb(32, 8);
  transpose_qkv<<<dim3(2, 32, 48), tb, 0, stream>>>(Wq, Wk, Wv, wqkv_t);
  transpose_to_bf16<<<dim3(128, 32, 1), tb, 0, stream>>>(W1, w1_t, 1024, 4096);
  transpose_to_bf16<<<dim3(32, 128, 1), tb, 0, stream>>>(W2, w2_t, 4096, 1024);

  ln1_kernel<<<4096, 256, 0, stream>>>(x, g1, b1, hbuf, hbb);

  gemm8_qkv<<<dim3(12, 16), 512, 131072, stream>>>(hbb, wqkv_t, bq, bk, bv,
                                                   qbuf, kbuf, vtb);

  attn_kernel<<<dim3(64, 16), 256, 0, stream>>>(qbuf, kbuf, vtb, obuf);

  ln2f_kernel<<<4096, 256, 0, stream>>>(hbuf, obuf, g2, b2, gf, bfp, x3b, hfb);

  gemm8_ffn1<<<dim3(16, 16), 512, 131072, stream>>>(hfb, w1_t, b1f, ub);

  gemm8_ffn2sk<<<dim3(4, 16, 4), 512, 131072, stream>>>(ub, w2_t, part);

  ffn2_reduce<<<4096, 256, 0, stream>>>(part, b2f, hfb, x3b, out);
}

// Round 5
// 206.568 us; speedup vs baseline: 1.3602x; 1.0514x over previous
//
#include <hip/hip_runtime.h>
#include <hip/hip_bf16.h>

// ---------------------------------------------------------------------------
// Decoder block on MI355X. GEMMs: 256x256 / BK=64 / 8-wave 8-phase
// counted-vmcnt schedule (guide §5 template, T2+T3+T4+T5), plain HIP.
// Attention: flash-style with SWAPPED QK^T (mfma(K,Q)) so each lane owns one
// q-row and 16 in-lane k-values: softmax reduces with 2 shuffles, P packs via
// v_cvt_pk_bf16_f32 into ds_write_b64, PV computes O^T = mfma(V,P), epilogue
// is float4 stores. Single-buffered K/V LDS (24KB) + reg-prefetch (T14).
// ---------------------------------------------------------------------------

typedef __attribute__((ext_vector_type(8))) short short8;
typedef __attribute__((ext_vector_type(4))) short short4v;
typedef __attribute__((ext_vector_type(4))) float f32x4;

#define DEVI static __device__ __forceinline__

#define BAR() __builtin_amdgcn_s_barrier()
#define SB0() __builtin_amdgcn_sched_barrier(0)
#define LGKM0()                                         \
  {                                                     \
    asm volatile("s_waitcnt lgkmcnt(0)" ::: "memory");  \
    __builtin_amdgcn_sched_barrier(0);                  \
  }
#define VMW(n)                                              \
  {                                                         \
    asm volatile("s_waitcnt vmcnt(" #n ")" ::: "memory");   \
    __builtin_amdgcn_sched_barrier(0);                      \
  }

DEVI void gload_lds16(const void* g, void* l) {
  __builtin_amdgcn_global_load_lds(
      (const __attribute__((address_space(1))) void*)g,
      (__attribute__((address_space(3))) void*)l, 16, 0, 0);
}

DEVI float bf2f(short s) {
  union { float f; unsigned u; } cv;
  cv.u = ((unsigned)(unsigned short)s) << 16;
  return cv.f;
}
DEVI short f2bf(float f) {  // round-to-nearest-even
  union { float f; unsigned u; } cv;
  cv.f = f;
  unsigned u = cv.u;
  u += 0x7FFFu + ((u >> 16) & 1u);
  return (short)(u >> 16);
}

DEVI void block_reduce2(float& s, float& s2, float* red, int t) {
#pragma unroll
  for (int off = 1; off < 64; off <<= 1) {
    s += __shfl_xor(s, off, 64);
    s2 += __shfl_xor(s2, off, 64);
  }
  __syncthreads();
  if ((t & 63) == 0) { red[(t >> 6) * 2] = s; red[(t >> 6) * 2 + 1] = s2; }
  __syncthreads();
  s = red[0] + red[2] + red[4] + red[6];
  s2 = red[1] + red[3] + red[5] + red[7];
}

// --------------------------- transpose f32 -> bf16 -------------------------
__global__ __launch_bounds__(256) void transpose_to_bf16(
    const float* __restrict__ in, short* __restrict__ out, int R, int C) {
  __shared__ float tile[32][33];
  const int b = blockIdx.z;
  in += (size_t)b * R * C;
  out += (size_t)b * R * C;
  const int r0 = blockIdx.y * 32, c0 = blockIdx.x * 32;
  const int tx = threadIdx.x, ty = threadIdx.y;
#pragma unroll
  for (int i = 0; i < 32; i += 8)
    tile[ty + i][tx] = in[(size_t)(r0 + ty + i) * C + c0 + tx];
  __syncthreads();
#pragma unroll
  for (int i = 0; i < 32; i += 8)
    out[(size_t)(c0 + ty + i) * R + r0 + tx] = f2bf(tile[tx][ty + i]);
}

// Wq/Wk/Wv merged: each [16][1024][64] -> wqkv_t [3][16][64][1024]
__global__ __launch_bounds__(256) void transpose_qkv(
    const float* __restrict__ Wq, const float* __restrict__ Wk,
    const float* __restrict__ Wv, short* __restrict__ out) {
  __shared__ float tile[32][33];
  const int z = blockIdx.z;  // 0..47
  const int sel = z >> 4, b = z & 15;
  const float* in = (sel == 0) ? Wq : (sel == 1) ? Wk : Wv;
  in += (size_t)b * 1024 * 64;
  short* o = out + (size_t)sel * 1024 * 1024 + (size_t)b * 1024 * 64;
  const int r0 = blockIdx.y * 32, c0 = blockIdx.x * 32;
  const int tx = threadIdx.x, ty = threadIdx.y;
#pragma unroll
  for (int i = 0; i < 32; i += 8)
    tile[ty + i][tx] = in[(size_t)(r0 + ty + i) * 64 + c0 + tx];
  __syncthreads();
#pragma unroll
  for (int i = 0; i < 32; i += 8)
    o[(size_t)(c0 + ty + i) * 1024 + r0 + tx] = f2bf(tile[tx][ty + i]);
}

// ------------------------------- LayerNorms --------------------------------
__global__ __launch_bounds__(256) void ln1_kernel(
    const float* __restrict__ x, const float* __restrict__ g,
    const float* __restrict__ b, float* __restrict__ hf,
    short* __restrict__ hb) {
  __shared__ float red[8];
  const int row = blockIdx.x, t = threadIdx.x;
  float4 v = ((const float4*)(x + (size_t)row * 1024))[t];
  float s = v.x + v.y + v.z + v.w;
  float s2 = v.x * v.x + v.y * v.y + v.z * v.z + v.w * v.w;
  block_reduce2(s, s2, red, t);
  const float mu = s * (1.0f / 1024.0f);
  const float rstd = rsqrtf(s2 * (1.0f / 1024.0f) - mu * mu + 1e-5f);
  float4 gv = ((const float4*)g)[t], bv = ((const float4*)b)[t];
  float4 o;
  o.x = (v.x - mu) * rstd * gv.x + bv.x;
  o.y = (v.y - mu) * rstd * gv.y + bv.y;
  o.z = (v.z - mu) * rstd * gv.z + bv.z;
  o.w = (v.w - mu) * rstd * gv.w + bv.w;
  ((float4*)(hf + (size_t)row * 1024))[t] = o;
  short4v p = {f2bf(o.x), f2bf(o.y), f2bf(o.z), f2bf(o.w)};
  ((short4v*)(hb + (size_t)row * 1024))[t] = p;
}

__global__ __launch_bounds__(256) void ln2f_kernel(
    const float* __restrict__ h, const float* __restrict__ o,
    const float* __restrict__ g2, const float* __restrict__ b2,
    const float* __restrict__ gf, const float* __restrict__ bfp,
    float* __restrict__ x3, short* __restrict__ hfb) {
  __shared__ float red[8];
  const int row = blockIdx.x, t = threadIdx.x;
  float4 hv = ((const float4*)(h + (size_t)row * 1024))[t];
  float4 ov = ((const float4*)(o + (size_t)row * 1024))[t];
  float4 v;
  v.x = hv.x + ov.x; v.y = hv.y + ov.y; v.z = hv.z + ov.z; v.w = hv.w + ov.w;
  float s = v.x + v.y + v.z + v.w;
  float s2 = v.x * v.x + v.y * v.y + v.z * v.z + v.w * v.w;
  block_reduce2(s, s2, red, t);
  float mu = s * (1.0f / 1024.0f);
  float rstd = rsqrtf(s2 * (1.0f / 1024.0f) - mu * mu + 1e-5f);
  float4 gv = ((const float4*)g2)[t], bv = ((const float4*)b2)[t];
  float4 xv;
  xv.x = (v.x - mu) * rstd * gv.x + bv.x;
  xv.y = (v.y - mu) * rstd * gv.y + bv.y;
  xv.z = (v.z - mu) * rstd * gv.z + bv.z;
  xv.w = (v.w - mu) * rstd * gv.w + bv.w;
  ((float4*)(x3 + (size_t)row * 1024))[t] = xv;
  s = xv.x + xv.y + xv.z + xv.w;
  s2 = xv.x * xv.x + xv.y * xv.y + xv.z * xv.z + xv.w * xv.w;
  block_reduce2(s, s2, red, t);
  mu = s * (1.0f / 1024.0f);
  rstd = rsqrtf(s2 * (1.0f / 1024.0f) - mu * mu + 1e-5f);
  float4 gv2 = ((const float4*)gf)[t], bv2 = ((const float4*)bfp)[t];
  short4v pk = {f2bf((xv.x - mu) * rstd * gv2.x + bv2.x),
                f2bf((xv.y - mu) * rstd * gv2.y + bv2.y),
                f2bf((xv.z - mu) * rstd * gv2.z + bv2.z),
                f2bf((xv.w - mu) * rstd * gv2.w + bv2.w)};
  ((short4v*)(hfb + (size_t)row * 1024))[t] = pk;
}

// --------------------- 256x256 8-phase GEMM core ---------------------------
template <int EPI>
DEVI void gemm8_body(const short* __restrict__ A, const short* __restrict__ B,
                     int K, int kbase, int m0, int n0,
                     const float* __restrict__ f0, const float* __restrict__ f1,
                     const float* __restrict__ f2, short* __restrict__ s0,
                     short* __restrict__ s1, short* __restrict__ s2,
                     float* __restrict__ fo) {
  extern __shared__ __align__(16) char lds[];  // 131072 B
  constexpr int NT = 16;
  const int tid = threadIdx.x;
  const int l = tid & 63, w = tid >> 6;
  const int wrM = w >> 2, wcN = w & 3;
  const int lr = l & 15, lg = l >> 4;

  const int cswz = (((lr & 1) << 2) | lg) ^ (lr >> 1);
  const int laneoff = ((lr >> 1) << 7) + (cswz << 4);

  const int rsel = l >> 3;
  const int scz = (l & 7) ^ rsel;
  const int s_roff = w * 16 + rsel * 2 + (scz >> 2);
  const int s_kc = (scz & 3) * 8;
  const short* Asrc = A + (size_t)(m0 + s_roff) * K + kbase + s_kc;
  const short* Bsrc = B + (size_t)(n0 + s_roff) * K + kbase + s_kc;
  const size_t rstep = (size_t)128 * K;

  auto STAGE = [&](int op, int kh, int t) {
    const short* g = (op ? Bsrc : Asrc) + t * 64 + kh * 32;
    char* d = lds + ((t & 1) * 65536 + op * 32768 + kh * 16384 + w * 1024);
    gload_lds16(g, d);
    gload_lds16(g + rstep, d + 8192);
  };

  f32x4 acc[8][4] = {};

  STAGE(0, 0, 0); STAGE(1, 0, 0); STAGE(0, 1, 0); STAGE(1, 1, 0);
  VMW(4); BAR(); SB0();

  for (int t = 0; t < NT; ++t) {
    const char* pa = lds + (t & 1) * 65536 + wrM * 8192 + laneoff;
    const char* pb = lds + (t & 1) * 65536 + 32768 + wcN * 4096 + laneoff;
    const bool st = (t + 1) < NT;
    short8 a[8], b[4];

#pragma unroll
    for (int mt = 0; mt < 8; ++mt) a[mt] = *(const short8*)(pa + mt * 1024);
    b[0] = *(const short8*)(pb);
    b[1] = *(const short8*)(pb + 1024);
    if (st) STAGE(0, 0, t + 1);
    BAR(); LGKM0();
    __builtin_amdgcn_s_setprio(1);
#pragma unroll
    for (int mt = 0; mt < 8; ++mt) {
      acc[mt][0] = __builtin_amdgcn_mfma_f32_16x16x32_bf16(a[mt], b[0], acc[mt][0], 0, 0, 0);
      acc[mt][1] = __builtin_amdgcn_mfma_f32_16x16x32_bf16(a[mt], b[1], acc[mt][1], 0, 0, 0);
    }
    __builtin_amdgcn_s_setprio(0);
    BAR(); SB0();

    b[2] = *(const short8*)(pb + 2048);
    b[3] = *(const short8*)(pb + 3072);
    if (st) STAGE(1, 0, t + 1);
    BAR(); LGKM0();
    __builtin_amdgcn_s_setprio(1);
#pragma unroll
    for (int mt = 0; mt < 8; ++mt) {
      acc[mt][2] = __builtin_amdgcn_mfma_f32_16x16x32_bf16(a[mt], b[2], acc[mt][2], 0, 0, 0);
      acc[mt][3] = __builtin_amdgcn_mfma_f32_16x16x32_bf16(a[mt], b[3], acc[mt][3], 0, 0, 0);
    }
    __builtin_amdgcn_s_setprio(0);
    if (st) { VMW(4); } else { VMW(0); }
    BAR(); SB0();

    pa += 16384; pb += 16384;
#pragma unroll
    for (int mt = 0; mt < 8; ++mt) a[mt] = *(const short8*)(pa + mt * 1024);
    b[0] = *(const short8*)(pb);
    b[1] = *(const short8*)(pb + 1024);
    if (st) STAGE(0, 1, t + 1);
    BAR(); LGKM0();
    __builtin_amdgcn_s_setprio(1);
#pragma unroll
    for (int mt = 0; mt < 8; ++mt) {
      acc[mt][0] = __builtin_amdgcn_mfma_f32_16x16x32_bf16(a[mt], b[0], acc[mt][0], 0, 0, 0);
      acc[mt][1] = __builtin_amdgcn_mfma_f32_16x16x32_bf16(a[mt], b[1], acc[mt][1], 0, 0, 0);
    }
    __builtin_amdgcn_s_setprio(0);
    BAR(); SB0();

    b[2] = *(const short8*)(pb + 2048);
    b[3] = *(const short8*)(pb + 3072);
    if (st) STAGE(1, 1, t + 1);
    BAR(); LGKM0();
    __builtin_amdgcn_s_setprio(1);
#pragma unroll
    for (int mt = 0; mt < 8; ++mt) {
      acc[mt][2] = __builtin_amdgcn_mfma_f32_16x16x32_bf16(a[mt], b[2], acc[mt][2], 0, 0, 0);
      acc[mt][3] = __builtin_amdgcn_mfma_f32_16x16x32_bf16(a[mt], b[3], acc[mt][3], 0, 0, 0);
    }
    __builtin_amdgcn_s_setprio(0);
    if (st) VMW(4);
    BAR(); SB0();
  }

#pragma unroll
  for (int mt = 0; mt < 8; ++mt) {
#pragma unroll
    for (int nt = 0; nt < 4; ++nt) {
      const int col = n0 + wcN * 64 + nt * 16 + lr;
      const int row0 = m0 + wrM * 128 + mt * 16 + lg * 4;
      if constexpr (EPI == 0) {  // QKV scatter
        const int sel = col >> 10, nn = col & 1023;
        const int hh = nn >> 6, dd = nn & 63;
        const int bb = row0 >> 10, tt0 = row0 & 1023;
        if (sel == 2) {
          const float bias = f2[nn];
          short4v pk = {f2bf(acc[mt][nt][0] + bias), f2bf(acc[mt][nt][1] + bias),
                        f2bf(acc[mt][nt][2] + bias), f2bf(acc[mt][nt][3] + bias)};
          *(short4v*)&s2[(((size_t)(bb * 16 + hh)) * 64 + dd) * 1024 + tt0] = pk;
        } else {
          const float bias = (sel == 0) ? f0[nn] : f1[nn];
          short* dst = (sel == 0) ? s0 : s1;
#pragma unroll
          for (int r = 0; r < 4; ++r)
            dst[(((size_t)(bb * 16 + hh)) * 1024 + tt0 + r) * 64 + dd] =
                f2bf(acc[mt][nt][r] + bias);
        }
      } else if constexpr (EPI == 1) {  // FFN1 bias+relu -> bf16
#pragma unroll
        for (int r = 0; r < 4; ++r) {
          float val = fmaxf(acc[mt][nt][r] + f0[col], 0.0f);
          s0[(size_t)(row0 + r) * 4096 + col] = f2bf(val);
        }
      } else {  // split-K partials f32
#pragma unroll
        for (int r = 0; r < 4; ++r)
          fo[(size_t)(row0 + r) * 1024 + col] = acc[mt][nt][r];
      }
    }
  }
}

__global__ __launch_bounds__(512, 2) void gemm8_qkv(
    const short* __restrict__ A, const short* __restrict__ B,
    const float* __restrict__ bq, const float* __restrict__ bk,
    const float* __restrict__ bv, short* __restrict__ q,
    short* __restrict__ k, short* __restrict__ vt) {
  gemm8_body<0>(A, B, 1024, 0, blockIdx.y * 256, blockIdx.x * 256, bq, bk, bv,
                q, k, vt, nullptr);
}

__global__ __launch_bounds__(512, 2) void gemm8_ffn1(
    const short* __restrict__ A, const short* __restrict__ B,
    const float* __restrict__ b1f, short* __restrict__ u) {
  gemm8_body<1>(A, B, 1024, 0, blockIdx.y * 256, blockIdx.x * 256, b1f,
                nullptr, nullptr, u, nullptr, nullptr, nullptr);
}

__global__ __launch_bounds__(512, 2) void gemm8_ffn2sk(
    const short* __restrict__ A, const short* __restrict__ B,
    float* __restrict__ part) {
  const int z = blockIdx.z;
  gemm8_body<2>(A, B, 4096, z * 1024, blockIdx.y * 256, blockIdx.x * 256,
                nullptr, nullptr, nullptr, nullptr, nullptr, nullptr,
                part + (size_t)z * 4096 * 1024);
}

// out = sum_z part[z] + b2f + hf + x3
__global__ __launch_bounds__(256) void ffn2_reduce(
    const float* __restrict__ part, const float* __restrict__ b2f,
    const short* __restrict__ hfb, const float* __restrict__ x3,
    float* __restrict__ out) {
  const size_t i = (size_t)blockIdx.x * 256 + threadIdx.x;
  const size_t S = (size_t)4096 * 1024 / 4;
  float4 a0 = ((const float4*)part)[i];
  float4 a1 = ((const float4*)part)[i + S];
  float4 a2 = ((const float4*)part)[i + 2 * S];
  float4 a3 = ((const float4*)part)[i + 3 * S];
  float4 bb = ((const float4*)b2f)[i & 255];
  float4 xv = ((const float4*)x3)[i];
  short4v hv = ((const short4v*)hfb)[i];
  float4 o;
  o.x = a0.x + a1.x + a2.x + a3.x + bb.x + bf2f(hv.x) + xv.x;
  o.y = a0.y + a1.y + a2.y + a3.y + bb.y + bf2f(hv.y) + xv.y;
  o.z = a0.z + a1.z + a2.z + a3.z + bb.z + bf2f(hv.z) + xv.z;
  o.w = a0.w + a1.w + a2.w + a3.w + bb.w + bf2f(hv.w) + xv.w;
  ((float4*)out)[i] = o;
}

// ----------------------------- flash attention -----------------------------
// q,k: [64 bh][1024][64] bf16 ; vt: [64 bh][64 d][1024 t] bf16 ;
// o: [4][1024][1024] f32. Block = (bh, 64-row q-tile), 4 waves x 16 q-rows.
// SWAPPED QK^T: S^T = mfma(K,Q) -> lane (lr,lg) holds q=lr, k=nt*16+lg*4+r.
// Softmax: in-lane reduce + shfl_xor(16,32). P packed via v_cvt_pk_bf16_f32
// to per-wave LDS [16 q][64 k] (XOR-swizzled); PV: O^T = mfma(V^T, P^T).
__global__ __launch_bounds__(256, 5) void attn_kernel(
    const short* __restrict__ q, const short* __restrict__ k,
    const short* __restrict__ vt, float* __restrict__ o) {
  __shared__ __align__(16) short Ksm[64 * 64];
  __shared__ __align__(16) short Vsm[64 * 64];
  __shared__ __align__(16) short Psm[4 * 16 * 64];
  const int bh = blockIdx.x, qt = blockIdx.y;
  const int tid = threadIdx.x, lane = tid & 63, w = tid >> 6;
  const int lr = lane & 15, lg = lane >> 4;

  const short* qb = q + (size_t)bh * 1024 * 64;
  const short* kb = k + (size_t)bh * 1024 * 64;
  const short* vb = vt + (size_t)bh * 64 * 1024;

  const int qrow = qt * 64 + w * 16 + lr;
  short8 qf0 = *(const short8*)&qb[(size_t)qrow * 64 + lg * 8];
  short8 qf1 = *(const short8*)&qb[(size_t)qrow * 64 + 32 + lg * 8];

  f32x4 oacc[4] = {};       // O^T frags: col q=lr, row d=nt*16+lg*4+r
  float mrun = -1e30f, lrun = 0.0f;  // per-lane: this lane's q-row

  const float scale2 = 0.03125f * 1.44269504088896f;  // (1/sqrt(C))*log2(e)
  const int srow = tid >> 3;  // staging row 0..31 (+32 on second chunk)
  const int sc8 = tid & 7;    // 16B chunk within 128B row
  char* pw = (char*)(Psm + w * 1024);  // per-wave 16x64 P tile
  const int qloc = w * 16 + lr;        // q-row local to 64-row block
  const int rowswz = (lr & 7) << 4;    // P row XOR swizzle

  short8 kreg[2], vreg[2];
  // prologue: KV tile 0 -> regs
#pragma unroll
  for (int p = 0; p < 2; ++p) {
    const int rr = srow + p * 32;
    kreg[p] = *(const short8*)&kb[(size_t)rr * 64 + sc8 * 8];
    vreg[p] = *(const short8*)&vb[(size_t)rr * 1024 + sc8 * 8];
  }

  for (int kt = 0; kt <= qt; ++kt) {
    // write staged regs -> LDS
#pragma unroll
    for (int p = 0; p < 2; ++p) {
      const int rr = srow + p * 32;
      *(short8*)((char*)Ksm + rr * 128 + ((sc8 ^ (rr & 7)) << 4)) = kreg[p];
      *(short8*)((char*)Vsm + rr * 128 + ((sc8 ^ (rr & 7)) << 4)) = vreg[p];
    }
    __syncthreads();
    // issue next tile's global loads now; latency hides under compute
    if (kt < qt) {
#pragma unroll
      for (int p = 0; p < 2; ++p) {
        const int rr = srow + p * 32;
        kreg[p] =
            *(const short8*)&kb[((size_t)((kt + 1) * 64 + rr)) * 64 + sc8 * 8];
        vreg[p] =
            *(const short8*)&vb[(size_t)rr * 1024 + (kt + 1) * 64 + sc8 * 8];
      }
    }

    // S^T = K Q^T : lane (lr,lg) gets q=lr, k = nt*16 + lg*4 + r
    f32x4 sfr[4];
#pragma unroll
    for (int nt = 0; nt < 4; ++nt) {
      const int krow = nt * 16 + lr;
      short8 kf0 = *(const short8*)((const char*)Ksm + krow * 128 +
                                    (((0 + lg) ^ (krow & 7)) << 4));
      short8 kf1 = *(const short8*)((const char*)Ksm + krow * 128 +
                                    (((4 + lg) ^ (krow & 7)) << 4));
      f32x4 z = {};
      z = __builtin_amdgcn_mfma_f32_16x16x32_bf16(kf0, qf0, z, 0, 0, 0);
      z = __builtin_amdgcn_mfma_f32_16x16x32_bf16(kf1, qf1, z, 0, 0, 0);
      sfr[nt] = z;
    }
    // scale + causal mask (k_local <= q_local on the diagonal tile)
    if (kt == qt) {
#pragma unroll
      for (int nt = 0; nt < 4; ++nt) {
        const int kb0 = nt * 16 + lg * 4;
#pragma unroll
        for (int r = 0; r < 4; ++r)
          sfr[nt][r] = (kb0 + r <= qloc) ? sfr[nt][r] * scale2 : -1e30f;
      }
    } else {
#pragma unroll
      for (int nt = 0; nt < 4; ++nt)
#pragma unroll
        for (int r = 0; r < 4; ++r) sfr[nt][r] *= scale2;
    }
    // in-lane max tree (16 values) + 2 shuffles across lg groups
    float pm;
    {
      float a0 = fmaxf(fmaxf(sfr[0][0], sfr[0][1]), fmaxf(sfr[0][2], sfr[0][3]));
      float a1 = fmaxf(fmaxf(sfr[1][0], sfr[1][1]), fmaxf(sfr[1][2], sfr[1][3]));
      float a2 = fmaxf(fmaxf(sfr[2][0], sfr[2][1]), fmaxf(sfr[2][2], sfr[2][3]));
      float a3 = fmaxf(fmaxf(sfr[3][0], sfr[3][1]), fmaxf(sfr[3][2], sfr[3][3]));
      pm = fmaxf(fmaxf(a0, a1), fmaxf(a2, a3));
      pm = fmaxf(pm, __shfl_xor(pm, 16, 64));
      pm = fmaxf(pm, __shfl_xor(pm, 32, 64));
    }
    const float mnew = fmaxf(mrun, pm);
    const float alpha = exp2f(mrun - mnew);
    mrun = mnew;
    // p = exp2(s - m), in-lane sum tree
    float rs;
    {
#pragma unroll
      for (int nt = 0; nt < 4; ++nt)
#pragma unroll
        for (int r = 0; r < 4; ++r) sfr[nt][r] = exp2f(sfr[nt][r] - mnew);
      float s0 = (sfr[0][0] + sfr[0][1]) + (sfr[0][2] + sfr[0][3]);
      float s1 = (sfr[1][0] + sfr[1][1]) + (sfr[1][2] + sfr[1][3]);
      float s2 = (sfr[2][0] + sfr[2][1]) + (sfr[2][2] + sfr[2][3]);
      float s3 = (sfr[3][0] + sfr[3][1]) + (sfr[3][2] + sfr[3][3]);
      rs = (s0 + s1) + (s2 + s3);
      rs += __shfl_xor(rs, 16, 64);
      rs += __shfl_xor(rs, 32, 64);
    }
    lrun = lrun * alpha + rs;
#pragma unroll
    for (int nt = 0; nt < 4; ++nt)
#pragma unroll
      for (int r = 0; r < 4; ++r) oacc[nt][r] *= alpha;

    // P[q=lr][k] pack: 2x cvt_pk -> ds_write_b64 per nt (k in-lane contiguous)
#pragma unroll
    for (int nt = 0; nt < 4; ++nt) {
      unsigned w0, w1;
      asm("v_cvt_pk_bf16_f32 %0, %1, %2"
          : "=v"(w0) : "v"(sfr[nt][0]), "v"(sfr[nt][1]));
      asm("v_cvt_pk_bf16_f32 %0, %1, %2"
          : "=v"(w1) : "v"(sfr[nt][2]), "v"(sfr[nt][3]));
      uint2 pk2 = {w0, w1};
      *(uint2*)(pw + lr * 128 + ((nt * 32 + lg * 8) ^ rowswz)) = pk2;
    }

    // O^T += V^T P^T  (A = V^T rows d, B = P^T cols q)
#pragma unroll
    for (int kc = 0; kc < 2; ++kc) {
      short8 pb8 = *(const short8*)(pw + lr * 128 + ((kc * 64 + lg * 16) ^ rowswz));
#pragma unroll
      for (int nt = 0; nt < 4; ++nt) {
        const int vrow = nt * 16 + lr;
        short8 vf = *(const short8*)((const char*)Vsm + vrow * 128 +
                                     (((kc * 4 + lg) ^ (vrow & 7)) << 4));
        oacc[nt] = __builtin_amdgcn_mfma_f32_16x16x32_bf16(vf, pb8, oacc[nt], 0, 0, 0);
      }
    }
    __syncthreads();  // everyone done reading K/V before next staging write
  }

  // epilogue: O^T -> o ; lane (lr,lg): row q = qt*64+qloc, d = nt*16+lg*4..+3
  const float inv = 1.0f / lrun;
  float* ob = o + (size_t)(bh >> 4) * 1024 * 1024 +
              (size_t)(qt * 64 + qloc) * 1024 + (bh & 15) * 64;
#pragma unroll
  for (int nt = 0; nt < 4; ++nt) {
    float4 ov = {oacc[nt][0] * inv, oacc[nt][1] * inv, oacc[nt][2] * inv,
                 oacc[nt][3] * inv};
    *(float4*)&ob[nt * 16 + lg * 4] = ov;
  }
}

// ------------------------------- launcher ----------------------------------
extern "C" void kernel_launch(void* const* d_in, const int* in_sizes, int n_in,
                              void* d_out, int out_size, void* d_ws,
                              size_t ws_size, hipStream_t stream) {
  const float* x = (const float*)d_in[0];
  const float* Wq = (const float*)d_in[1];
  const float* bq = (const float*)d_in[2];
  const float* Wk = (const float*)d_in[3];
  const float* bk = (const float*)d_in[4];
  const float* Wv = (const float*)d_in[5];
  const float* bv = (const float*)d_in[6];
  const float* g1 = (const float*)d_in[7];
  const float* b1 = (const float*)d_in[8];
  const float* g2 = (const float*)d_in[9];
  const float* b2 = (const float*)d_in[10];
  const float* gf = (const float*)d_in[11];
  const float* bfp = (const float*)d_in[12];
  const float* W1 = (const float*)d_in[13];
  const float* b1f = (const float*)d_in[14];
  const float* W2 = (const float*)d_in[15];
  const float* b2f = (const float*)d_in[16];
  float* out = (float*)d_out;

  hipFuncSetAttribute((const void*)gemm8_qkv,
                      hipFuncAttributeMaxDynamicSharedMemorySize, 131072);
  hipFuncSetAttribute((const void*)gemm8_ffn1,
                      hipFuncAttributeMaxDynamicSharedMemorySize, 131072);
  hipFuncSetAttribute((const void*)gemm8_ffn2sk,
                      hipFuncAttributeMaxDynamicSharedMemorySize, 131072);

  const size_t MB = 1024 * 1024;
  char* p = (char*)d_ws;
  // Region A (70MB): dead before gemm8_ffn2sk; 64MB split-K partials alias it.
  float* hbuf = (float*)(p + 0 * MB);      // 16MB  h (f32), dead after ln2f
  short* qbuf = (short*)(p + 16 * MB);     // 8MB   dead after attn
  short* kbuf = (short*)(p + 24 * MB);     // 8MB   dead after attn
  short* vtb = (short*)(p + 32 * MB);      // 8MB   dead after attn
  float* obuf = (float*)(p + 40 * MB);     // 16MB  dead after ln2f
  short* wqkv_t = (short*)(p + 56 * MB);   // 6MB   dead after gemm8_qkv
  short* w1_t = (short*)(p + 62 * MB);     // 8MB   dead after gemm8_ffn1
  float* part = (float*)(p + 0 * MB);      // 64MB  alias
  // Region B (72MB): live through the end.
  char* q = p + 70 * MB;
  short* w2_t = (short*)(q + 0 * MB);      // 8MB
  short* hbb = (short*)(q + 8 * MB);       // 8MB
  float* x3b = (float*)(q + 16 * MB);      // 16MB
  short* hfb = (short*)(q + 32 * MB);      // 8MB
  short* ub = (short*)(q + 40 * MB);       // 32MB

  dim3 tb(32, 8);
  transpose_qkv<<<dim3(2, 32, 48), tb, 0, stream>>>(Wq, Wk, Wv, wqkv_t);
  transpose_to_bf16<<<dim3(128, 32, 1), tb, 0, stream>>>(W1, w1_t, 1024, 4096);
  transpose_to_bf16<<<dim3(32, 128, 1), tb, 0, stream>>>(W2, w2_t, 4096, 1024);

  ln1_kernel<<<4096, 256, 0, stream>>>(x, g1, b1, hbuf, hbb);

  gemm8_qkv<<<dim3(12, 16), 512, 131072, stream>>>(hbb, wqkv_t, bq, bk, bv,
                                                   qbuf, kbuf, vtb);

  attn_kernel<<<dim3(64, 16), 256, 0, stream>>>(qbuf, kbuf, vtb, obuf);

  ln2f_kernel<<<4096, 256, 0, stream>>>(hbuf, obuf, g2, b2, gf, bfp, x3b, hfb);

  gemm8_ffn1<<<dim3(16, 16), 512, 131072, stream>>>(hfb, w1_t, b1f, ub);

  gemm8_ffn2sk<<<dim3(4, 16, 4), 512, 131072, stream>>>(ub, w2_t, part);

  ffn2_reduce<<<4096, 256, 0, stream>>>(part, b2f, hfb, x3b, out);
}

// Round 6
// 197.323 us; speedup vs baseline: 1.4240x; 1.0469x over previous
//
#include <hip/hip_runtime.h>
#include <hip/hip_bf16.h>

// ---------------------------------------------------------------------------
// Decoder block on MI355X. GEMMs: 256x256 / BK=64 / 8-wave 8-phase
// counted-vmcnt schedule (guide §5 template, T2+T3+T4+T5), plain HIP.
// Attention: flash-style with SWAPPED QK^T (mfma(K,Q)); softmax lane-local
// (2 shuffles), P packed via v_cvt_pk_bf16_f32, PV computes O^T = mfma(V,P).
// R6: heavy-first dispatch (qt = 15 - blockIdx.y) to kill the causal-tail,
// T13 defer-max (skip rescale when __all(pm - mrun <= 8), log2 domain).
// ---------------------------------------------------------------------------

typedef __attribute__((ext_vector_type(8))) short short8;
typedef __attribute__((ext_vector_type(4))) short short4v;
typedef __attribute__((ext_vector_type(4))) float f32x4;

#define DEVI static __device__ __forceinline__

#define BAR() __builtin_amdgcn_s_barrier()
#define SB0() __builtin_amdgcn_sched_barrier(0)
#define LGKM0()                                         \
  {                                                     \
    asm volatile("s_waitcnt lgkmcnt(0)" ::: "memory");  \
    __builtin_amdgcn_sched_barrier(0);                  \
  }
#define VMW(n)                                              \
  {                                                         \
    asm volatile("s_waitcnt vmcnt(" #n ")" ::: "memory");   \
    __builtin_amdgcn_sched_barrier(0);                      \
  }

DEVI void gload_lds16(const void* g, void* l) {
  __builtin_amdgcn_global_load_lds(
      (const __attribute__((address_space(1))) void*)g,
      (__attribute__((address_space(3))) void*)l, 16, 0, 0);
}

DEVI float bf2f(short s) {
  union { float f; unsigned u; } cv;
  cv.u = ((unsigned)(unsigned short)s) << 16;
  return cv.f;
}
DEVI short f2bf(float f) {  // round-to-nearest-even
  union { float f; unsigned u; } cv;
  cv.f = f;
  unsigned u = cv.u;
  u += 0x7FFFu + ((u >> 16) & 1u);
  return (short)(u >> 16);
}

DEVI void block_reduce2(float& s, float& s2, float* red, int t) {
#pragma unroll
  for (int off = 1; off < 64; off <<= 1) {
    s += __shfl_xor(s, off, 64);
    s2 += __shfl_xor(s2, off, 64);
  }
  __syncthreads();
  if ((t & 63) == 0) { red[(t >> 6) * 2] = s; red[(t >> 6) * 2 + 1] = s2; }
  __syncthreads();
  s = red[0] + red[2] + red[4] + red[6];
  s2 = red[1] + red[3] + red[5] + red[7];
}

// --------------------------- transpose f32 -> bf16 -------------------------
__global__ __launch_bounds__(256) void transpose_to_bf16(
    const float* __restrict__ in, short* __restrict__ out, int R, int C) {
  __shared__ float tile[32][33];
  const int b = blockIdx.z;
  in += (size_t)b * R * C;
  out += (size_t)b * R * C;
  const int r0 = blockIdx.y * 32, c0 = blockIdx.x * 32;
  const int tx = threadIdx.x, ty = threadIdx.y;
#pragma unroll
  for (int i = 0; i < 32; i += 8)
    tile[ty + i][tx] = in[(size_t)(r0 + ty + i) * C + c0 + tx];
  __syncthreads();
#pragma unroll
  for (int i = 0; i < 32; i += 8)
    out[(size_t)(c0 + ty + i) * R + r0 + tx] = f2bf(tile[tx][ty + i]);
}

// Wq/Wk/Wv merged: each [16][1024][64] -> wqkv_t [3][16][64][1024]
__global__ __launch_bounds__(256) void transpose_qkv(
    const float* __restrict__ Wq, const float* __restrict__ Wk,
    const float* __restrict__ Wv, short* __restrict__ out) {
  __shared__ float tile[32][33];
  const int z = blockIdx.z;  // 0..47
  const int sel = z >> 4, b = z & 15;
  const float* in = (sel == 0) ? Wq : (sel == 1) ? Wk : Wv;
  in += (size_t)b * 1024 * 64;
  short* o = out + (size_t)sel * 1024 * 1024 + (size_t)b * 1024 * 64;
  const int r0 = blockIdx.y * 32, c0 = blockIdx.x * 32;
  const int tx = threadIdx.x, ty = threadIdx.y;
#pragma unroll
  for (int i = 0; i < 32; i += 8)
    tile[ty + i][tx] = in[(size_t)(r0 + ty + i) * 64 + c0 + tx];
  __syncthreads();
#pragma unroll
  for (int i = 0; i < 32; i += 8)
    o[(size_t)(c0 + ty + i) * 1024 + r0 + tx] = f2bf(tile[tx][ty + i]);
}

// ------------------------------- LayerNorms --------------------------------
__global__ __launch_bounds__(256) void ln1_kernel(
    const float* __restrict__ x, const float* __restrict__ g,
    const float* __restrict__ b, float* __restrict__ hf,
    short* __restrict__ hb) {
  __shared__ float red[8];
  const int row = blockIdx.x, t = threadIdx.x;
  float4 v = ((const float4*)(x + (size_t)row * 1024))[t];
  float s = v.x + v.y + v.z + v.w;
  float s2 = v.x * v.x + v.y * v.y + v.z * v.z + v.w * v.w;
  block_reduce2(s, s2, red, t);
  const float mu = s * (1.0f / 1024.0f);
  const float rstd = rsqrtf(s2 * (1.0f / 1024.0f) - mu * mu + 1e-5f);
  float4 gv = ((const float4*)g)[t], bv = ((const float4*)b)[t];
  float4 o;
  o.x = (v.x - mu) * rstd * gv.x + bv.x;
  o.y = (v.y - mu) * rstd * gv.y + bv.y;
  o.z = (v.z - mu) * rstd * gv.z + bv.z;
  o.w = (v.w - mu) * rstd * gv.w + bv.w;
  ((float4*)(hf + (size_t)row * 1024))[t] = o;
  short4v p = {f2bf(o.x), f2bf(o.y), f2bf(o.z), f2bf(o.w)};
  ((short4v*)(hb + (size_t)row * 1024))[t] = p;
}

__global__ __launch_bounds__(256) void ln2f_kernel(
    const float* __restrict__ h, const float* __restrict__ o,
    const float* __restrict__ g2, const float* __restrict__ b2,
    const float* __restrict__ gf, const float* __restrict__ bfp,
    float* __restrict__ x3, short* __restrict__ hfb) {
  __shared__ float red[8];
  const int row = blockIdx.x, t = threadIdx.x;
  float4 hv = ((const float4*)(h + (size_t)row * 1024))[t];
  float4 ov = ((const float4*)(o + (size_t)row * 1024))[t];
  float4 v;
  v.x = hv.x + ov.x; v.y = hv.y + ov.y; v.z = hv.z + ov.z; v.w = hv.w + ov.w;
  float s = v.x + v.y + v.z + v.w;
  float s2 = v.x * v.x + v.y * v.y + v.z * v.z + v.w * v.w;
  block_reduce2(s, s2, red, t);
  float mu = s * (1.0f / 1024.0f);
  float rstd = rsqrtf(s2 * (1.0f / 1024.0f) - mu * mu + 1e-5f);
  float4 gv = ((const float4*)g2)[t], bv = ((const float4*)b2)[t];
  float4 xv;
  xv.x = (v.x - mu) * rstd * gv.x + bv.x;
  xv.y = (v.y - mu) * rstd * gv.y + bv.y;
  xv.z = (v.z - mu) * rstd * gv.z + bv.z;
  xv.w = (v.w - mu) * rstd * gv.w + bv.w;
  ((float4*)(x3 + (size_t)row * 1024))[t] = xv;
  s = xv.x + xv.y + xv.z + xv.w;
  s2 = xv.x * xv.x + xv.y * xv.y + xv.z * xv.z + xv.w * xv.w;
  block_reduce2(s, s2, red, t);
  mu = s * (1.0f / 1024.0f);
  rstd = rsqrtf(s2 * (1.0f / 1024.0f) - mu * mu + 1e-5f);
  float4 gv2 = ((const float4*)gf)[t], bv2 = ((const float4*)bfp)[t];
  short4v pk = {f2bf((xv.x - mu) * rstd * gv2.x + bv2.x),
                f2bf((xv.y - mu) * rstd * gv2.y + bv2.y),
                f2bf((xv.z - mu) * rstd * gv2.z + bv2.z),
                f2bf((xv.w - mu) * rstd * gv2.w + bv2.w)};
  ((short4v*)(hfb + (size_t)row * 1024))[t] = pk;
}

// --------------------- 256x256 8-phase GEMM core ---------------------------
template <int EPI>
DEVI void gemm8_body(const short* __restrict__ A, const short* __restrict__ B,
                     int K, int kbase, int m0, int n0,
                     const float* __restrict__ f0, const float* __restrict__ f1,
                     const float* __restrict__ f2, short* __restrict__ s0,
                     short* __restrict__ s1, short* __restrict__ s2,
                     float* __restrict__ fo) {
  extern __shared__ __align__(16) char lds[];  // 131072 B
  constexpr int NT = 16;
  const int tid = threadIdx.x;
  const int l = tid & 63, w = tid >> 6;
  const int wrM = w >> 2, wcN = w & 3;
  const int lr = l & 15, lg = l >> 4;

  const int cswz = (((lr & 1) << 2) | lg) ^ (lr >> 1);
  const int laneoff = ((lr >> 1) << 7) + (cswz << 4);

  const int rsel = l >> 3;
  const int scz = (l & 7) ^ rsel;
  const int s_roff = w * 16 + rsel * 2 + (scz >> 2);
  const int s_kc = (scz & 3) * 8;
  const short* Asrc = A + (size_t)(m0 + s_roff) * K + kbase + s_kc;
  const short* Bsrc = B + (size_t)(n0 + s_roff) * K + kbase + s_kc;
  const size_t rstep = (size_t)128 * K;

  auto STAGE = [&](int op, int kh, int t) {
    const short* g = (op ? Bsrc : Asrc) + t * 64 + kh * 32;
    char* d = lds + ((t & 1) * 65536 + op * 32768 + kh * 16384 + w * 1024);
    gload_lds16(g, d);
    gload_lds16(g + rstep, d + 8192);
  };

  f32x4 acc[8][4] = {};

  STAGE(0, 0, 0); STAGE(1, 0, 0); STAGE(0, 1, 0); STAGE(1, 1, 0);
  VMW(4); BAR(); SB0();

  for (int t = 0; t < NT; ++t) {
    const char* pa = lds + (t & 1) * 65536 + wrM * 8192 + laneoff;
    const char* pb = lds + (t & 1) * 65536 + 32768 + wcN * 4096 + laneoff;
    const bool st = (t + 1) < NT;
    short8 a[8], b[4];

#pragma unroll
    for (int mt = 0; mt < 8; ++mt) a[mt] = *(const short8*)(pa + mt * 1024);
    b[0] = *(const short8*)(pb);
    b[1] = *(const short8*)(pb + 1024);
    if (st) STAGE(0, 0, t + 1);
    BAR(); LGKM0();
    __builtin_amdgcn_s_setprio(1);
#pragma unroll
    for (int mt = 0; mt < 8; ++mt) {
      acc[mt][0] = __builtin_amdgcn_mfma_f32_16x16x32_bf16(a[mt], b[0], acc[mt][0], 0, 0, 0);
      acc[mt][1] = __builtin_amdgcn_mfma_f32_16x16x32_bf16(a[mt], b[1], acc[mt][1], 0, 0, 0);
    }
    __builtin_amdgcn_s_setprio(0);
    BAR(); SB0();

    b[2] = *(const short8*)(pb + 2048);
    b[3] = *(const short8*)(pb + 3072);
    if (st) STAGE(1, 0, t + 1);
    BAR(); LGKM0();
    __builtin_amdgcn_s_setprio(1);
#pragma unroll
    for (int mt = 0; mt < 8; ++mt) {
      acc[mt][2] = __builtin_amdgcn_mfma_f32_16x16x32_bf16(a[mt], b[2], acc[mt][2], 0, 0, 0);
      acc[mt][3] = __builtin_amdgcn_mfma_f32_16x16x32_bf16(a[mt], b[3], acc[mt][3], 0, 0, 0);
    }
    __builtin_amdgcn_s_setprio(0);
    if (st) { VMW(4); } else { VMW(0); }
    BAR(); SB0();

    pa += 16384; pb += 16384;
#pragma unroll
    for (int mt = 0; mt < 8; ++mt) a[mt] = *(const short8*)(pa + mt * 1024);
    b[0] = *(const short8*)(pb);
    b[1] = *(const short8*)(pb + 1024);
    if (st) STAGE(0, 1, t + 1);
    BAR(); LGKM0();
    __builtin_amdgcn_s_setprio(1);
#pragma unroll
    for (int mt = 0; mt < 8; ++mt) {
      acc[mt][0] = __builtin_amdgcn_mfma_f32_16x16x32_bf16(a[mt], b[0], acc[mt][0], 0, 0, 0);
      acc[mt][1] = __builtin_amdgcn_mfma_f32_16x16x32_bf16(a[mt], b[1], acc[mt][1], 0, 0, 0);
    }
    __builtin_amdgcn_s_setprio(0);
    BAR(); SB0();

    b[2] = *(const short8*)(pb + 2048);
    b[3] = *(const short8*)(pb + 3072);
    if (st) STAGE(1, 1, t + 1);
    BAR(); LGKM0();
    __builtin_amdgcn_s_setprio(1);
#pragma unroll
    for (int mt = 0; mt < 8; ++mt) {
      acc[mt][2] = __builtin_amdgcn_mfma_f32_16x16x32_bf16(a[mt], b[2], acc[mt][2], 0, 0, 0);
      acc[mt][3] = __builtin_amdgcn_mfma_f32_16x16x32_bf16(a[mt], b[3], acc[mt][3], 0, 0, 0);
    }
    __builtin_amdgcn_s_setprio(0);
    if (st) VMW(4);
    BAR(); SB0();
  }

#pragma unroll
  for (int mt = 0; mt < 8; ++mt) {
#pragma unroll
    for (int nt = 0; nt < 4; ++nt) {
      const int col = n0 + wcN * 64 + nt * 16 + lr;
      const int row0 = m0 + wrM * 128 + mt * 16 + lg * 4;
      if constexpr (EPI == 0) {  // QKV scatter
        const int sel = col >> 10, nn = col & 1023;
        const int hh = nn >> 6, dd = nn & 63;
        const int bb = row0 >> 10, tt0 = row0 & 1023;
        if (sel == 2) {
          const float bias = f2[nn];
          short4v pk = {f2bf(acc[mt][nt][0] + bias), f2bf(acc[mt][nt][1] + bias),
                        f2bf(acc[mt][nt][2] + bias), f2bf(acc[mt][nt][3] + bias)};
          *(short4v*)&s2[(((size_t)(bb * 16 + hh)) * 64 + dd) * 1024 + tt0] = pk;
        } else {
          const float bias = (sel == 0) ? f0[nn] : f1[nn];
          short* dst = (sel == 0) ? s0 : s1;
#pragma unroll
          for (int r = 0; r < 4; ++r)
            dst[(((size_t)(bb * 16 + hh)) * 1024 + tt0 + r) * 64 + dd] =
                f2bf(acc[mt][nt][r] + bias);
        }
      } else if constexpr (EPI == 1) {  // FFN1 bias+relu -> bf16
#pragma unroll
        for (int r = 0; r < 4; ++r) {
          float val = fmaxf(acc[mt][nt][r] + f0[col], 0.0f);
          s0[(size_t)(row0 + r) * 4096 + col] = f2bf(val);
        }
      } else {  // split-K partials f32
#pragma unroll
        for (int r = 0; r < 4; ++r)
          fo[(size_t)(row0 + r) * 1024 + col] = acc[mt][nt][r];
      }
    }
  }
}

__global__ __launch_bounds__(512, 2) void gemm8_qkv(
    const short* __restrict__ A, const short* __restrict__ B,
    const float* __restrict__ bq, const float* __restrict__ bk,
    const float* __restrict__ bv, short* __restrict__ q,
    short* __restrict__ k, short* __restrict__ vt) {
  gemm8_body<0>(A, B, 1024, 0, blockIdx.y * 256, blockIdx.x * 256, bq, bk, bv,
                q, k, vt, nullptr);
}

__global__ __launch_bounds__(512, 2) void gemm8_ffn1(
    const short* __restrict__ A, const short* __restrict__ B,
    const float* __restrict__ b1f, short* __restrict__ u) {
  gemm8_body<1>(A, B, 1024, 0, blockIdx.y * 256, blockIdx.x * 256, b1f,
                nullptr, nullptr, u, nullptr, nullptr, nullptr);
}

__global__ __launch_bounds__(512, 2) void gemm8_ffn2sk(
    const short* __restrict__ A, const short* __restrict__ B,
    float* __restrict__ part) {
  const int z = blockIdx.z;
  gemm8_body<2>(A, B, 4096, z * 1024, blockIdx.y * 256, blockIdx.x * 256,
                nullptr, nullptr, nullptr, nullptr, nullptr, nullptr,
                part + (size_t)z * 4096 * 1024);
}

// out = sum_z part[z] + b2f + hf + x3
__global__ __launch_bounds__(256) void ffn2_reduce(
    const float* __restrict__ part, const float* __restrict__ b2f,
    const short* __restrict__ hfb, const float* __restrict__ x3,
    float* __restrict__ out) {
  const size_t i = (size_t)blockIdx.x * 256 + threadIdx.x;
  const size_t S = (size_t)4096 * 1024 / 4;
  float4 a0 = ((const float4*)part)[i];
  float4 a1 = ((const float4*)part)[i + S];
  float4 a2 = ((const float4*)part)[i + 2 * S];
  float4 a3 = ((const float4*)part)[i + 3 * S];
  float4 bb = ((const float4*)b2f)[i & 255];
  float4 xv = ((const float4*)x3)[i];
  short4v hv = ((const short4v*)hfb)[i];
  float4 o;
  o.x = a0.x + a1.x + a2.x + a3.x + bb.x + bf2f(hv.x) + xv.x;
  o.y = a0.y + a1.y + a2.y + a3.y + bb.y + bf2f(hv.y) + xv.y;
  o.z = a0.z + a1.z + a2.z + a3.z + bb.z + bf2f(hv.z) + xv.z;
  o.w = a0.w + a1.w + a2.w + a3.w + bb.w + bf2f(hv.w) + xv.w;
  ((float4*)out)[i] = o;
}

// ----------------------------- flash attention -----------------------------
// q,k: [64 bh][1024][64] bf16 ; vt: [64 bh][64 d][1024 t] bf16 ;
// o: [4][1024][1024] f32. Block = (bh, 64-row q-tile), 4 waves x 16 q-rows.
// SWAPPED QK^T: S^T = mfma(K,Q) -> lane (lr,lg) holds q=lr, k=nt*16+lg*4+r.
// Heavy-first: qt = 15 - blockIdx.y (kills the causal dispatch tail).
// T13 defer-max: skip rescale when __all(pm - mrun <= 8) (log2 domain).
__global__ __launch_bounds__(256, 5) void attn_kernel(
    const short* __restrict__ q, const short* __restrict__ k,
    const short* __restrict__ vt, float* __restrict__ o) {
  __shared__ __align__(16) short Ksm[64 * 64];
  __shared__ __align__(16) short Vsm[64 * 64];
  __shared__ __align__(16) short Psm[4 * 16 * 64];
  const int bh = blockIdx.x;
  const int qt = 15 - blockIdx.y;  // heavy blocks dispatch FIRST
  const int tid = threadIdx.x, lane = tid & 63, w = tid >> 6;
  const int lr = lane & 15, lg = lane >> 4;

  const short* qb = q + (size_t)bh * 1024 * 64;
  const short* kb = k + (size_t)bh * 1024 * 64;
  const short* vb = vt + (size_t)bh * 64 * 1024;

  const int qrow = qt * 64 + w * 16 + lr;
  short8 qf0 = *(const short8*)&qb[(size_t)qrow * 64 + lg * 8];
  short8 qf1 = *(const short8*)&qb[(size_t)qrow * 64 + 32 + lg * 8];

  f32x4 oacc[4] = {};       // O^T frags: col q=lr, row d=nt*16+lg*4+r
  float mrun = -1e30f, lrun = 0.0f;  // per-lane: this lane's q-row

  const float scale2 = 0.03125f * 1.44269504088896f;  // (1/sqrt(C))*log2(e)
  const int srow = tid >> 3;  // staging row 0..31 (+32 on second chunk)
  const int sc8 = tid & 7;    // 16B chunk within 128B row
  char* pw = (char*)(Psm + w * 1024);  // per-wave 16x64 P tile
  const int qloc = w * 16 + lr;        // q-row local to 64-row block
  const int rowswz = (lr & 7) << 4;    // P row XOR swizzle

  short8 kreg[2], vreg[2];
  // prologue: KV tile 0 -> regs
#pragma unroll
  for (int p = 0; p < 2; ++p) {
    const int rr = srow + p * 32;
    kreg[p] = *(const short8*)&kb[(size_t)rr * 64 + sc8 * 8];
    vreg[p] = *(const short8*)&vb[(size_t)rr * 1024 + sc8 * 8];
  }

  for (int kt = 0; kt <= qt; ++kt) {
    // write staged regs -> LDS
#pragma unroll
    for (int p = 0; p < 2; ++p) {
      const int rr = srow + p * 32;
      *(short8*)((char*)Ksm + rr * 128 + ((sc8 ^ (rr & 7)) << 4)) = kreg[p];
      *(short8*)((char*)Vsm + rr * 128 + ((sc8 ^ (rr & 7)) << 4)) = vreg[p];
    }
    __syncthreads();
    // issue next tile's global loads now; latency hides under compute
    if (kt < qt) {
#pragma unroll
      for (int p = 0; p < 2; ++p) {
        const int rr = srow + p * 32;
        kreg[p] =
            *(const short8*)&kb[((size_t)((kt + 1) * 64 + rr)) * 64 + sc8 * 8];
        vreg[p] =
            *(const short8*)&vb[(size_t)rr * 1024 + (kt + 1) * 64 + sc8 * 8];
      }
    }

    // S^T = K Q^T : lane (lr,lg) gets q=lr, k = nt*16 + lg*4 + r
    f32x4 sfr[4];
#pragma unroll
    for (int nt = 0; nt < 4; ++nt) {
      const int krow = nt * 16 + lr;
      short8 kf0 = *(const short8*)((const char*)Ksm + krow * 128 +
                                    (((0 + lg) ^ (krow & 7)) << 4));
      short8 kf1 = *(const short8*)((const char*)Ksm + krow * 128 +
                                    (((4 + lg) ^ (krow & 7)) << 4));
      f32x4 z = {};
      z = __builtin_amdgcn_mfma_f32_16x16x32_bf16(kf0, qf0, z, 0, 0, 0);
      z = __builtin_amdgcn_mfma_f32_16x16x32_bf16(kf1, qf1, z, 0, 0, 0);
      sfr[nt] = z;
    }
    // scale + causal mask (k_local <= q_local on the diagonal tile)
    if (kt == qt) {
#pragma unroll
      for (int nt = 0; nt < 4; ++nt) {
        const int kb0 = nt * 16 + lg * 4;
#pragma unroll
        for (int r = 0; r < 4; ++r)
          sfr[nt][r] = (kb0 + r <= qloc) ? sfr[nt][r] * scale2 : -1e30f;
      }
    } else {
#pragma unroll
      for (int nt = 0; nt < 4; ++nt)
#pragma unroll
        for (int r = 0; r < 4; ++r) sfr[nt][r] *= scale2;
    }
    // in-lane max tree (16 values) + 2 shuffles across lg groups
    float pm;
    {
      float a0 = fmaxf(fmaxf(sfr[0][0], sfr[0][1]), fmaxf(sfr[0][2], sfr[0][3]));
      float a1 = fmaxf(fmaxf(sfr[1][0], sfr[1][1]), fmaxf(sfr[1][2], sfr[1][3]));
      float a2 = fmaxf(fmaxf(sfr[2][0], sfr[2][1]), fmaxf(sfr[2][2], sfr[2][3]));
      float a3 = fmaxf(fmaxf(sfr[3][0], sfr[3][1]), fmaxf(sfr[3][2], sfr[3][3]));
      pm = fmaxf(fmaxf(a0, a1), fmaxf(a2, a3));
      pm = fmaxf(pm, __shfl_xor(pm, 16, 64));
      pm = fmaxf(pm, __shfl_xor(pm, 32, 64));
    }
    // T13 defer-max: only rescale when the running max grew materially.
    // Skipped => P bounded by 2^8 (log2 domain), fine in f32 accum.
    if (!__all(pm - mrun <= 8.0f)) {
      const float mnew = fmaxf(mrun, pm);
      const float alpha = exp2f(mrun - mnew);
      mrun = mnew;
      lrun *= alpha;
#pragma unroll
      for (int nt = 0; nt < 4; ++nt)
#pragma unroll
        for (int r = 0; r < 4; ++r) oacc[nt][r] *= alpha;
    }
    // p = exp2(s - m), in-lane sum tree
    float rs;
    {
#pragma unroll
      for (int nt = 0; nt < 4; ++nt)
#pragma unroll
        for (int r = 0; r < 4; ++r) sfr[nt][r] = exp2f(sfr[nt][r] - mrun);
      float s0 = (sfr[0][0] + sfr[0][1]) + (sfr[0][2] + sfr[0][3]);
      float s1 = (sfr[1][0] + sfr[1][1]) + (sfr[1][2] + sfr[1][3]);
      float s2 = (sfr[2][0] + sfr[2][1]) + (sfr[2][2] + sfr[2][3]);
      float s3 = (sfr[3][0] + sfr[3][1]) + (sfr[3][2] + sfr[3][3]);
      rs = (s0 + s1) + (s2 + s3);
      rs += __shfl_xor(rs, 16, 64);
      rs += __shfl_xor(rs, 32, 64);
    }
    lrun += rs;

    // P[q=lr][k] pack: 2x cvt_pk -> ds_write_b64 per nt (k in-lane contiguous)
#pragma unroll
    for (int nt = 0; nt < 4; ++nt) {
      unsigned w0, w1;
      asm("v_cvt_pk_bf16_f32 %0, %1, %2"
          : "=v"(w0) : "v"(sfr[nt][0]), "v"(sfr[nt][1]));
      asm("v_cvt_pk_bf16_f32 %0, %1, %2"
          : "=v"(w1) : "v"(sfr[nt][2]), "v"(sfr[nt][3]));
      uint2 pk2 = {w0, w1};
      *(uint2*)(pw + lr * 128 + ((nt * 32 + lg * 8) ^ rowswz)) = pk2;
    }

    // O^T += V^T P^T  (A = V^T rows d, B = P^T cols q)
#pragma unroll
    for (int kc = 0; kc < 2; ++kc) {
      short8 pb8 = *(const short8*)(pw + lr * 128 + ((kc * 64 + lg * 16) ^ rowswz));
#pragma unroll
      for (int nt = 0; nt < 4; ++nt) {
        const int vrow = nt * 16 + lr;
        short8 vf = *(const short8*)((const char*)Vsm + vrow * 128 +
                                     (((kc * 4 + lg) ^ (vrow & 7)) << 4));
        oacc[nt] = __builtin_amdgcn_mfma_f32_16x16x32_bf16(vf, pb8, oacc[nt], 0, 0, 0);
      }
    }
    __syncthreads();  // everyone done reading K/V before next staging write
  }

  // epilogue: O^T -> o ; lane (lr,lg): row q = qt*64+qloc, d = nt*16+lg*4..+3
  const float inv = 1.0f / lrun;
  float* ob = o + (size_t)(bh >> 4) * 1024 * 1024 +
              (size_t)(qt * 64 + qloc) * 1024 + (bh & 15) * 64;
#pragma unroll
  for (int nt = 0; nt < 4; ++nt) {
    float4 ov = {oacc[nt][0] * inv, oacc[nt][1] * inv, oacc[nt][2] * inv,
                 oacc[nt][3] * inv};
    *(float4*)&ob[nt * 16 + lg * 4] = ov;
  }
}

// ------------------------------- launcher ----------------------------------
extern "C" void kernel_launch(void* const* d_in, const int* in_sizes, int n_in,
                              void* d_out, int out_size, void* d_ws,
                              size_t ws_size, hipStream_t stream) {
  const float* x = (const float*)d_in[0];
  const float* Wq = (const float*)d_in[1];
  const float* bq = (const float*)d_in[2];
  const float* Wk = (const float*)d_in[3];
  const float* bk = (const float*)d_in[4];
  const float* Wv = (const float*)d_in[5];
  const float* bv = (const float*)d_in[6];
  const float* g1 = (const float*)d_in[7];
  const float* b1 = (const float*)d_in[8];
  const float* g2 = (const float*)d_in[9];
  const float* b2 = (const float*)d_in[10];
  const float* gf = (const float*)d_in[11];
  const float* bfp = (const float*)d_in[12];
  const float* W1 = (const float*)d_in[13];
  const float* b1f = (const float*)d_in[14];
  const float* W2 = (const float*)d_in[15];
  const float* b2f = (const float*)d_in[16];
  float* out = (float*)d_out;

  hipFuncSetAttribute((const void*)gemm8_qkv,
                      hipFuncAttributeMaxDynamicSharedMemorySize, 131072);
  hipFuncSetAttribute((const void*)gemm8_ffn1,
                      hipFuncAttributeMaxDynamicSharedMemorySize, 131072);
  hipFuncSetAttribute((const void*)gemm8_ffn2sk,
                      hipFuncAttributeMaxDynamicSharedMemorySize, 131072);

  const size_t MB = 1024 * 1024;
  char* p = (char*)d_ws;
  // Region A (70MB): dead before gemm8_ffn2sk; 64MB split-K partials alias it.
  float* hbuf = (float*)(p + 0 * MB);      // 16MB  h (f32), dead after ln2f
  short* qbuf = (short*)(p + 16 * MB);     // 8MB   dead after attn
  short* kbuf = (short*)(p + 24 * MB);     // 8MB   dead after attn
  short* vtb = (short*)(p + 32 * MB);      // 8MB   dead after attn
  float* obuf = (float*)(p + 40 * MB);     // 16MB  dead after ln2f
  short* wqkv_t = (short*)(p + 56 * MB);   // 6MB   dead after gemm8_qkv
  short* w1_t = (short*)(p + 62 * MB);     // 8MB   dead after gemm8_ffn1
  float* part = (float*)(p + 0 * MB);      // 64MB  alias
  // Region B (72MB): live through the end.
  char* q = p + 70 * MB;
  short* w2_t = (short*)(q + 0 * MB);      // 8MB
  short* hbb = (short*)(q + 8 * MB);       // 8MB
  float* x3b = (float*)(q + 16 * MB);      // 16MB
  short* hfb = (short*)(q + 32 * MB);      // 8MB
  short* ub = (short*)(q + 40 * MB);       // 32MB

  dim3 tb(32, 8);
  transpose_qkv<<<dim3(2, 32, 48), tb, 0, stream>>>(Wq, Wk, Wv, wqkv_t);
  transpose_to_bf16<<<dim3(128, 32, 1), tb, 0, stream>>>(W1, w1_t, 1024, 4096);
  transpose_to_bf16<<<dim3(32, 128, 1), tb, 0, stream>>>(W2, w2_t, 4096, 1024);

  ln1_kernel<<<4096, 256, 0, stream>>>(x, g1, b1, hbuf, hbb);

  gemm8_qkv<<<dim3(12, 16), 512, 131072, stream>>>(hbb, wqkv_t, bq, bk, bv,
                                                   qbuf, kbuf, vtb);

  attn_kernel<<<dim3(64, 16), 256, 0, stream>>>(qbuf, kbuf, vtb, obuf);

  ln2f_kernel<<<4096, 256, 0, stream>>>(hbuf, obuf, g2, b2, gf, bfp, x3b, hfb);

  gemm8_ffn1<<<dim3(16, 16), 512, 131072, stream>>>(hfb, w1_t, b1f, ub);

  gemm8_ffn2sk<<<dim3(4, 16, 4), 512, 131072, stream>>>(ub, w2_t, part);

  ffn2_reduce<<<4096, 256, 0, stream>>>(part, b2f, hfb, x3b, out);
}

// Round 7
// 195.869 us; speedup vs baseline: 1.4345x; 1.0074x over previous
//
#include <hip/hip_runtime.h>
#include <hip/hip_bf16.h>

// ---------------------------------------------------------------------------
// Decoder block on MI355X. GEMMs: 256x256 / BK=64 / 8-wave 8-phase
// counted-vmcnt schedule; R7: reads-upfront phases (phases 2/4 pure-MFMA,
// one lgkm drain per K-half) + bijective XCD swizzle on GEMM grids (T1).
// Attention: swapped-QK^T flash (R5) + heavy-first dispatch + defer-max (R6).
// ---------------------------------------------------------------------------

typedef __attribute__((ext_vector_type(8))) short short8;
typedef __attribute__((ext_vector_type(4))) short short4v;
typedef __attribute__((ext_vector_type(4))) float f32x4;

#define DEVI static __device__ __forceinline__

#define BAR() __builtin_amdgcn_s_barrier()
#define SB0() __builtin_amdgcn_sched_barrier(0)
#define LGKM0()                                         \
  {                                                     \
    asm volatile("s_waitcnt lgkmcnt(0)" ::: "memory");  \
    __builtin_amdgcn_sched_barrier(0);                  \
  }
#define VMW(n)                                              \
  {                                                         \
    asm volatile("s_waitcnt vmcnt(" #n ")" ::: "memory");   \
    __builtin_amdgcn_sched_barrier(0);                      \
  }

DEVI void gload_lds16(const void* g, void* l) {
  __builtin_amdgcn_global_load_lds(
      (const __attribute__((address_space(1))) void*)g,
      (__attribute__((address_space(3))) void*)l, 16, 0, 0);
}

DEVI float bf2f(short s) {
  union { float f; unsigned u; } cv;
  cv.u = ((unsigned)(unsigned short)s) << 16;
  return cv.f;
}
DEVI short f2bf(float f) {  // round-to-nearest-even
  union { float f; unsigned u; } cv;
  cv.f = f;
  unsigned u = cv.u;
  u += 0x7FFFu + ((u >> 16) & 1u);
  return (short)(u >> 16);
}

DEVI void block_reduce2(float& s, float& s2, float* red, int t) {
#pragma unroll
  for (int off = 1; off < 64; off <<= 1) {
    s += __shfl_xor(s, off, 64);
    s2 += __shfl_xor(s2, off, 64);
  }
  __syncthreads();
  if ((t & 63) == 0) { red[(t >> 6) * 2] = s; red[(t >> 6) * 2 + 1] = s2; }
  __syncthreads();
  s = red[0] + red[2] + red[4] + red[6];
  s2 = red[1] + red[3] + red[5] + red[7];
}

// bijective XCD swizzle: nwg must be divisible by 8 (all our GEMM grids are).
DEVI void xcd_swz(int gx, int gy, int& bx, int& by) {
  const int flat = blockIdx.y * gx + blockIdx.x;
  const int c = (gx * gy) >> 3;
  const int nf = (flat & 7) * c + (flat >> 3);
  bx = nf % gx;
  by = nf / gx;
}

// --------------------------- transpose f32 -> bf16 -------------------------
__global__ __launch_bounds__(256) void transpose_to_bf16(
    const float* __restrict__ in, short* __restrict__ out, int R, int C) {
  __shared__ float tile[32][33];
  const int b = blockIdx.z;
  in += (size_t)b * R * C;
  out += (size_t)b * R * C;
  const int r0 = blockIdx.y * 32, c0 = blockIdx.x * 32;
  const int tx = threadIdx.x, ty = threadIdx.y;
#pragma unroll
  for (int i = 0; i < 32; i += 8)
    tile[ty + i][tx] = in[(size_t)(r0 + ty + i) * C + c0 + tx];
  __syncthreads();
#pragma unroll
  for (int i = 0; i < 32; i += 8)
    out[(size_t)(c0 + ty + i) * R + r0 + tx] = f2bf(tile[tx][ty + i]);
}

// Wq/Wk/Wv merged: each [16][1024][64] -> wqkv_t [3][16][64][1024]
__global__ __launch_bounds__(256) void transpose_qkv(
    const float* __restrict__ Wq, const float* __restrict__ Wk,
    const float* __restrict__ Wv, short* __restrict__ out) {
  __shared__ float tile[32][33];
  const int z = blockIdx.z;  // 0..47
  const int sel = z >> 4, b = z & 15;
  const float* in = (sel == 0) ? Wq : (sel == 1) ? Wk : Wv;
  in += (size_t)b * 1024 * 64;
  short* o = out + (size_t)sel * 1024 * 1024 + (size_t)b * 1024 * 64;
  const int r0 = blockIdx.y * 32, c0 = blockIdx.x * 32;
  const int tx = threadIdx.x, ty = threadIdx.y;
#pragma unroll
  for (int i = 0; i < 32; i += 8)
    tile[ty + i][tx] = in[(size_t)(r0 + ty + i) * 64 + c0 + tx];
  __syncthreads();
#pragma unroll
  for (int i = 0; i < 32; i += 8)
    o[(size_t)(c0 + ty + i) * 1024 + r0 + tx] = f2bf(tile[tx][ty + i]);
}

// ------------------------------- LayerNorms --------------------------------
__global__ __launch_bounds__(256) void ln1_kernel(
    const float* __restrict__ x, const float* __restrict__ g,
    const float* __restrict__ b, float* __restrict__ hf,
    short* __restrict__ hb) {
  __shared__ float red[8];
  const int row = blockIdx.x, t = threadIdx.x;
  float4 v = ((const float4*)(x + (size_t)row * 1024))[t];
  float s = v.x + v.y + v.z + v.w;
  float s2 = v.x * v.x + v.y * v.y + v.z * v.z + v.w * v.w;
  block_reduce2(s, s2, red, t);
  const float mu = s * (1.0f / 1024.0f);
  const float rstd = rsqrtf(s2 * (1.0f / 1024.0f) - mu * mu + 1e-5f);
  float4 gv = ((const float4*)g)[t], bv = ((const float4*)b)[t];
  float4 o;
  o.x = (v.x - mu) * rstd * gv.x + bv.x;
  o.y = (v.y - mu) * rstd * gv.y + bv.y;
  o.z = (v.z - mu) * rstd * gv.z + bv.z;
  o.w = (v.w - mu) * rstd * gv.w + bv.w;
  ((float4*)(hf + (size_t)row * 1024))[t] = o;
  short4v p = {f2bf(o.x), f2bf(o.y), f2bf(o.z), f2bf(o.w)};
  ((short4v*)(hb + (size_t)row * 1024))[t] = p;
}

__global__ __launch_bounds__(256) void ln2f_kernel(
    const float* __restrict__ h, const float* __restrict__ o,
    const float* __restrict__ g2, const float* __restrict__ b2,
    const float* __restrict__ gf, const float* __restrict__ bfp,
    float* __restrict__ x3, short* __restrict__ hfb) {
  __shared__ float red[8];
  const int row = blockIdx.x, t = threadIdx.x;
  float4 hv = ((const float4*)(h + (size_t)row * 1024))[t];
  float4 ov = ((const float4*)(o + (size_t)row * 1024))[t];
  float4 v;
  v.x = hv.x + ov.x; v.y = hv.y + ov.y; v.z = hv.z + ov.z; v.w = hv.w + ov.w;
  float s = v.x + v.y + v.z + v.w;
  float s2 = v.x * v.x + v.y * v.y + v.z * v.z + v.w * v.w;
  block_reduce2(s, s2, red, t);
  float mu = s * (1.0f / 1024.0f);
  float rstd = rsqrtf(s2 * (1.0f / 1024.0f) - mu * mu + 1e-5f);
  float4 gv = ((const float4*)g2)[t], bv = ((const float4*)b2)[t];
  float4 xv;
  xv.x = (v.x - mu) * rstd * gv.x + bv.x;
  xv.y = (v.y - mu) * rstd * gv.y + bv.y;
  xv.z = (v.z - mu) * rstd * gv.z + bv.z;
  xv.w = (v.w - mu) * rstd * gv.w + bv.w;
  ((float4*)(x3 + (size_t)row * 1024))[t] = xv;
  s = xv.x + xv.y + xv.z + xv.w;
  s2 = xv.x * xv.x + xv.y * xv.y + xv.z * xv.z + xv.w * xv.w;
  block_reduce2(s, s2, red, t);
  mu = s * (1.0f / 1024.0f);
  rstd = rsqrtf(s2 * (1.0f / 1024.0f) - mu * mu + 1e-5f);
  float4 gv2 = ((const float4*)gf)[t], bv2 = ((const float4*)bfp)[t];
  short4v pk = {f2bf((xv.x - mu) * rstd * gv2.x + bv2.x),
                f2bf((xv.y - mu) * rstd * gv2.y + bv2.y),
                f2bf((xv.z - mu) * rstd * gv2.z + bv2.z),
                f2bf((xv.w - mu) * rstd * gv2.w + bv2.w)};
  ((short4v*)(hfb + (size_t)row * 1024))[t] = pk;
}

// --------------------- 256x256 8-phase GEMM core ---------------------------
// R7 phase layout per K-tile t (2 K-halves):
//  ph1: read 12 frags (8A+4B) of half0 | stage A0(t+1) | BAR lgkm0 | 16 MFMA | BAR
//  ph2: pure MFMA (b2,b3)             | stage B0(t+1) | BAR       | 16 MFMA | VMW(4) BAR
//  ph3/ph4: same on half1, staging A1/B1(t+1), VMW(4) at end.
template <int EPI>
DEVI void gemm8_body(const short* __restrict__ A, const short* __restrict__ B,
                     int K, int kbase, int m0, int n0,
                     const float* __restrict__ f0, const float* __restrict__ f1,
                     const float* __restrict__ f2, short* __restrict__ s0,
                     short* __restrict__ s1, short* __restrict__ s2,
                     float* __restrict__ fo) {
  extern __shared__ __align__(16) char lds[];  // 131072 B
  constexpr int NT = 16;
  const int tid = threadIdx.x;
  const int l = tid & 63, w = tid >> 6;
  const int wrM = w >> 2, wcN = w & 3;
  const int lr = l & 15, lg = l >> 4;

  const int cswz = (((lr & 1) << 2) | lg) ^ (lr >> 1);
  const int laneoff = ((lr >> 1) << 7) + (cswz << 4);

  const int rsel = l >> 3;
  const int scz = (l & 7) ^ rsel;
  const int s_roff = w * 16 + rsel * 2 + (scz >> 2);
  const int s_kc = (scz & 3) * 8;
  const short* Asrc = A + (size_t)(m0 + s_roff) * K + kbase + s_kc;
  const short* Bsrc = B + (size_t)(n0 + s_roff) * K + kbase + s_kc;
  const size_t rstep = (size_t)128 * K;

  auto STAGE = [&](int op, int kh, int t) {
    const short* g = (op ? Bsrc : Asrc) + t * 64 + kh * 32;
    char* d = lds + ((t & 1) * 65536 + op * 32768 + kh * 16384 + w * 1024);
    gload_lds16(g, d);
    gload_lds16(g + rstep, d + 8192);
  };

  f32x4 acc[8][4] = {};

  STAGE(0, 0, 0); STAGE(1, 0, 0); STAGE(0, 1, 0); STAGE(1, 1, 0);
  VMW(4); BAR(); SB0();

  for (int t = 0; t < NT; ++t) {
    const char* pa = lds + (t & 1) * 65536 + wrM * 8192 + laneoff;
    const char* pb = lds + (t & 1) * 65536 + 32768 + wcN * 4096 + laneoff;
    const bool st = (t + 1) < NT;
    short8 a[8], b[4];

    // ---- phase 1 (half0): all 12 reads upfront ----
#pragma unroll
    for (int mt = 0; mt < 8; ++mt) a[mt] = *(const short8*)(pa + mt * 1024);
#pragma unroll
    for (int nt = 0; nt < 4; ++nt) b[nt] = *(const short8*)(pb + nt * 1024);
    if (st) STAGE(0, 0, t + 1);
    BAR(); LGKM0();
    __builtin_amdgcn_s_setprio(1);
#pragma unroll
    for (int mt = 0; mt < 8; ++mt) {
      acc[mt][0] = __builtin_amdgcn_mfma_f32_16x16x32_bf16(a[mt], b[0], acc[mt][0], 0, 0, 0);
      acc[mt][1] = __builtin_amdgcn_mfma_f32_16x16x32_bf16(a[mt], b[1], acc[mt][1], 0, 0, 0);
    }
    __builtin_amdgcn_s_setprio(0);
    BAR(); SB0();

    // ---- phase 2 (half0): pure MFMA ----
    if (st) STAGE(1, 0, t + 1);
    BAR(); SB0();
    __builtin_amdgcn_s_setprio(1);
#pragma unroll
    for (int mt = 0; mt < 8; ++mt) {
      acc[mt][2] = __builtin_amdgcn_mfma_f32_16x16x32_bf16(a[mt], b[2], acc[mt][2], 0, 0, 0);
      acc[mt][3] = __builtin_amdgcn_mfma_f32_16x16x32_bf16(a[mt], b[3], acc[mt][3], 0, 0, 0);
    }
    __builtin_amdgcn_s_setprio(0);
    if (st) { VMW(4); } else { VMW(0); }
    BAR(); SB0();

    // ---- phase 3 (half1): all 12 reads upfront ----
    pa += 16384; pb += 16384;
#pragma unroll
    for (int mt = 0; mt < 8; ++mt) a[mt] = *(const short8*)(pa + mt * 1024);
#pragma unroll
    for (int nt = 0; nt < 4; ++nt) b[nt] = *(const short8*)(pb + nt * 1024);
    if (st) STAGE(0, 1, t + 1);
    BAR(); LGKM0();
    __builtin_amdgcn_s_setprio(1);
#pragma unroll
    for (int mt = 0; mt < 8; ++mt) {
      acc[mt][0] = __builtin_amdgcn_mfma_f32_16x16x32_bf16(a[mt], b[0], acc[mt][0], 0, 0, 0);
      acc[mt][1] = __builtin_amdgcn_mfma_f32_16x16x32_bf16(a[mt], b[1], acc[mt][1], 0, 0, 0);
    }
    __builtin_amdgcn_s_setprio(0);
    BAR(); SB0();

    // ---- phase 4 (half1): pure MFMA ----
    if (st) STAGE(1, 1, t + 1);
    BAR(); SB0();
    __builtin_amdgcn_s_setprio(1);
#pragma unroll
    for (int mt = 0; mt < 8; ++mt) {
      acc[mt][2] = __builtin_amdgcn_mfma_f32_16x16x32_bf16(a[mt], b[2], acc[mt][2], 0, 0, 0);
      acc[mt][3] = __builtin_amdgcn_mfma_f32_16x16x32_bf16(a[mt], b[3], acc[mt][3], 0, 0, 0);
    }
    __builtin_amdgcn_s_setprio(0);
    if (st) VMW(4);
    BAR(); SB0();
  }

#pragma unroll
  for (int mt = 0; mt < 8; ++mt) {
#pragma unroll
    for (int nt = 0; nt < 4; ++nt) {
      const int col = n0 + wcN * 64 + nt * 16 + lr;
      const int row0 = m0 + wrM * 128 + mt * 16 + lg * 4;
      if constexpr (EPI == 0) {  // QKV scatter
        const int sel = col >> 10, nn = col & 1023;
        const int hh = nn >> 6, dd = nn & 63;
        const int bb = row0 >> 10, tt0 = row0 & 1023;
        if (sel == 2) {
          const float bias = f2[nn];
          short4v pk = {f2bf(acc[mt][nt][0] + bias), f2bf(acc[mt][nt][1] + bias),
                        f2bf(acc[mt][nt][2] + bias), f2bf(acc[mt][nt][3] + bias)};
          *(short4v*)&s2[(((size_t)(bb * 16 + hh)) * 64 + dd) * 1024 + tt0] = pk;
        } else {
          const float bias = (sel == 0) ? f0[nn] : f1[nn];
          short* dst = (sel == 0) ? s0 : s1;
#pragma unroll
          for (int r = 0; r < 4; ++r)
            dst[(((size_t)(bb * 16 + hh)) * 1024 + tt0 + r) * 64 + dd] =
                f2bf(acc[mt][nt][r] + bias);
        }
      } else if constexpr (EPI == 1) {  // FFN1 bias+relu -> bf16
#pragma unroll
        for (int r = 0; r < 4; ++r) {
          float val = fmaxf(acc[mt][nt][r] + f0[col], 0.0f);
          s0[(size_t)(row0 + r) * 4096 + col] = f2bf(val);
        }
      } else {  // split-K partials f32
#pragma unroll
        for (int r = 0; r < 4; ++r)
          fo[(size_t)(row0 + r) * 1024 + col] = acc[mt][nt][r];
      }
    }
  }
}

__global__ __launch_bounds__(512, 2) void gemm8_qkv(
    const short* __restrict__ A, const short* __restrict__ B,
    const float* __restrict__ bq, const float* __restrict__ bk,
    const float* __restrict__ bv, short* __restrict__ q,
    short* __restrict__ k, short* __restrict__ vt) {
  int bx, by;
  xcd_swz(12, 16, bx, by);
  gemm8_body<0>(A, B, 1024, 0, by * 256, bx * 256, bq, bk, bv,
                q, k, vt, nullptr);
}

__global__ __launch_bounds__(512, 2) void gemm8_ffn1(
    const short* __restrict__ A, const short* __restrict__ B,
    const float* __restrict__ b1f, short* __restrict__ u) {
  int bx, by;
  xcd_swz(16, 16, bx, by);
  gemm8_body<1>(A, B, 1024, 0, by * 256, bx * 256, b1f,
                nullptr, nullptr, u, nullptr, nullptr, nullptr);
}

__global__ __launch_bounds__(512, 2) void gemm8_ffn2sk(
    const short* __restrict__ A, const short* __restrict__ B,
    float* __restrict__ part) {
  const int z = blockIdx.z;
  int bx, by;
  xcd_swz(4, 16, bx, by);
  gemm8_body<2>(A, B, 4096, z * 1024, by * 256, bx * 256,
                nullptr, nullptr, nullptr, nullptr, nullptr, nullptr,
                part + (size_t)z * 4096 * 1024);
}

// out = sum_z part[z] + b2f + hf + x3
__global__ __launch_bounds__(256) void ffn2_reduce(
    const float* __restrict__ part, const float* __restrict__ b2f,
    const short* __restrict__ hfb, const float* __restrict__ x3,
    float* __restrict__ out) {
  const size_t i = (size_t)blockIdx.x * 256 + threadIdx.x;
  const size_t S = (size_t)4096 * 1024 / 4;
  float4 a0 = ((const float4*)part)[i];
  float4 a1 = ((const float4*)part)[i + S];
  float4 a2 = ((const float4*)part)[i + 2 * S];
  float4 a3 = ((const float4*)part)[i + 3 * S];
  float4 bb = ((const float4*)b2f)[i & 255];
  float4 xv = ((const float4*)x3)[i];
  short4v hv = ((const short4v*)hfb)[i];
  float4 o;
  o.x = a0.x + a1.x + a2.x + a3.x + bb.x + bf2f(hv.x) + xv.x;
  o.y = a0.y + a1.y + a2.y + a3.y + bb.y + bf2f(hv.y) + xv.y;
  o.z = a0.z + a1.z + a2.z + a3.z + bb.z + bf2f(hv.z) + xv.z;
  o.w = a0.w + a1.w + a2.w + a3.w + bb.w + bf2f(hv.w) + xv.w;
  ((float4*)out)[i] = o;
}

// ----------------------------- flash attention -----------------------------
__global__ __launch_bounds__(256, 5) void attn_kernel(
    const short* __restrict__ q, const short* __restrict__ k,
    const short* __restrict__ vt, float* __restrict__ o) {
  __shared__ __align__(16) short Ksm[64 * 64];
  __shared__ __align__(16) short Vsm[64 * 64];
  __shared__ __align__(16) short Psm[4 * 16 * 64];
  const int bh = blockIdx.x;
  const int qt = 15 - blockIdx.y;  // heavy blocks dispatch FIRST
  const int tid = threadIdx.x, lane = tid & 63, w = tid >> 6;
  const int lr = lane & 15, lg = lane >> 4;

  const short* qb = q + (size_t)bh * 1024 * 64;
  const short* kb = k + (size_t)bh * 1024 * 64;
  const short* vb = vt + (size_t)bh * 64 * 1024;

  const int qrow = qt * 64 + w * 16 + lr;
  short8 qf0 = *(const short8*)&qb[(size_t)qrow * 64 + lg * 8];
  short8 qf1 = *(const short8*)&qb[(size_t)qrow * 64 + 32 + lg * 8];

  f32x4 oacc[4] = {};       // O^T frags: col q=lr, row d=nt*16+lg*4+r
  float mrun = -1e30f, lrun = 0.0f;  // per-lane: this lane's q-row

  const float scale2 = 0.03125f * 1.44269504088896f;  // (1/sqrt(C))*log2(e)
  const int srow = tid >> 3;  // staging row 0..31 (+32 on second chunk)
  const int sc8 = tid & 7;    // 16B chunk within 128B row
  char* pw = (char*)(Psm + w * 1024);  // per-wave 16x64 P tile
  const int qloc = w * 16 + lr;        // q-row local to 64-row block
  const int rowswz = (lr & 7) << 4;    // P row XOR swizzle

  short8 kreg[2], vreg[2];
#pragma unroll
  for (int p = 0; p < 2; ++p) {
    const int rr = srow + p * 32;
    kreg[p] = *(const short8*)&kb[(size_t)rr * 64 + sc8 * 8];
    vreg[p] = *(const short8*)&vb[(size_t)rr * 1024 + sc8 * 8];
  }

  for (int kt = 0; kt <= qt; ++kt) {
#pragma unroll
    for (int p = 0; p < 2; ++p) {
      const int rr = srow + p * 32;
      *(short8*)((char*)Ksm + rr * 128 + ((sc8 ^ (rr & 7)) << 4)) = kreg[p];
      *(short8*)((char*)Vsm + rr * 128 + ((sc8 ^ (rr & 7)) << 4)) = vreg[p];
    }
    __syncthreads();
    if (kt < qt) {
#pragma unroll
      for (int p = 0; p < 2; ++p) {
        const int rr = srow + p * 32;
        kreg[p] =
            *(const short8*)&kb[((size_t)((kt + 1) * 64 + rr)) * 64 + sc8 * 8];
        vreg[p] =
            *(const short8*)&vb[(size_t)rr * 1024 + (kt + 1) * 64 + sc8 * 8];
      }
    }

    // S^T = K Q^T : lane (lr,lg) gets q=lr, k = nt*16 + lg*4 + r
    f32x4 sfr[4];
#pragma unroll
    for (int nt = 0; nt < 4; ++nt) {
      const int krow = nt * 16 + lr;
      short8 kf0 = *(const short8*)((const char*)Ksm + krow * 128 +
                                    (((0 + lg) ^ (krow & 7)) << 4));
      short8 kf1 = *(const short8*)((const char*)Ksm + krow * 128 +
                                    (((4 + lg) ^ (krow & 7)) << 4));
      f32x4 z = {};
      z = __builtin_amdgcn_mfma_f32_16x16x32_bf16(kf0, qf0, z, 0, 0, 0);
      z = __builtin_amdgcn_mfma_f32_16x16x32_bf16(kf1, qf1, z, 0, 0, 0);
      sfr[nt] = z;
    }
    if (kt == qt) {
#pragma unroll
      for (int nt = 0; nt < 4; ++nt) {
        const int kb0 = nt * 16 + lg * 4;
#pragma unroll
        for (int r = 0; r < 4; ++r)
          sfr[nt][r] = (kb0 + r <= qloc) ? sfr[nt][r] * scale2 : -1e30f;
      }
    } else {
#pragma unroll
      for (int nt = 0; nt < 4; ++nt)
#pragma unroll
        for (int r = 0; r < 4; ++r) sfr[nt][r] *= scale2;
    }
    float pm;
    {
      float a0 = fmaxf(fmaxf(sfr[0][0], sfr[0][1]), fmaxf(sfr[0][2], sfr[0][3]));
      float a1 = fmaxf(fmaxf(sfr[1][0], sfr[1][1]), fmaxf(sfr[1][2], sfr[1][3]));
      float a2 = fmaxf(fmaxf(sfr[2][0], sfr[2][1]), fmaxf(sfr[2][2], sfr[2][3]));
      float a3 = fmaxf(fmaxf(sfr[3][0], sfr[3][1]), fmaxf(sfr[3][2], sfr[3][3]));
      pm = fmaxf(fmaxf(a0, a1), fmaxf(a2, a3));
      pm = fmaxf(pm, __shfl_xor(pm, 16, 64));
      pm = fmaxf(pm, __shfl_xor(pm, 32, 64));
    }
    if (!__all(pm - mrun <= 8.0f)) {
      const float mnew = fmaxf(mrun, pm);
      const float alpha = exp2f(mrun - mnew);
      mrun = mnew;
      lrun *= alpha;
#pragma unroll
      for (int nt = 0; nt < 4; ++nt)
#pragma unroll
        for (int r = 0; r < 4; ++r) oacc[nt][r] *= alpha;
    }
    float rs;
    {
#pragma unroll
      for (int nt = 0; nt < 4; ++nt)
#pragma unroll
        for (int r = 0; r < 4; ++r) sfr[nt][r] = exp2f(sfr[nt][r] - mrun);
      float s0 = (sfr[0][0] + sfr[0][1]) + (sfr[0][2] + sfr[0][3]);
      float s1 = (sfr[1][0] + sfr[1][1]) + (sfr[1][2] + sfr[1][3]);
      float s2 = (sfr[2][0] + sfr[2][1]) + (sfr[2][2] + sfr[2][3]);
      float s3 = (sfr[3][0] + sfr[3][1]) + (sfr[3][2] + sfr[3][3]);
      rs = (s0 + s1) + (s2 + s3);
      rs += __shfl_xor(rs, 16, 64);
      rs += __shfl_xor(rs, 32, 64);
    }
    lrun += rs;

#pragma unroll
    for (int nt = 0; nt < 4; ++nt) {
      unsigned w0, w1;
      asm("v_cvt_pk_bf16_f32 %0, %1, %2"
          : "=v"(w0) : "v"(sfr[nt][0]), "v"(sfr[nt][1]));
      asm("v_cvt_pk_bf16_f32 %0, %1, %2"
          : "=v"(w1) : "v"(sfr[nt][2]), "v"(sfr[nt][3]));
      uint2 pk2 = {w0, w1};
      *(uint2*)(pw + lr * 128 + ((nt * 32 + lg * 8) ^ rowswz)) = pk2;
    }

#pragma unroll
    for (int kc = 0; kc < 2; ++kc) {
      short8 pb8 = *(const short8*)(pw + lr * 128 + ((kc * 64 + lg * 16) ^ rowswz));
#pragma unroll
      for (int nt = 0; nt < 4; ++nt) {
        const int vrow = nt * 16 + lr;
        short8 vf = *(const short8*)((const char*)Vsm + vrow * 128 +
                                     (((kc * 4 + lg) ^ (vrow & 7)) << 4));
        oacc[nt] = __builtin_amdgcn_mfma_f32_16x16x32_bf16(vf, pb8, oacc[nt], 0, 0, 0);
      }
    }
    __syncthreads();
  }

  const float inv = 1.0f / lrun;
  float* ob = o + (size_t)(bh >> 4) * 1024 * 1024 +
              (size_t)(qt * 64 + qloc) * 1024 + (bh & 15) * 64;
#pragma unroll
  for (int nt = 0; nt < 4; ++nt) {
    float4 ov = {oacc[nt][0] * inv, oacc[nt][1] * inv, oacc[nt][2] * inv,
                 oacc[nt][3] * inv};
    *(float4*)&ob[nt * 16 + lg * 4] = ov;
  }
}

// ------------------------------- launcher ----------------------------------
extern "C" void kernel_launch(void* const* d_in, const int* in_sizes, int n_in,
                              void* d_out, int out_size, void* d_ws,
                              size_t ws_size, hipStream_t stream) {
  const float* x = (const float*)d_in[0];
  const float* Wq = (const float*)d_in[1];
  const float* bq = (const float*)d_in[2];
  const float* Wk = (const float*)d_in[3];
  const float* bk = (const float*)d_in[4];
  const float* Wv = (const float*)d_in[5];
  const float* bv = (const float*)d_in[6];
  const float* g1 = (const float*)d_in[7];
  const float* b1 = (const float*)d_in[8];
  const float* g2 = (const float*)d_in[9];
  const float* b2 = (const float*)d_in[10];
  const float* gf = (const float*)d_in[11];
  const float* bfp = (const float*)d_in[12];
  const float* W1 = (const float*)d_in[13];
  const float* b1f = (const float*)d_in[14];
  const float* W2 = (const float*)d_in[15];
  const float* b2f = (const float*)d_in[16];
  float* out = (float*)d_out;

  hipFuncSetAttribute((const void*)gemm8_qkv,
                      hipFuncAttributeMaxDynamicSharedMemorySize, 131072);
  hipFuncSetAttribute((const void*)gemm8_ffn1,
                      hipFuncAttributeMaxDynamicSharedMemorySize, 131072);
  hipFuncSetAttribute((const void*)gemm8_ffn2sk,
                      hipFuncAttributeMaxDynamicSharedMemorySize, 131072);

  const size_t MB = 1024 * 1024;
  char* p = (char*)d_ws;
  // Region A (70MB): dead before gemm8_ffn2sk; 64MB split-K partials alias it.
  float* hbuf = (float*)(p + 0 * MB);      // 16MB  h (f32), dead after ln2f
  short* qbuf = (short*)(p + 16 * MB);     // 8MB   dead after attn
  short* kbuf = (short*)(p + 24 * MB);     // 8MB   dead after attn
  short* vtb = (short*)(p + 32 * MB);      // 8MB   dead after attn
  float* obuf = (float*)(p + 40 * MB);     // 16MB  dead after ln2f
  short* wqkv_t = (short*)(p + 56 * MB);   // 6MB   dead after gemm8_qkv
  short* w1_t = (short*)(p + 62 * MB);     // 8MB   dead after gemm8_ffn1
  float* part = (float*)(p + 0 * MB);      // 64MB  alias
  // Region B (72MB): live through the end.
  char* q = p + 70 * MB;
  short* w2_t = (short*)(q + 0 * MB);      // 8MB
  short* hbb = (short*)(q + 8 * MB);       // 8MB
  float* x3b = (float*)(q + 16 * MB);      // 16MB
  short* hfb = (short*)(q + 32 * MB);      // 8MB
  short* ub = (short*)(q + 40 * MB);       // 32MB

  dim3 tb(32, 8);
  transpose_qkv<<<dim3(2, 32, 48), tb, 0, stream>>>(Wq, Wk, Wv, wqkv_t);
  transpose_to_bf16<<<dim3(128, 32, 1), tb, 0, stream>>>(W1, w1_t, 1024, 4096);
  transpose_to_bf16<<<dim3(32, 128, 1), tb, 0, stream>>>(W2, w2_t, 4096, 1024);

  ln1_kernel<<<4096, 256, 0, stream>>>(x, g1, b1, hbuf, hbb);

  gemm8_qkv<<<dim3(12, 16), 512, 131072, stream>>>(hbb, wqkv_t, bq, bk, bv,
                                                   qbuf, kbuf, vtb);

  attn_kernel<<<dim3(64, 16), 256, 0, stream>>>(qbuf, kbuf, vtb, obuf);

  ln2f_kernel<<<4096, 256, 0, stream>>>(hbuf, obuf, g2, b2, gf, bfp, x3b, hfb);

  gemm8_ffn1<<<dim3(16, 16), 512, 131072, stream>>>(hfb, w1_t, b1f, ub);

  gemm8_ffn2sk<<<dim3(4, 16, 4), 512, 131072, stream>>>(ub, w2_t, part);

  ffn2_reduce<<<4096, 256, 0, stream>>>(part, b2f, hfb, x3b, out);
}